// Round 1
// baseline (1658.371 us; speedup 1.0000x reference)
//
#include <hip/hip_runtime.h>
#include <hip/hip_bf16.h>

// ---------------------------------------------------------------------------
// Sub_Cluster_Level_GCN — fp32 baseline (round 0)
// Pipeline:
//   memset(cnt,cursor) -> count -> scan -> scatter -> cluster_sum
//   -> prep(norms,sublabs) -> gram+softmax(A) -> xnorm -> agg1
//   -> gemm1(cat[x,agg1]@W1) -> agg2 -> gemm2 -> classifier+softmax
// ---------------------------------------------------------------------------

#define NROW 50000
#define DIM  2048
#define NSUB 2000
#define BB   256
#define KK   64
#define NHID 512
#define DOUT 256

// ------------------------- segment-mean path -------------------------------

__global__ __launch_bounds__(256) void k_count(const int* __restrict__ sub_label,
                                               int* __restrict__ cnt) {
  int i = blockIdx.x * 256 + threadIdx.x;
  if (i < NROW) atomicAdd(&cnt[sub_label[i]], 1);
}

__global__ __launch_bounds__(256) void k_scan(const int* __restrict__ cnt,
                                              int* __restrict__ offs,
                                              int* __restrict__ cursor) {
  __shared__ int part[256];
  int t = threadIdx.x;
  int base = t * 8;
  int local[8];
  int sum = 0;
#pragma unroll
  for (int i = 0; i < 8; i++) {
    int v = (base + i < NSUB) ? cnt[base + i] : 0;
    local[i] = sum;
    sum += v;
  }
  part[t] = sum;
  __syncthreads();
  for (int off = 1; off < 256; off <<= 1) {
    int v = (t >= off) ? part[t - off] : 0;
    __syncthreads();
    part[t] += v;
    __syncthreads();
  }
  int pre = (t == 0) ? 0 : part[t - 1];
#pragma unroll
  for (int i = 0; i < 8; i++) {
    if (base + i < NSUB) {
      int o = pre + local[i];
      offs[base + i] = o;
      cursor[base + i] = o;
    }
  }
  if (t == 255) offs[NSUB] = pre + sum;
}

__global__ __launch_bounds__(256) void k_scatter(const int* __restrict__ sub_label,
                                                 int* __restrict__ cursor,
                                                 int* __restrict__ rowlist) {
  int i = blockIdx.x * 256 + threadIdx.x;
  if (i < NROW) {
    int s = sub_label[i];
    int pos = atomicAdd(&cursor[s], 1);
    rowlist[pos] = i;
  }
}

// one block per cluster: coalesced sum of its rows, write mean + simm + nums
__global__ __launch_bounds__(256) void k_cluster_sum(const float* __restrict__ features,
                                                     const int* __restrict__ rowlist,
                                                     const int* __restrict__ offs,
                                                     float* __restrict__ submean,
                                                     float* __restrict__ simm,
                                                     float* __restrict__ nums) {
  int s = blockIdx.x;
  int t = threadIdx.x;
  int start = offs[s], end = offs[s + 1];
  float acc[8] = {0, 0, 0, 0, 0, 0, 0, 0};
  for (int r = start; r < end; r++) {
    const float* row = features + (size_t)rowlist[r] * DIM + t * 8;
    float4 v0 = *(const float4*)(row);
    float4 v1 = *(const float4*)(row + 4);
    acc[0] += v0.x; acc[1] += v0.y; acc[2] += v0.z; acc[3] += v0.w;
    acc[4] += v1.x; acc[5] += v1.y; acc[6] += v1.z; acc[7] += v1.w;
  }
  int cnt = end - start;
  float inv = 1.0f / (float)(cnt > 0 ? cnt : 1);
  float m[8];
  float ss = 0.f;
#pragma unroll
  for (int i = 0; i < 8; i++) { m[i] = acc[i] * inv; ss += m[i] * m[i]; }
  float* outp = submean + (size_t)s * DIM + t * 8;
  *(float4*)(outp)     = make_float4(m[0], m[1], m[2], m[3]);
  *(float4*)(outp + 4) = make_float4(m[4], m[5], m[6], m[7]);
  __shared__ float red[256];
  red[t] = ss;
  __syncthreads();
  for (int s2 = 128; s2 > 0; s2 >>= 1) {
    if (t < s2) red[t] += red[t + s2];
    __syncthreads();
  }
  if (t == 0) {
    simm[s] = red[0];
    nums[s] = (float)cnt;
  }
}

// per-sample: feature-row norm, neighbor sub-labels, row norms (sqrt(simm))
__global__ __launch_bounds__(256) void k_prep(const int* __restrict__ indexes,
                                              const float* __restrict__ features,
                                              const int* __restrict__ sub_label,
                                              const int* __restrict__ knn,
                                              const float* __restrict__ simm,
                                              int* __restrict__ sublabs,
                                              float* __restrict__ norms) {
  int b = blockIdx.x;
  int t = threadIdx.x;
  const float* row = features + (size_t)indexes[b] * DIM;
  float ss = 0.f;
  for (int i = t; i < DIM; i += 256) {
    float v = row[i];
    ss += v * v;
  }
  __shared__ float red[256];
  red[t] = ss;
  __syncthreads();
  for (int s2 = 128; s2 > 0; s2 >>= 1) {
    if (t < s2) red[t] += red[t + s2];
    __syncthreads();
  }
  __shared__ float n0s;
  if (t == 0) n0s = sqrtf(red[0]);
  __syncthreads();
  if (t < KK) {
    int sl = sub_label[knn[b * KK + t]];
    sublabs[b * KK + t] = sl;
    norms[b * KK + t] = (t == 0) ? n0s : sqrtf(simm[sl]);
  }
}

// ------------------------ gram + weight + softmax ---------------------------
// one block per sample b; A[b,k,j] = softmax_j( dot(sf_k, sf_j) * exp(pred[b,j,1]) )
__global__ __launch_bounds__(256) void k_gram(const int* __restrict__ indexes,
                                              const float* __restrict__ features,
                                              const float* __restrict__ submean,
                                              const int* __restrict__ sublabs,
                                              const float* __restrict__ all_pred,
                                              float* __restrict__ A) {
  int b = blockIdx.x;
  int t = threadIdx.x;
  __shared__ float tileT[128][68];  // [d_local][k], padded
  __shared__ const float* rowp[KK];
  __shared__ float wj[KK];
  if (t < KK) {
    rowp[t] = (t == 0) ? (features + (size_t)indexes[b] * DIM)
                       : (submean + (size_t)sublabs[b * KK + t] * DIM);
    wj[t] = expf(all_pred[(size_t)(b * KK + t) * 2 + 1]);
  }
  __syncthreads();

  const int k = t >> 2;
  const int jg = (t & 3) * 16;
  float acc[16];
#pragma unroll
  for (int i = 0; i < 16; i++) acc[i] = 0.f;

  for (int c = 0; c < 16; c++) {
    int dc = c * 128;
#pragma unroll
    for (int i = 0; i < 8; i++) {
      int v = t + 256 * i;
      int kr = v >> 5;
      int d4 = v & 31;
      float4 f = *(const float4*)(rowp[kr] + dc + d4 * 4);
      int dl = d4 * 4;
      tileT[dl + 0][kr] = f.x;
      tileT[dl + 1][kr] = f.y;
      tileT[dl + 2][kr] = f.z;
      tileT[dl + 3][kr] = f.w;
    }
    __syncthreads();
#pragma unroll 4
    for (int d = 0; d < 128; d++) {
      float a = tileT[d][k];
      float4 b0 = *(const float4*)&tileT[d][jg + 0];
      float4 b1 = *(const float4*)&tileT[d][jg + 4];
      float4 b2 = *(const float4*)&tileT[d][jg + 8];
      float4 b3 = *(const float4*)&tileT[d][jg + 12];
      acc[0] += a * b0.x;  acc[1] += a * b0.y;  acc[2] += a * b0.z;  acc[3] += a * b0.w;
      acc[4] += a * b1.x;  acc[5] += a * b1.y;  acc[6] += a * b1.z;  acc[7] += a * b1.w;
      acc[8] += a * b2.x;  acc[9] += a * b2.y;  acc[10] += a * b2.z; acc[11] += a * b2.w;
      acc[12] += a * b3.x; acc[13] += a * b3.y; acc[14] += a * b3.z; acc[15] += a * b3.w;
    }
    __syncthreads();
  }

  // scale by wj, softmax over full row (4 threads per row, same wave)
  float sv[16];
  float mx = -1e30f;
#pragma unroll
  for (int j = 0; j < 16; j++) {
    sv[j] = acc[j] * wj[jg + j];
    mx = fmaxf(mx, sv[j]);
  }
  mx = fmaxf(mx, __shfl_xor(mx, 1));
  mx = fmaxf(mx, __shfl_xor(mx, 2));
  float sum = 0.f;
#pragma unroll
  for (int j = 0; j < 16; j++) {
    sv[j] = expf(sv[j] - mx);
    sum += sv[j];
  }
  sum += __shfl_xor(sum, 1);
  sum += __shfl_xor(sum, 2);
  float inv = 1.0f / sum;
  float* outp = A + ((size_t)b * KK + k) * KK + jg;
  *(float4*)(outp + 0)  = make_float4(sv[0] * inv, sv[1] * inv, sv[2] * inv, sv[3] * inv);
  *(float4*)(outp + 4)  = make_float4(sv[4] * inv, sv[5] * inv, sv[6] * inv, sv[7] * inv);
  *(float4*)(outp + 8)  = make_float4(sv[8] * inv, sv[9] * inv, sv[10] * inv, sv[11] * inv);
  *(float4*)(outp + 12) = make_float4(sv[12] * inv, sv[13] * inv, sv[14] * inv, sv[15] * inv);
}

// ------------------------------ x normalize --------------------------------
// x[b,k,d] = sf[b,k,d]/||sf_k|| - sf[b,0,d]/||sf_0||
__global__ __launch_bounds__(256) void k_xnorm(const int* __restrict__ indexes,
                                               const float* __restrict__ features,
                                               const float* __restrict__ submean,
                                               const int* __restrict__ sublabs,
                                               const float* __restrict__ norms,
                                               float* __restrict__ xn) {
  int b = blockIdx.y;
  int d = blockIdx.x * 256 + threadIdx.x;
  int t = threadIdx.x;
  __shared__ float ninv[KK];
  __shared__ int sl[KK];
  if (t < KK) {
    ninv[t] = 1.0f / norms[b * KK + t];
    sl[t] = sublabs[b * KK + t];
  }
  __syncthreads();
  float f0 = features[(size_t)indexes[b] * DIM + d];
  float r0 = f0 * ninv[0];
#pragma unroll 4
  for (int kk = 0; kk < KK; kk++) {
    float val = (kk == 0) ? f0 : submean[(size_t)sl[kk] * DIM + d];
    xn[((size_t)b * KK + kk) * DIM + d] = val * ninv[kk] - r0;
  }
}

// ------------------------------- agg = A @ X --------------------------------
template <int DD>
__global__ __launch_bounds__(256) void k_agg(const float* __restrict__ A,
                                             const float* __restrict__ X,
                                             float* __restrict__ out) {
  int b = blockIdx.y;
  int d = blockIdx.x * 256 + threadIdx.x;
  int t = threadIdx.x;
  __shared__ float At[KK][68];  // At[j][k] = A[b,k,j]
#pragma unroll
  for (int i = 0; i < 16; i++) {
    int v = t + 256 * i;
    int kr = v >> 6;
    int j = v & 63;
    At[j][kr] = A[((size_t)b * KK + kr) * KK + j];
  }
  __syncthreads();
  float acc[KK];
#pragma unroll
  for (int i = 0; i < KK; i++) acc[i] = 0.f;
#pragma unroll 4
  for (int j = 0; j < KK; j++) {
    float xv = X[((size_t)b * KK + j) * DD + d];
#pragma unroll
    for (int k4 = 0; k4 < 16; k4++) {
      float4 a = *(const float4*)&At[j][k4 * 4];
      acc[k4 * 4 + 0] += a.x * xv;
      acc[k4 * 4 + 1] += a.y * xv;
      acc[k4 * 4 + 2] += a.z * xv;
      acc[k4 * 4 + 3] += a.w * xv;
    }
  }
#pragma unroll
  for (int kk = 0; kk < KK; kk++)
    out[((size_t)b * KK + kk) * DD + d] = acc[kk];
}

// ---------------------- C = relu(cat(Xa,Xb) @ W + bias) ---------------------
template <int KHALF, int NDIM>
__global__ __launch_bounds__(256) void k_gemm_cat(const float* __restrict__ Xa,
                                                  const float* __restrict__ Xb,
                                                  const float* __restrict__ W,
                                                  const float* __restrict__ bias,
                                                  float* __restrict__ out) {
  const int mt = blockIdx.y * 64;
  const int nt = blockIdx.x * 64;
  const int t = threadIdx.x;
  const int tm = t >> 4, tn = t & 15;
  __shared__ float As[32][68];  // As[kk][m]
  __shared__ float Bs[32][68];  // Bs[kk][n]
  float acc[4][4];
#pragma unroll
  for (int i = 0; i < 4; i++)
#pragma unroll
    for (int j = 0; j < 4; j++) acc[i][j] = 0.f;

  const int nchunk = (2 * KHALF) / 32;
  for (int kc = 0; kc < nchunk; kc++) {
    int k0 = kc * 32;
    const float* src = (k0 < KHALF) ? Xa : Xb;
    int kk0 = (k0 < KHALF) ? k0 : (k0 - KHALF);
#pragma unroll
    for (int i = 0; i < 2; i++) {
      int v = t + 256 * i;
      int m = v >> 3, k4 = v & 7;
      float4 f = *(const float4*)(src + (size_t)(mt + m) * KHALF + kk0 + k4 * 4);
      As[k4 * 4 + 0][m] = f.x;
      As[k4 * 4 + 1][m] = f.y;
      As[k4 * 4 + 2][m] = f.z;
      As[k4 * 4 + 3][m] = f.w;
    }
#pragma unroll
    for (int i = 0; i < 2; i++) {
      int v = t + 256 * i;
      int kkr = v >> 4, n4 = v & 15;
      *(float4*)&Bs[kkr][n4 * 4] =
          *(const float4*)(W + (size_t)(k0 + kkr) * NDIM + nt + n4 * 4);
    }
    __syncthreads();
#pragma unroll
    for (int kk = 0; kk < 32; kk++) {
      float4 a = *(const float4*)&As[kk][tm * 4];
      float4 bv = *(const float4*)&Bs[kk][tn * 4];
      acc[0][0] += a.x * bv.x; acc[0][1] += a.x * bv.y; acc[0][2] += a.x * bv.z; acc[0][3] += a.x * bv.w;
      acc[1][0] += a.y * bv.x; acc[1][1] += a.y * bv.y; acc[1][2] += a.y * bv.z; acc[1][3] += a.y * bv.w;
      acc[2][0] += a.z * bv.x; acc[2][1] += a.z * bv.y; acc[2][2] += a.z * bv.z; acc[2][3] += a.z * bv.w;
      acc[3][0] += a.w * bv.x; acc[3][1] += a.w * bv.y; acc[3][2] += a.w * bv.z; acc[3][3] += a.w * bv.w;
    }
    __syncthreads();
  }
  float4 bb = *(const float4*)(bias + nt + tn * 4);
#pragma unroll
  for (int i = 0; i < 4; i++) {
    float4 c;
    c.x = fmaxf(acc[i][0] + bb.x, 0.f);
    c.y = fmaxf(acc[i][1] + bb.y, 0.f);
    c.z = fmaxf(acc[i][2] + bb.z, 0.f);
    c.w = fmaxf(acc[i][3] + bb.w, 0.f);
    *(float4*)(out + (size_t)(mt + tm * 4 + i) * NDIM + nt + tn * 4) = c;
  }
}

// --------------- classifier: h=x2@Wc1+bc1, PReLU, @Wc2+bc2, softmax ---------
__global__ __launch_bounds__(256) void k_cls(const float* __restrict__ x2,
                                             const float* __restrict__ Wc1,
                                             const float* __restrict__ bc1,
                                             const float* __restrict__ pa,
                                             const float* __restrict__ Wc2,
                                             const float* __restrict__ bc2,
                                             float* __restrict__ probs) {
  int mt = blockIdx.x * 64;
  int t = threadIdx.x;
  __shared__ float Ws[32][260];
  __shared__ float As[32][68];
  float h[64];
#pragma unroll
  for (int i = 0; i < 64; i++) h[i] = 0.f;
  const int r = t >> 2;
  const int cg = (t & 3) * 64;
  for (int kc = 0; kc < 8; kc++) {
    int k0 = kc * 32;
#pragma unroll
    for (int i = 0; i < 2; i++) {
      int v = t + 256 * i;
      int m = v >> 3, k4 = v & 7;
      float4 f = *(const float4*)(x2 + (size_t)(mt + m) * DOUT + k0 + k4 * 4);
      As[k4 * 4 + 0][m] = f.x;
      As[k4 * 4 + 1][m] = f.y;
      As[k4 * 4 + 2][m] = f.z;
      As[k4 * 4 + 3][m] = f.w;
    }
#pragma unroll
    for (int i = 0; i < 8; i++) {
      int v = t + 256 * i;
      int kkr = v >> 6, c4 = v & 63;
      *(float4*)&Ws[kkr][c4 * 4] =
          *(const float4*)(Wc1 + (size_t)(k0 + kkr) * DOUT + c4 * 4);
    }
    __syncthreads();
    for (int kk = 0; kk < 32; kk++) {
      float a = As[kk][r];
#pragma unroll
      for (int c4 = 0; c4 < 16; c4++) {
        float4 w = *(const float4*)&Ws[kk][cg + c4 * 4];
        h[c4 * 4 + 0] += a * w.x;
        h[c4 * 4 + 1] += a * w.y;
        h[c4 * 4 + 2] += a * w.z;
        h[c4 * 4 + 3] += a * w.w;
      }
    }
    __syncthreads();
  }
  float l0 = 0.f, l1 = 0.f;
#pragma unroll 8
  for (int j = 0; j < 64; j++) {
    int c = cg + j;
    float v = h[j] + bc1[c];
    v = (v >= 0.f) ? v : pa[c] * v;
    l0 += v * Wc2[c * 2 + 0];
    l1 += v * Wc2[c * 2 + 1];
  }
  l0 += __shfl_xor(l0, 1);
  l0 += __shfl_xor(l0, 2);
  l1 += __shfl_xor(l1, 1);
  l1 += __shfl_xor(l1, 2);
  if ((t & 3) == 0) {
    l0 += bc2[0];
    l1 += bc2[1];
    float m = fmaxf(l0, l1);
    float e0 = expf(l0 - m), e1 = expf(l1 - m);
    float inv = 1.0f / (e0 + e1);
    int row = mt + r;
    *(float2*)(probs + (size_t)row * 2) = make_float2(e0 * inv, e1 * inv);
  }
}

// ---------------------------------------------------------------------------

extern "C" void kernel_launch(void* const* d_in, const int* in_sizes, int n_in,
                              void* d_out, int out_size, void* d_ws, size_t ws_size,
                              hipStream_t stream) {
  const int* indexes = (const int*)d_in[0];
  const float* features = (const float*)d_in[1];
  const int* sub_label = (const int*)d_in[3];
  const int* knn = (const int*)d_in[6];
  const float* all_pred = (const float*)d_in[7];
  const float* W1 = (const float*)d_in[9];
  const float* b1 = (const float*)d_in[10];
  const float* W2 = (const float*)d_in[11];
  const float* b2 = (const float*)d_in[12];
  const float* Wc1 = (const float*)d_in[13];
  const float* bc1 = (const float*)d_in[14];
  const float* pa = (const float*)d_in[15];
  const float* Wc2 = (const float*)d_in[16];
  const float* bc2 = (const float*)d_in[17];

  float* out = (float*)d_out;
  float* probs = out;                    // [B*K*2]        = 32768
  float* simm = out + 32768;             // [2000]
  float* submean = out + 34768;          // [2000*2048]
  float* nums = out + 4130768;           // [2000]

  // workspace layout (floats)
  constexpr size_t SZ_XNORM = (size_t)BB * KK * DIM;   // 33,554,432
  constexpr size_t SZ_AGG1 = SZ_XNORM;
  constexpr size_t SZ_X1 = (size_t)BB * KK * NHID;     // 8,388,608
  constexpr size_t SZ_A = (size_t)BB * KK * KK;        // 1,048,576
  float* wsf = (float*)d_ws;
  float* xnorm = wsf;                      // dead after gemm1 -> reused as agg2
  float* agg1 = wsf + SZ_XNORM;            // dead after gemm1 -> reused as x2
  float* x1 = agg1 + SZ_AGG1;
  float* Abuf = x1 + SZ_X1;
  int* cnt = (int*)(Abuf + SZ_A);
  int* cursor = cnt + NSUB;                // contiguous with cnt (single memset)
  int* offs = cursor + NSUB;               // NSUB+1
  int* rowlist = offs + NSUB + 4;
  int* sublabs = rowlist + NROW + 8;
  float* norms = (float*)(sublabs + BB * KK);
  float* agg2 = xnorm;  // alias
  float* x2 = agg1;     // alias

  hipMemsetAsync(cnt, 0, 2 * NSUB * sizeof(int), stream);

  const int nrb = (NROW + 255) / 256;
  k_count<<<nrb, 256, 0, stream>>>(sub_label, cnt);
  k_scan<<<1, 256, 0, stream>>>(cnt, offs, cursor);
  k_scatter<<<nrb, 256, 0, stream>>>(sub_label, cursor, rowlist);
  k_cluster_sum<<<NSUB, 256, 0, stream>>>(features, rowlist, offs, submean, simm, nums);
  k_prep<<<BB, 256, 0, stream>>>(indexes, features, sub_label, knn, simm, sublabs, norms);
  k_gram<<<BB, 256, 0, stream>>>(indexes, features, submean, sublabs, all_pred, Abuf);

  dim3 g8(8, BB);
  k_xnorm<<<g8, 256, 0, stream>>>(indexes, features, submean, sublabs, norms, xnorm);
  k_agg<DIM><<<g8, 256, 0, stream>>>(Abuf, xnorm, agg1);
  k_gemm_cat<DIM, NHID><<<dim3(NHID / 64, BB), 256, 0, stream>>>(xnorm, agg1, W1, b1, x1);
  k_agg<NHID><<<dim3(NHID / 256, BB), 256, 0, stream>>>(Abuf, x1, agg2);
  k_gemm_cat<NHID, DOUT><<<dim3(DOUT / 64, BB), 256, 0, stream>>>(x1, agg2, W2, b2, x2);
  k_cls<<<BB, 256, 0, stream>>>(x2, Wc1, bc1, pa, Wc2, bc2, probs);
}

// Round 2
// 687.303 us; speedup vs baseline: 2.4129x; 2.4129x over previous
//
#include <hip/hip_runtime.h>
#include <hip/hip_bf16.h>

// ---------------------------------------------------------------------------
// Sub_Cluster_Level_GCN — round 1: bf16 MFMA GEMMs (m97 recipe + T2 swizzle)
// ---------------------------------------------------------------------------

#define NROW 50000
#define DIM  2048
#define NSUB 2000
#define BB   256
#define KK   64
#define NHID 512
#define DOUT 256

typedef __attribute__((ext_vector_type(8))) short bf16x8;
typedef __attribute__((ext_vector_type(4))) float f32x4;

__device__ __forceinline__ unsigned short f2bf(float f) {
  union { float f; unsigned u; } v; v.f = f;
  unsigned r = v.u + 0x7FFF + ((v.u >> 16) & 1);
  return (unsigned short)(r >> 16);
}
__device__ __forceinline__ float bf2f(unsigned short h) {
  union { unsigned u; float f; } v; v.u = ((unsigned)h) << 16;
  return v.f;
}

// ------------------------- segment-mean path -------------------------------

__global__ __launch_bounds__(256) void k_count(const int* __restrict__ sub_label,
                                               int* __restrict__ cnt) {
  int i = blockIdx.x * 256 + threadIdx.x;
  if (i < NROW) atomicAdd(&cnt[sub_label[i]], 1);
}

__global__ __launch_bounds__(256) void k_scan(const int* __restrict__ cnt,
                                              int* __restrict__ offs,
                                              int* __restrict__ cursor) {
  __shared__ int part[256];
  int t = threadIdx.x;
  int base = t * 8;
  int local[8];
  int sum = 0;
#pragma unroll
  for (int i = 0; i < 8; i++) {
    int v = (base + i < NSUB) ? cnt[base + i] : 0;
    local[i] = sum;
    sum += v;
  }
  part[t] = sum;
  __syncthreads();
  for (int off = 1; off < 256; off <<= 1) {
    int v = (t >= off) ? part[t - off] : 0;
    __syncthreads();
    part[t] += v;
    __syncthreads();
  }
  int pre = (t == 0) ? 0 : part[t - 1];
#pragma unroll
  for (int i = 0; i < 8; i++) {
    if (base + i < NSUB) {
      int o = pre + local[i];
      offs[base + i] = o;
      cursor[base + i] = o;
    }
  }
  if (t == 255) offs[NSUB] = pre + sum;
}

__global__ __launch_bounds__(256) void k_scatter(const int* __restrict__ sub_label,
                                                 int* __restrict__ cursor,
                                                 int* __restrict__ rowlist) {
  int i = blockIdx.x * 256 + threadIdx.x;
  if (i < NROW) {
    int s = sub_label[i];
    int pos = atomicAdd(&cursor[s], 1);
    rowlist[pos] = i;
  }
}

__global__ __launch_bounds__(256) void k_cluster_sum(const float* __restrict__ features,
                                                     const int* __restrict__ rowlist,
                                                     const int* __restrict__ offs,
                                                     float* __restrict__ submean,
                                                     float* __restrict__ simm,
                                                     float* __restrict__ nums) {
  int s = blockIdx.x;
  int t = threadIdx.x;
  int start = offs[s], end = offs[s + 1];
  float acc[8] = {0, 0, 0, 0, 0, 0, 0, 0};
  for (int r = start; r < end; r++) {
    const float* row = features + (size_t)rowlist[r] * DIM + t * 8;
    float4 v0 = *(const float4*)(row);
    float4 v1 = *(const float4*)(row + 4);
    acc[0] += v0.x; acc[1] += v0.y; acc[2] += v0.z; acc[3] += v0.w;
    acc[4] += v1.x; acc[5] += v1.y; acc[6] += v1.z; acc[7] += v1.w;
  }
  int cnt = end - start;
  float inv = 1.0f / (float)(cnt > 0 ? cnt : 1);
  float m[8];
  float ss = 0.f;
#pragma unroll
  for (int i = 0; i < 8; i++) { m[i] = acc[i] * inv; ss += m[i] * m[i]; }
  float* outp = submean + (size_t)s * DIM + t * 8;
  *(float4*)(outp)     = make_float4(m[0], m[1], m[2], m[3]);
  *(float4*)(outp + 4) = make_float4(m[4], m[5], m[6], m[7]);
  __shared__ float red[256];
  red[t] = ss;
  __syncthreads();
  for (int s2 = 128; s2 > 0; s2 >>= 1) {
    if (t < s2) red[t] += red[t + s2];
    __syncthreads();
  }
  if (t == 0) {
    simm[s] = red[0];
    nums[s] = (float)cnt;
  }
}

__global__ __launch_bounds__(256) void k_prep(const int* __restrict__ indexes,
                                              const float* __restrict__ features,
                                              const int* __restrict__ sub_label,
                                              const int* __restrict__ knn,
                                              const float* __restrict__ simm,
                                              int* __restrict__ sublabs,
                                              float* __restrict__ norms) {
  int b = blockIdx.x;
  int t = threadIdx.x;
  const float* row = features + (size_t)indexes[b] * DIM;
  float ss = 0.f;
  for (int i = t; i < DIM; i += 256) {
    float v = row[i];
    ss += v * v;
  }
  __shared__ float red[256];
  red[t] = ss;
  __syncthreads();
  for (int s2 = 128; s2 > 0; s2 >>= 1) {
    if (t < s2) red[t] += red[t + s2];
    __syncthreads();
  }
  __shared__ float n0s;
  if (t == 0) n0s = sqrtf(red[0]);
  __syncthreads();
  if (t < KK) {
    int sl = sub_label[knn[b * KK + t]];
    sublabs[b * KK + t] = sl;
    norms[b * KK + t] = (t == 0) ? n0s : sqrtf(simm[sl]);
  }
}

// ------------------------ gram + weight + softmax ---------------------------
__global__ __launch_bounds__(256) void k_gram(const int* __restrict__ indexes,
                                              const float* __restrict__ features,
                                              const float* __restrict__ submean,
                                              const int* __restrict__ sublabs,
                                              const float* __restrict__ all_pred,
                                              float* __restrict__ A) {
  int b = blockIdx.x;
  int t = threadIdx.x;
  __shared__ float tileT[128][68];
  __shared__ const float* rowp[KK];
  __shared__ float wj[KK];
  if (t < KK) {
    rowp[t] = (t == 0) ? (features + (size_t)indexes[b] * DIM)
                       : (submean + (size_t)sublabs[b * KK + t] * DIM);
    wj[t] = expf(all_pred[(size_t)(b * KK + t) * 2 + 1]);
  }
  __syncthreads();

  const int k = t >> 2;
  const int jg = (t & 3) * 16;
  float acc[16];
#pragma unroll
  for (int i = 0; i < 16; i++) acc[i] = 0.f;

  for (int c = 0; c < 16; c++) {
    int dc = c * 128;
#pragma unroll
    for (int i = 0; i < 8; i++) {
      int v = t + 256 * i;
      int kr = v >> 5;
      int d4 = v & 31;
      float4 f = *(const float4*)(rowp[kr] + dc + d4 * 4);
      int dl = d4 * 4;
      tileT[dl + 0][kr] = f.x;
      tileT[dl + 1][kr] = f.y;
      tileT[dl + 2][kr] = f.z;
      tileT[dl + 3][kr] = f.w;
    }
    __syncthreads();
#pragma unroll 4
    for (int d = 0; d < 128; d++) {
      float a = tileT[d][k];
      float4 b0 = *(const float4*)&tileT[d][jg + 0];
      float4 b1 = *(const float4*)&tileT[d][jg + 4];
      float4 b2 = *(const float4*)&tileT[d][jg + 8];
      float4 b3 = *(const float4*)&tileT[d][jg + 12];
      acc[0] += a * b0.x;  acc[1] += a * b0.y;  acc[2] += a * b0.z;  acc[3] += a * b0.w;
      acc[4] += a * b1.x;  acc[5] += a * b1.y;  acc[6] += a * b1.z;  acc[7] += a * b1.w;
      acc[8] += a * b2.x;  acc[9] += a * b2.y;  acc[10] += a * b2.z; acc[11] += a * b2.w;
      acc[12] += a * b3.x; acc[13] += a * b3.y; acc[14] += a * b3.z; acc[15] += a * b3.w;
    }
    __syncthreads();
  }

  float sv[16];
  float mx = -1e30f;
#pragma unroll
  for (int j = 0; j < 16; j++) {
    sv[j] = acc[j] * wj[jg + j];
    mx = fmaxf(mx, sv[j]);
  }
  mx = fmaxf(mx, __shfl_xor(mx, 1));
  mx = fmaxf(mx, __shfl_xor(mx, 2));
  float sum = 0.f;
#pragma unroll
  for (int j = 0; j < 16; j++) {
    sv[j] = expf(sv[j] - mx);
    sum += sv[j];
  }
  sum += __shfl_xor(sum, 1);
  sum += __shfl_xor(sum, 2);
  float inv = 1.0f / sum;
  float* outp = A + ((size_t)b * KK + k) * KK + jg;
  *(float4*)(outp + 0)  = make_float4(sv[0] * inv, sv[1] * inv, sv[2] * inv, sv[3] * inv);
  *(float4*)(outp + 4)  = make_float4(sv[4] * inv, sv[5] * inv, sv[6] * inv, sv[7] * inv);
  *(float4*)(outp + 8)  = make_float4(sv[8] * inv, sv[9] * inv, sv[10] * inv, sv[11] * inv);
  *(float4*)(outp + 12) = make_float4(sv[12] * inv, sv[13] * inv, sv[14] * inv, sv[15] * inv);
}

// ------------------------------ x normalize (bf16 out) ----------------------
__global__ __launch_bounds__(256) void k_xnorm(const int* __restrict__ indexes,
                                               const float* __restrict__ features,
                                               const float* __restrict__ submean,
                                               const int* __restrict__ sublabs,
                                               const float* __restrict__ norms,
                                               unsigned short* __restrict__ xn) {
  int b = blockIdx.y;
  int d = blockIdx.x * 256 + threadIdx.x;
  int t = threadIdx.x;
  __shared__ float ninv[KK];
  __shared__ int sl[KK];
  if (t < KK) {
    ninv[t] = 1.0f / norms[b * KK + t];
    sl[t] = sublabs[b * KK + t];
  }
  __syncthreads();
  float f0 = features[(size_t)indexes[b] * DIM + d];
  float r0 = f0 * ninv[0];
#pragma unroll 4
  for (int kk = 0; kk < KK; kk++) {
    float val = (kk == 0) ? f0 : submean[(size_t)sl[kk] * DIM + d];
    xn[((size_t)b * KK + kk) * DIM + d] = f2bf(val * ninv[kk] - r0);
  }
}

// ------------------------------- agg = A @ X (bf16) -------------------------
template <int DD>
__global__ __launch_bounds__(256) void k_agg(const float* __restrict__ A,
                                             const unsigned short* __restrict__ X,
                                             unsigned short* __restrict__ out) {
  int b = blockIdx.y;
  int d = blockIdx.x * 256 + threadIdx.x;
  int t = threadIdx.x;
  __shared__ float At[KK][68];
#pragma unroll
  for (int i = 0; i < 16; i++) {
    int v = t + 256 * i;
    int kr = v >> 6;
    int j = v & 63;
    At[j][kr] = A[((size_t)b * KK + kr) * KK + j];
  }
  __syncthreads();
  float acc[KK];
#pragma unroll
  for (int i = 0; i < KK; i++) acc[i] = 0.f;
#pragma unroll 4
  for (int j = 0; j < KK; j++) {
    float xv = bf2f(X[((size_t)b * KK + j) * DD + d]);
#pragma unroll
    for (int k4 = 0; k4 < 16; k4++) {
      float4 a = *(const float4*)&At[j][k4 * 4];
      acc[k4 * 4 + 0] += a.x * xv;
      acc[k4 * 4 + 1] += a.y * xv;
      acc[k4 * 4 + 2] += a.z * xv;
      acc[k4 * 4 + 3] += a.w * xv;
    }
  }
#pragma unroll
  for (int kk = 0; kk < KK; kk++)
    out[((size_t)b * KK + kk) * DD + d] = f2bf(acc[kk]);
}

// ---------------------- W [K][N] f32 -> Wt [N][K] bf16 ----------------------
__global__ __launch_bounds__(256) void k_wt(const float* __restrict__ W,
                                            unsigned short* __restrict__ Wt,
                                            int Kdim, int Ndim) {
  __shared__ float tile[32][33];
  int n0 = blockIdx.x * 32, k0 = blockIdx.y * 32;
  int c = threadIdx.x & 31, r8 = threadIdx.x >> 5;
#pragma unroll
  for (int i = 0; i < 4; i++) {
    int r = r8 + i * 8;
    tile[r][c] = W[(size_t)(k0 + r) * Ndim + n0 + c];
  }
  __syncthreads();
#pragma unroll
  for (int i = 0; i < 4; i++) {
    int r = r8 + i * 8;
    Wt[(size_t)(n0 + r) * Kdim + k0 + c] = f2bf(tile[c][r]);
  }
}

// ------------- MFMA GEMM: C = relu(cat(Xa,Xb) @ Wt^T + bias) ----------------
// Xa,Xb bf16 [M][KHALF]; Wt bf16 [NTOT][2*KHALF]; 128x128 tile, BK=64, 4 waves.
// T2 swizzle: linear LDS dest, pre-swizzled global source, swizzled ds_read.
template <int KHALF, int NTOT, bool OUTBF>
__global__ __launch_bounds__(256) void k_mfma_gemm(const unsigned short* __restrict__ Xa,
                                                   const unsigned short* __restrict__ Xb,
                                                   const unsigned short* __restrict__ Wt,
                                                   const float* __restrict__ bias,
                                                   void* __restrict__ outp) {
  constexpr int KTOT = 2 * KHALF;
  const int tid = threadIdx.x;
  const int w = tid >> 6, lane = tid & 63;
  const int mt = blockIdx.x * 128, nt = blockIdx.y * 128;
  __shared__ unsigned short As[128 * 64];
  __shared__ unsigned short Bs[128 * 64];

  f32x4 acc[4][4];
#pragma unroll
  for (int m = 0; m < 4; m++)
#pragma unroll
    for (int n = 0; n < 4; n++) acc[m][n] = (f32x4){0.f, 0.f, 0.f, 0.f};

  const int wr = w >> 1, wc = w & 1;
  const int lr = lane & 15, kg = lane >> 4;

  for (int kc = 0; kc < KTOT / 64; kc++) {
    const int k0 = kc * 64;
    const unsigned short* srcA;
    int koff;
    if (k0 < KHALF) { srcA = Xa; koff = k0; }
    else            { srcA = Xb; koff = k0 - KHALF; }
#pragma unroll
    for (int i = 0; i < 4; i++) {
      int q = (w * 4 + i) * 64 + lane;        // 16B-chunk id in [0,1024)
      int r = q >> 3;                          // tile row
      int cl = (q & 7) ^ (r & 7);              // logical chunk (pre-swizzle)
      __builtin_amdgcn_global_load_lds(
          (const __attribute__((address_space(1))) void*)(srcA + (size_t)(mt + r) * KHALF + koff + cl * 8),
          (__attribute__((address_space(3))) void*)(As + (w * 4 + i) * 512), 16, 0, 0);
    }
#pragma unroll
    for (int i = 0; i < 4; i++) {
      int q = (w * 4 + i) * 64 + lane;
      int r = q >> 3;
      int cl = (q & 7) ^ (r & 7);
      __builtin_amdgcn_global_load_lds(
          (const __attribute__((address_space(1))) void*)(Wt + (size_t)(nt + r) * KTOT + k0 + cl * 8),
          (__attribute__((address_space(3))) void*)(Bs + (w * 4 + i) * 512), 16, 0, 0);
    }
    __syncthreads();
#pragma unroll
    for (int ks = 0; ks < 2; ks++) {
      bf16x8 af[4], bfr[4];
      const int ch = ks * 4 + kg;
#pragma unroll
      for (int m = 0; m < 4; m++) {
        int row = wr * 64 + m * 16 + lr;
        af[m] = *(const bf16x8*)&As[row * 64 + ((ch ^ (row & 7)) << 3)];
      }
#pragma unroll
      for (int n = 0; n < 4; n++) {
        int row = wc * 64 + n * 16 + lr;
        bfr[n] = *(const bf16x8*)&Bs[row * 64 + ((ch ^ (row & 7)) << 3)];
      }
#pragma unroll
      for (int m = 0; m < 4; m++)
#pragma unroll
        for (int n = 0; n < 4; n++)
          acc[m][n] = __builtin_amdgcn_mfma_f32_16x16x32_bf16(af[m], bfr[n], acc[m][n], 0, 0, 0);
    }
    __syncthreads();
  }

#pragma unroll
  for (int m = 0; m < 4; m++) {
    int rm = mt + wr * 64 + m * 16 + kg * 4;
#pragma unroll
    for (int n = 0; n < 4; n++) {
      int col = nt + wc * 64 + n * 16 + lr;
      float bv = bias[col];
#pragma unroll
      for (int j = 0; j < 4; j++) {
        float v = fmaxf(acc[m][n][j] + bv, 0.f);
        if (OUTBF)
          ((unsigned short*)outp)[(size_t)(rm + j) * NTOT + col] = f2bf(v);
        else
          ((float*)outp)[(size_t)(rm + j) * NTOT + col] = v;
      }
    }
  }
}

// --------------- classifier: h=x2@Wc1+bc1, PReLU, @Wc2+bc2, softmax ---------
__global__ __launch_bounds__(256) void k_cls(const float* __restrict__ x2,
                                             const float* __restrict__ Wc1,
                                             const float* __restrict__ bc1,
                                             const float* __restrict__ pa,
                                             const float* __restrict__ Wc2,
                                             const float* __restrict__ bc2,
                                             float* __restrict__ probs) {
  int mt = blockIdx.x * 64;
  int t = threadIdx.x;
  __shared__ float Ws[32][260];
  __shared__ float As[32][68];
  float h[64];
#pragma unroll
  for (int i = 0; i < 64; i++) h[i] = 0.f;
  const int r = t >> 2;
  const int cg = (t & 3) * 64;
  for (int kc = 0; kc < 8; kc++) {
    int k0 = kc * 32;
#pragma unroll
    for (int i = 0; i < 2; i++) {
      int v = t + 256 * i;
      int m = v >> 3, k4 = v & 7;
      float4 f = *(const float4*)(x2 + (size_t)(mt + m) * DOUT + k0 + k4 * 4);
      As[k4 * 4 + 0][m] = f.x;
      As[k4 * 4 + 1][m] = f.y;
      As[k4 * 4 + 2][m] = f.z;
      As[k4 * 4 + 3][m] = f.w;
    }
#pragma unroll
    for (int i = 0; i < 8; i++) {
      int v = t + 256 * i;
      int kkr = v >> 6, c4 = v & 63;
      *(float4*)&Ws[kkr][c4 * 4] =
          *(const float4*)(Wc1 + (size_t)(k0 + kkr) * DOUT + c4 * 4);
    }
    __syncthreads();
    for (int kk = 0; kk < 32; kk++) {
      float a = As[kk][r];
#pragma unroll
      for (int c4 = 0; c4 < 16; c4++) {
        float4 w = *(const float4*)&Ws[kk][cg + c4 * 4];
        h[c4 * 4 + 0] += a * w.x;
        h[c4 * 4 + 1] += a * w.y;
        h[c4 * 4 + 2] += a * w.z;
        h[c4 * 4 + 3] += a * w.w;
      }
    }
    __syncthreads();
  }
  float l0 = 0.f, l1 = 0.f;
#pragma unroll 8
  for (int j = 0; j < 64; j++) {
    int c = cg + j;
    float v = h[j] + bc1[c];
    v = (v >= 0.f) ? v : pa[c] * v;
    l0 += v * Wc2[c * 2 + 0];
    l1 += v * Wc2[c * 2 + 1];
  }
  l0 += __shfl_xor(l0, 1);
  l0 += __shfl_xor(l0, 2);
  l1 += __shfl_xor(l1, 1);
  l1 += __shfl_xor(l1, 2);
  if ((t & 3) == 0) {
    l0 += bc2[0];
    l1 += bc2[1];
    float m = fmaxf(l0, l1);
    float e0 = expf(l0 - m), e1 = expf(l1 - m);
    float inv = 1.0f / (e0 + e1);
    int row = mt + r;
    *(float2*)(probs + (size_t)row * 2) = make_float2(e0 * inv, e1 * inv);
  }
}

// ---------------------------------------------------------------------------

extern "C" void kernel_launch(void* const* d_in, const int* in_sizes, int n_in,
                              void* d_out, int out_size, void* d_ws, size_t ws_size,
                              hipStream_t stream) {
  const int* indexes = (const int*)d_in[0];
  const float* features = (const float*)d_in[1];
  const int* sub_label = (const int*)d_in[3];
  const int* knn = (const int*)d_in[6];
  const float* all_pred = (const float*)d_in[7];
  const float* W1 = (const float*)d_in[9];
  const float* b1 = (const float*)d_in[10];
  const float* W2 = (const float*)d_in[11];
  const float* b2 = (const float*)d_in[12];
  const float* Wc1 = (const float*)d_in[13];
  const float* bc1 = (const float*)d_in[14];
  const float* pa = (const float*)d_in[15];
  const float* Wc2 = (const float*)d_in[16];
  const float* bc2 = (const float*)d_in[17];

  float* out = (float*)d_out;
  float* probs = out;                    // [B*K*2]
  float* simm = out + 32768;             // [2000]
  float* submean = out + 34768;          // [2000*2048]
  float* nums = out + 4130768;           // [2000]

  // ---- workspace layout (bytes) ----
  char* ws = (char*)d_ws;
  size_t off = 0;
  unsigned short* xnorm_bf = (unsigned short*)(ws + off); off += (size_t)BB * KK * DIM * 2;   // 67MB
  unsigned short* agg1_bf  = (unsigned short*)(ws + off); off += (size_t)BB * KK * DIM * 2;   // 67MB
  unsigned short* x1_bf    = (unsigned short*)(ws + off); off += (size_t)BB * KK * NHID * 2;  // 16.8MB
  unsigned short* agg2_bf  = (unsigned short*)(ws + off); off += (size_t)BB * KK * NHID * 2;  // 16.8MB
  unsigned short* W1t      = (unsigned short*)(ws + off); off += (size_t)NHID * 2 * DIM * 2;  // 4MB
  unsigned short* W2t      = (unsigned short*)(ws + off); off += (size_t)DOUT * 2 * NHID * 2; // 0.5MB
  float* x2   = (float*)(ws + off); off += (size_t)BB * KK * DOUT * 4;                        // 16.8MB
  float* Abuf = (float*)(ws + off); off += (size_t)BB * KK * KK * 4;                          // 4MB
  int* cnt    = (int*)(ws + off); off += NSUB * 4;
  int* cursor = (int*)(ws + off); off += NSUB * 4;
  int* offs   = (int*)(ws + off); off += (NSUB + 4) * 4;
  int* rowlist = (int*)(ws + off); off += (NROW + 8) * 4;
  int* sublabs = (int*)(ws + off); off += (size_t)BB * KK * 4;
  float* norms = (float*)(ws + off); off += (size_t)BB * KK * 4;

  hipMemsetAsync(cnt, 0, 2 * NSUB * sizeof(int), stream);

  const int nrb = (NROW + 255) / 256;
  k_count<<<nrb, 256, 0, stream>>>(sub_label, cnt);
  k_scan<<<1, 256, 0, stream>>>(cnt, offs, cursor);
  k_scatter<<<nrb, 256, 0, stream>>>(sub_label, cursor, rowlist);
  k_cluster_sum<<<NSUB, 256, 0, stream>>>(features, rowlist, offs, submean, simm, nums);
  k_prep<<<BB, 256, 0, stream>>>(indexes, features, sub_label, knn, simm, sublabs, norms);
  k_gram<<<BB, 256, 0, stream>>>(indexes, features, submean, sublabs, all_pred, Abuf);

  // weight transpose-casts (independent; cheap)
  k_wt<<<dim3(NHID / 32, (2 * DIM) / 32), 256, 0, stream>>>(W1, W1t, 2 * DIM, NHID);
  k_wt<<<dim3(DOUT / 32, (2 * NHID) / 32), 256, 0, stream>>>(W2, W2t, 2 * NHID, DOUT);

  dim3 g8(8, BB);
  k_xnorm<<<g8, 256, 0, stream>>>(indexes, features, submean, sublabs, norms, xnorm_bf);
  k_agg<DIM><<<g8, 256, 0, stream>>>(Abuf, xnorm_bf, agg1_bf);
  k_mfma_gemm<DIM, NHID, true><<<dim3(128, NHID / 128), 256, 0, stream>>>(
      xnorm_bf, agg1_bf, W1t, b1, (void*)x1_bf);
  k_agg<NHID><<<dim3(NHID / 256, BB), 256, 0, stream>>>(Abuf, x1_bf, agg2_bf);
  k_mfma_gemm<NHID, DOUT, false><<<dim3(128, DOUT / 128), 256, 0, stream>>>(
      x1_bf, agg2_bf, W2t, b2, (void*)x2);
  k_cls<<<BB, 256, 0, stream>>>(x2, Wc1, bc1, pa, Wc2, bc2, probs);
}

// Round 3
// 481.171 us; speedup vs baseline: 3.4465x; 1.4284x over previous
//
#include <hip/hip_runtime.h>
#include <hip/hip_bf16.h>

// ---------------------------------------------------------------------------
// Sub_Cluster_Level_GCN — round 2:
//   * algebraic reorder: cat(x,A@x)@W  ->  Z = x@[Wa|Wb]; out = relu(Za + A@Zb + b)
//     (removes both agg passes and their 134MB round-trips)
//   * classifier on MFMA (bf16) with PReLU epilogue + tiny softmax pass
// ---------------------------------------------------------------------------

#define NROW 50000
#define DIM  2048
#define NSUB 2000
#define BB   256
#define KK   64
#define NHID 512
#define DOUT 256
#define MM   (BB * KK)   // 16384 rows

typedef __attribute__((ext_vector_type(8))) short bf16x8;
typedef __attribute__((ext_vector_type(4))) float f32x4;

__device__ __forceinline__ unsigned short f2bf(float f) {
  union { float f; unsigned u; } v; v.f = f;
  unsigned r = v.u + 0x7FFF + ((v.u >> 16) & 1);
  return (unsigned short)(r >> 16);
}
__device__ __forceinline__ float bf2f(unsigned short h) {
  union { unsigned u; float f; } v; v.u = ((unsigned)h) << 16;
  return v.f;
}

// ------------------------- segment-mean path -------------------------------

__global__ __launch_bounds__(256) void k_count(const int* __restrict__ sub_label,
                                               int* __restrict__ cnt) {
  int i = blockIdx.x * 256 + threadIdx.x;
  if (i < NROW) atomicAdd(&cnt[sub_label[i]], 1);
}

__global__ __launch_bounds__(256) void k_scan(const int* __restrict__ cnt,
                                              int* __restrict__ offs,
                                              int* __restrict__ cursor) {
  __shared__ int part[256];
  int t = threadIdx.x;
  int base = t * 8;
  int local[8];
  int sum = 0;
#pragma unroll
  for (int i = 0; i < 8; i++) {
    int v = (base + i < NSUB) ? cnt[base + i] : 0;
    local[i] = sum;
    sum += v;
  }
  part[t] = sum;
  __syncthreads();
  for (int off = 1; off < 256; off <<= 1) {
    int v = (t >= off) ? part[t - off] : 0;
    __syncthreads();
    part[t] += v;
    __syncthreads();
  }
  int pre = (t == 0) ? 0 : part[t - 1];
#pragma unroll
  for (int i = 0; i < 8; i++) {
    if (base + i < NSUB) {
      int o = pre + local[i];
      offs[base + i] = o;
      cursor[base + i] = o;
    }
  }
  if (t == 255) offs[NSUB] = pre + sum;
}

__global__ __launch_bounds__(256) void k_scatter(const int* __restrict__ sub_label,
                                                 int* __restrict__ cursor,
                                                 int* __restrict__ rowlist) {
  int i = blockIdx.x * 256 + threadIdx.x;
  if (i < NROW) {
    int s = sub_label[i];
    int pos = atomicAdd(&cursor[s], 1);
    rowlist[pos] = i;
  }
}

__global__ __launch_bounds__(256) void k_cluster_sum(const float* __restrict__ features,
                                                     const int* __restrict__ rowlist,
                                                     const int* __restrict__ offs,
                                                     float* __restrict__ submean,
                                                     float* __restrict__ simm,
                                                     float* __restrict__ nums) {
  int s = blockIdx.x;
  int t = threadIdx.x;
  int start = offs[s], end = offs[s + 1];
  float acc[8] = {0, 0, 0, 0, 0, 0, 0, 0};
  int r = start;
  // 2-row unroll for more loads in flight
  for (; r + 1 < end; r += 2) {
    const float* rowA = features + (size_t)rowlist[r] * DIM + t * 8;
    const float* rowB = features + (size_t)rowlist[r + 1] * DIM + t * 8;
    float4 a0 = *(const float4*)(rowA);
    float4 a1 = *(const float4*)(rowA + 4);
    float4 b0 = *(const float4*)(rowB);
    float4 b1 = *(const float4*)(rowB + 4);
    acc[0] += a0.x + b0.x; acc[1] += a0.y + b0.y;
    acc[2] += a0.z + b0.z; acc[3] += a0.w + b0.w;
    acc[4] += a1.x + b1.x; acc[5] += a1.y + b1.y;
    acc[6] += a1.z + b1.z; acc[7] += a1.w + b1.w;
  }
  if (r < end) {
    const float* row = features + (size_t)rowlist[r] * DIM + t * 8;
    float4 v0 = *(const float4*)(row);
    float4 v1 = *(const float4*)(row + 4);
    acc[0] += v0.x; acc[1] += v0.y; acc[2] += v0.z; acc[3] += v0.w;
    acc[4] += v1.x; acc[5] += v1.y; acc[6] += v1.z; acc[7] += v1.w;
  }
  int cnt = end - start;
  float inv = 1.0f / (float)(cnt > 0 ? cnt : 1);
  float m[8];
  float ss = 0.f;
#pragma unroll
  for (int i = 0; i < 8; i++) { m[i] = acc[i] * inv; ss += m[i] * m[i]; }
  float* outp = submean + (size_t)s * DIM + t * 8;
  *(float4*)(outp)     = make_float4(m[0], m[1], m[2], m[3]);
  *(float4*)(outp + 4) = make_float4(m[4], m[5], m[6], m[7]);
  __shared__ float red[256];
  red[t] = ss;
  __syncthreads();
  for (int s2 = 128; s2 > 0; s2 >>= 1) {
    if (t < s2) red[t] += red[t + s2];
    __syncthreads();
  }
  if (t == 0) {
    simm[s] = red[0];
    nums[s] = (float)cnt;
  }
}

__global__ __launch_bounds__(256) void k_prep(const int* __restrict__ indexes,
                                              const float* __restrict__ features,
                                              const int* __restrict__ sub_label,
                                              const int* __restrict__ knn,
                                              const float* __restrict__ simm,
                                              int* __restrict__ sublabs,
                                              float* __restrict__ norms) {
  int b = blockIdx.x;
  int t = threadIdx.x;
  const float* row = features + (size_t)indexes[b] * DIM;
  float ss = 0.f;
  for (int i = t; i < DIM; i += 256) {
    float v = row[i];
    ss += v * v;
  }
  __shared__ float red[256];
  red[t] = ss;
  __syncthreads();
  for (int s2 = 128; s2 > 0; s2 >>= 1) {
    if (t < s2) red[t] += red[t + s2];
    __syncthreads();
  }
  __shared__ float n0s;
  if (t == 0) n0s = sqrtf(red[0]);
  __syncthreads();
  if (t < KK) {
    int sl = sub_label[knn[b * KK + t]];
    sublabs[b * KK + t] = sl;
    norms[b * KK + t] = (t == 0) ? n0s : sqrtf(simm[sl]);
  }
}

// ------------------------ gram + weight + softmax ---------------------------
__global__ __launch_bounds__(256) void k_gram(const int* __restrict__ indexes,
                                              const float* __restrict__ features,
                                              const float* __restrict__ submean,
                                              const int* __restrict__ sublabs,
                                              const float* __restrict__ all_pred,
                                              float* __restrict__ A) {
  int b = blockIdx.x;
  int t = threadIdx.x;
  __shared__ float tileT[128][68];
  __shared__ const float* rowp[KK];
  __shared__ float wj[KK];
  if (t < KK) {
    rowp[t] = (t == 0) ? (features + (size_t)indexes[b] * DIM)
                       : (submean + (size_t)sublabs[b * KK + t] * DIM);
    wj[t] = expf(all_pred[(size_t)(b * KK + t) * 2 + 1]);
  }
  __syncthreads();

  const int k = t >> 2;
  const int jg = (t & 3) * 16;
  float acc[16];
#pragma unroll
  for (int i = 0; i < 16; i++) acc[i] = 0.f;

  for (int c = 0; c < 16; c++) {
    int dc = c * 128;
#pragma unroll
    for (int i = 0; i < 8; i++) {
      int v = t + 256 * i;
      int kr = v >> 5;
      int d4 = v & 31;
      float4 f = *(const float4*)(rowp[kr] + dc + d4 * 4);
      int dl = d4 * 4;
      tileT[dl + 0][kr] = f.x;
      tileT[dl + 1][kr] = f.y;
      tileT[dl + 2][kr] = f.z;
      tileT[dl + 3][kr] = f.w;
    }
    __syncthreads();
#pragma unroll 4
    for (int d = 0; d < 128; d++) {
      float a = tileT[d][k];
      float4 b0 = *(const float4*)&tileT[d][jg + 0];
      float4 b1 = *(const float4*)&tileT[d][jg + 4];
      float4 b2 = *(const float4*)&tileT[d][jg + 8];
      float4 b3 = *(const float4*)&tileT[d][jg + 12];
      acc[0] += a * b0.x;  acc[1] += a * b0.y;  acc[2] += a * b0.z;  acc[3] += a * b0.w;
      acc[4] += a * b1.x;  acc[5] += a * b1.y;  acc[6] += a * b1.z;  acc[7] += a * b1.w;
      acc[8] += a * b2.x;  acc[9] += a * b2.y;  acc[10] += a * b2.z; acc[11] += a * b2.w;
      acc[12] += a * b3.x; acc[13] += a * b3.y; acc[14] += a * b3.z; acc[15] += a * b3.w;
    }
    __syncthreads();
  }

  float sv[16];
  float mx = -1e30f;
#pragma unroll
  for (int j = 0; j < 16; j++) {
    sv[j] = acc[j] * wj[jg + j];
    mx = fmaxf(mx, sv[j]);
  }
  mx = fmaxf(mx, __shfl_xor(mx, 1));
  mx = fmaxf(mx, __shfl_xor(mx, 2));
  float sum = 0.f;
#pragma unroll
  for (int j = 0; j < 16; j++) {
    sv[j] = expf(sv[j] - mx);
    sum += sv[j];
  }
  sum += __shfl_xor(sum, 1);
  sum += __shfl_xor(sum, 2);
  float inv = 1.0f / sum;
  float* outp = A + ((size_t)b * KK + k) * KK + jg;
  *(float4*)(outp + 0)  = make_float4(sv[0] * inv, sv[1] * inv, sv[2] * inv, sv[3] * inv);
  *(float4*)(outp + 4)  = make_float4(sv[4] * inv, sv[5] * inv, sv[6] * inv, sv[7] * inv);
  *(float4*)(outp + 8)  = make_float4(sv[8] * inv, sv[9] * inv, sv[10] * inv, sv[11] * inv);
  *(float4*)(outp + 12) = make_float4(sv[12] * inv, sv[13] * inv, sv[14] * inv, sv[15] * inv);
}

// ------------------------------ x normalize (bf16 out) ----------------------
__global__ __launch_bounds__(256) void k_xnorm(const int* __restrict__ indexes,
                                               const float* __restrict__ features,
                                               const float* __restrict__ submean,
                                               const int* __restrict__ sublabs,
                                               const float* __restrict__ norms,
                                               unsigned short* __restrict__ xn) {
  int b = blockIdx.y;
  int d = blockIdx.x * 256 + threadIdx.x;
  int t = threadIdx.x;
  __shared__ float ninv[KK];
  __shared__ int sl[KK];
  if (t < KK) {
    ninv[t] = 1.0f / norms[b * KK + t];
    sl[t] = sublabs[b * KK + t];
  }
  __syncthreads();
  float f0 = features[(size_t)indexes[b] * DIM + d];
  float r0 = f0 * ninv[0];
#pragma unroll 4
  for (int kk = 0; kk < KK; kk++) {
    float val = (kk == 0) ? f0 : submean[(size_t)sl[kk] * DIM + d];
    xn[((size_t)b * KK + kk) * DIM + d] = f2bf(val * ninv[kk] - r0);
  }
}

// -------------- W[k][n] (f32, row-stride Nsrc) -> Wt[n][k] (bf16) -----------
__global__ __launch_bounds__(256) void k_wt(const float* __restrict__ W,
                                            unsigned short* __restrict__ Wt,
                                            int Nsrc, int KTOT) {
  __shared__ float tile[32][33];
  int n0 = blockIdx.x * 32, k0 = blockIdx.y * 32;
  int c = threadIdx.x & 31, r8 = threadIdx.x >> 5;
#pragma unroll
  for (int i = 0; i < 4; i++) {
    int r = r8 + i * 8;
    tile[r][c] = W[(size_t)(k0 + r) * Nsrc + n0 + c];
  }
  __syncthreads();
#pragma unroll
  for (int i = 0; i < 4; i++) {
    int r = r8 + i * 8;
    Wt[(size_t)(n0 + r) * KTOT + k0 + c] = f2bf(tile[c][r]);
  }
}

// -------------- MFMA GEMM: C = epi(X @ Wt^T) ; X[M][KTOT], Wt[NTOT][KTOT] ---
// 128x128 tile, BK=64, 4 waves; T2 swizzle (linear LDS dest, pre-swizzled
// global source, swizzled ds_read). EPI: 0 = raw bf16; 1 = bias+PReLU bf16.
template <int KTOT, int NTOT, int EPI>
__global__ __launch_bounds__(256) void k_gemm_bt(const unsigned short* __restrict__ X,
                                                 const unsigned short* __restrict__ Wt,
                                                 const float* __restrict__ bias,
                                                 const float* __restrict__ pa,
                                                 unsigned short* __restrict__ out) {
  const int tid = threadIdx.x;
  const int w = tid >> 6, lane = tid & 63;
  const int nt = blockIdx.x * 128, mt = blockIdx.y * 128;
  __shared__ unsigned short As[128 * 64];
  __shared__ unsigned short Bs[128 * 64];

  f32x4 acc[4][4];
#pragma unroll
  for (int m = 0; m < 4; m++)
#pragma unroll
    for (int n = 0; n < 4; n++) acc[m][n] = (f32x4){0.f, 0.f, 0.f, 0.f};

  const int wr = w >> 1, wc = w & 1;
  const int lr = lane & 15, kg = lane >> 4;

  for (int kc = 0; kc < KTOT / 64; kc++) {
    const int k0 = kc * 64;
#pragma unroll
    for (int i = 0; i < 4; i++) {
      int q = (w * 4 + i) * 64 + lane;   // 16B-chunk id in [0,1024)
      int r = q >> 3;                     // tile row
      int cl = (q & 7) ^ (r & 7);         // pre-swizzled source chunk
      __builtin_amdgcn_global_load_lds(
          (const __attribute__((address_space(1))) void*)(X + (size_t)(mt + r) * KTOT + k0 + cl * 8),
          (__attribute__((address_space(3))) void*)(As + (w * 4 + i) * 512), 16, 0, 0);
    }
#pragma unroll
    for (int i = 0; i < 4; i++) {
      int q = (w * 4 + i) * 64 + lane;
      int r = q >> 3;
      int cl = (q & 7) ^ (r & 7);
      __builtin_amdgcn_global_load_lds(
          (const __attribute__((address_space(1))) void*)(Wt + (size_t)(nt + r) * KTOT + k0 + cl * 8),
          (__attribute__((address_space(3))) void*)(Bs + (w * 4 + i) * 512), 16, 0, 0);
    }
    __syncthreads();
#pragma unroll
    for (int ks = 0; ks < 2; ks++) {
      bf16x8 af[4], bfr[4];
      const int ch = ks * 4 + kg;
#pragma unroll
      for (int m = 0; m < 4; m++) {
        int row = wr * 64 + m * 16 + lr;
        af[m] = *(const bf16x8*)&As[row * 64 + ((ch ^ (row & 7)) << 3)];
      }
#pragma unroll
      for (int n = 0; n < 4; n++) {
        int row = wc * 64 + n * 16 + lr;
        bfr[n] = *(const bf16x8*)&Bs[row * 64 + ((ch ^ (row & 7)) << 3)];
      }
#pragma unroll
      for (int m = 0; m < 4; m++)
#pragma unroll
        for (int n = 0; n < 4; n++)
          acc[m][n] = __builtin_amdgcn_mfma_f32_16x16x32_bf16(af[m], bfr[n], acc[m][n], 0, 0, 0);
    }
    __syncthreads();
  }

#pragma unroll
  for (int m = 0; m < 4; m++) {
    int rm = mt + wr * 64 + m * 16 + kg * 4;
#pragma unroll
    for (int n = 0; n < 4; n++) {
      int col = nt + wc * 64 + n * 16 + lr;
      float bv = (EPI == 1) ? bias[col] : 0.f;
      float av = (EPI == 1) ? pa[col] : 0.f;
#pragma unroll
      for (int j = 0; j < 4; j++) {
        float v = acc[m][n][j];
        if (EPI == 1) {
          v += bv;
          v = (v >= 0.f) ? v : av * v;
        }
        out[(size_t)(rm + j) * NTOT + col] = f2bf(v);
      }
    }
  }
}

// -------- combine: out = relu(Za + A@Zb + bias), per-sample small GEMM ------
// Z [MM][2*DD] bf16 (Za = cols 0..DD-1, Zb = cols DD..2DD-1); out bf16 [MM][DD]
template <int DD>
__global__ __launch_bounds__(256) void k_combine(const float* __restrict__ A,
                                                 const unsigned short* __restrict__ Z,
                                                 const float* __restrict__ bias,
                                                 unsigned short* __restrict__ out) {
  constexpr int NSTR = 2 * DD;
  int b = blockIdx.y;
  int d = blockIdx.x * 256 + threadIdx.x;
  int t = threadIdx.x;
  __shared__ float At[KK][68];  // At[j][k] = A[b,k,j]
#pragma unroll
  for (int i = 0; i < 16; i++) {
    int v = t + 256 * i;
    int kr = v >> 6;
    int j = v & 63;
    At[j][kr] = A[((size_t)b * KK + kr) * KK + j];
  }
  __syncthreads();
  float acc[KK];
#pragma unroll
  for (int i = 0; i < KK; i++) acc[i] = 0.f;
#pragma unroll 4
  for (int j = 0; j < KK; j++) {
    float xv = bf2f(Z[((size_t)b * KK + j) * NSTR + DD + d]);
#pragma unroll
    for (int k4 = 0; k4 < 16; k4++) {
      float4 a = *(const float4*)&At[j][k4 * 4];
      acc[k4 * 4 + 0] += a.x * xv;
      acc[k4 * 4 + 1] += a.y * xv;
      acc[k4 * 4 + 2] += a.z * xv;
      acc[k4 * 4 + 3] += a.w * xv;
    }
  }
  float bd = bias[d];
#pragma unroll
  for (int kk = 0; kk < KK; kk++) {
    float v = bf2f(Z[((size_t)b * KK + kk) * NSTR + d]) + acc[kk] + bd;
    out[((size_t)b * KK + kk) * DD + d] = f2bf(fmaxf(v, 0.f));
  }
}

// --------- cls2: logits = h@Wc2 + bc2; probs = softmax(logits) --------------
// h bf16 [MM][256]; 4 lanes per row, 64 rows per block.
__global__ __launch_bounds__(256) void k_cls2(const unsigned short* __restrict__ h,
                                              const float* __restrict__ Wc2,
                                              const float* __restrict__ bc2,
                                              float* __restrict__ probs) {
  __shared__ float W0[256], W1s[256];
  int t = threadIdx.x;
  W0[t] = Wc2[t * 2 + 0];
  W1s[t] = Wc2[t * 2 + 1];
  __syncthreads();
  int row = blockIdx.x * 64 + (t >> 2);
  int c4 = t & 3;
  const unsigned short* hp = h + (size_t)row * DOUT + c4 * 64;
  float l0 = 0.f, l1 = 0.f;
#pragma unroll
  for (int i = 0; i < 8; i++) {
    bf16x8 v = *(const bf16x8*)(hp + i * 8);
#pragma unroll
    for (int e = 0; e < 8; e++) {
      float x = bf2f((unsigned short)v[e]);
      int c = c4 * 64 + i * 8 + e;
      l0 += x * W0[c];
      l1 += x * W1s[c];
    }
  }
  l0 += __shfl_xor(l0, 1);
  l0 += __shfl_xor(l0, 2);
  l1 += __shfl_xor(l1, 1);
  l1 += __shfl_xor(l1, 2);
  if (c4 == 0) {
    l0 += bc2[0];
    l1 += bc2[1];
    float m = fmaxf(l0, l1);
    float e0 = expf(l0 - m), e1 = expf(l1 - m);
    float inv = 1.0f / (e0 + e1);
    *(float2*)(probs + (size_t)row * 2) = make_float2(e0 * inv, e1 * inv);
  }
}

// ---------------------------------------------------------------------------

extern "C" void kernel_launch(void* const* d_in, const int* in_sizes, int n_in,
                              void* d_out, int out_size, void* d_ws, size_t ws_size,
                              hipStream_t stream) {
  const int* indexes = (const int*)d_in[0];
  const float* features = (const float*)d_in[1];
  const int* sub_label = (const int*)d_in[3];
  const int* knn = (const int*)d_in[6];
  const float* all_pred = (const float*)d_in[7];
  const float* W1 = (const float*)d_in[9];
  const float* b1 = (const float*)d_in[10];
  const float* W2 = (const float*)d_in[11];
  const float* b2 = (const float*)d_in[12];
  const float* Wc1 = (const float*)d_in[13];
  const float* bc1 = (const float*)d_in[14];
  const float* pa = (const float*)d_in[15];
  const float* Wc2 = (const float*)d_in[16];
  const float* bc2 = (const float*)d_in[17];

  float* out = (float*)d_out;
  float* probs = out;                    // [B*K*2]
  float* simm = out + 32768;             // [2000]
  float* submean = out + 34768;          // [2000*2048]
  float* nums = out + 4130768;           // [2000]

  // ---- workspace layout (bytes) ----
  char* ws = (char*)d_ws;
  size_t off = 0;
  unsigned short* xnorm_bf = (unsigned short*)(ws + off); off += (size_t)MM * DIM * 2;        // 67MB
  unsigned short* Z1  = (unsigned short*)(ws + off); off += (size_t)MM * 2 * NHID * 2;        // 33.5MB
  unsigned short* x1  = (unsigned short*)(ws + off); off += (size_t)MM * NHID * 2;            // 16.8MB
  unsigned short* Z2  = (unsigned short*)(ws + off); off += (size_t)MM * 2 * DOUT * 2;        // 16.8MB
  unsigned short* x2  = (unsigned short*)(ws + off); off += (size_t)MM * DOUT * 2;            // 8.4MB
  unsigned short* hbuf = (unsigned short*)(ws + off); off += (size_t)MM * DOUT * 2;           // 8.4MB
  unsigned short* W1tp = (unsigned short*)(ws + off); off += (size_t)(2 * NHID) * DIM * 2;    // 4.2MB
  unsigned short* W2tp = (unsigned short*)(ws + off); off += (size_t)(2 * DOUT) * NHID * 2;   // 0.5MB
  unsigned short* Wc1t = (unsigned short*)(ws + off); off += (size_t)DOUT * DOUT * 2;         // 0.13MB
  float* Abuf = (float*)(ws + off); off += (size_t)MM * KK * 4;                               // 4MB
  int* cnt    = (int*)(ws + off); off += NSUB * 4;
  int* cursor = (int*)(ws + off); off += NSUB * 4;
  int* offs   = (int*)(ws + off); off += (NSUB + 4) * 4;
  int* rowlist = (int*)(ws + off); off += (NROW + 8) * 4;
  int* sublabs = (int*)(ws + off); off += (size_t)MM * 4;
  float* norms = (float*)(ws + off); off += (size_t)MM * 4;

  hipMemsetAsync(cnt, 0, 2 * NSUB * sizeof(int), stream);

  const int nrb = (NROW + 255) / 256;
  k_count<<<nrb, 256, 0, stream>>>(sub_label, cnt);
  k_scan<<<1, 256, 0, stream>>>(cnt, offs, cursor);
  k_scatter<<<nrb, 256, 0, stream>>>(sub_label, cursor, rowlist);
  k_cluster_sum<<<NSUB, 256, 0, stream>>>(features, rowlist, offs, submean, simm, nums);
  k_prep<<<BB, 256, 0, stream>>>(indexes, features, sub_label, knn, simm, sublabs, norms);
  k_gram<<<BB, 256, 0, stream>>>(indexes, features, submean, sublabs, all_pred, Abuf);

  // weight transpose-casts into [N][K] bf16, N-concatenated [Wa|Wb]
  // W1 [4096][512]: a-half rows 0..2047 -> Wt rows 0..511; b-half -> rows 512..1023
  k_wt<<<dim3(NHID / 32, DIM / 32), 256, 0, stream>>>(W1, W1tp, NHID, DIM);
  k_wt<<<dim3(NHID / 32, DIM / 32), 256, 0, stream>>>(W1 + (size_t)DIM * NHID,
                                                      W1tp + (size_t)NHID * DIM, NHID, DIM);
  // W2 [1024][256]
  k_wt<<<dim3(DOUT / 32, NHID / 32), 256, 0, stream>>>(W2, W2tp, DOUT, NHID);
  k_wt<<<dim3(DOUT / 32, NHID / 32), 256, 0, stream>>>(W2 + (size_t)NHID * DOUT,
                                                       W2tp + (size_t)DOUT * NHID, DOUT, NHID);
  // Wc1 [256][256]
  k_wt<<<dim3(DOUT / 32, DOUT / 32), 256, 0, stream>>>(Wc1, Wc1t, DOUT, DOUT);

  dim3 g8(8, BB);
  k_xnorm<<<g8, 256, 0, stream>>>(indexes, features, submean, sublabs, norms, xnorm_bf);

  // layer 1: Z1 = xnorm @ [W1a|W1b]  (M=16384, K=2048, N=1024)
  k_gemm_bt<DIM, 2 * NHID, 0><<<dim3((2 * NHID) / 128, MM / 128), 256, 0, stream>>>(
      xnorm_bf, W1tp, nullptr, nullptr, Z1);
  k_combine<NHID><<<dim3(NHID / 256, BB), 256, 0, stream>>>(Abuf, Z1, b1, x1);

  // layer 2: Z2 = x1 @ [W2a|W2b]  (M=16384, K=512, N=512)
  k_gemm_bt<NHID, 2 * DOUT, 0><<<dim3((2 * DOUT) / 128, MM / 128), 256, 0, stream>>>(
      x1, W2tp, nullptr, nullptr, Z2);
  k_combine<DOUT><<<dim3(DOUT / 256, BB), 256, 0, stream>>>(Abuf, Z2, b2, x2);

  // classifier: h = PReLU(x2 @ Wc1 + bc1)  (M=16384, K=256, N=256)
  k_gemm_bt<DOUT, DOUT, 1><<<dim3(DOUT / 128, MM / 128), 256, 0, stream>>>(
      x2, Wc1t, bc1, pa, hbuf);
  k_cls2<<<MM / 64, 256, 0, stream>>>(hbuf, Wc2, bc2, probs);
}

// Round 4
// 367.160 us; speedup vs baseline: 4.5168x; 1.3105x over previous
//
#include <hip/hip_runtime.h>
#include <hip/hip_bf16.h>

// ---------------------------------------------------------------------------
// Sub_Cluster_Level_GCN — round 3:
//   * gram -> bf16 MFMA (XOR-swizzled LDS, fp32 softmax epilogue)
//   * T1 XCD-aware block swizzle on all MFMA GEMMs
//   * k_wt x5 -> 1 launch; xnorm vectorized (float2/ushort2)
// ---------------------------------------------------------------------------

#define NROW 50000
#define DIM  2048
#define NSUB 2000
#define BB   256
#define KK   64
#define NHID 512
#define DOUT 256
#define MM   (BB * KK)   // 16384 rows

typedef __attribute__((ext_vector_type(8))) short bf16x8;
typedef __attribute__((ext_vector_type(4))) float f32x4;

__device__ __forceinline__ unsigned short f2bf(float f) {
  union { float f; unsigned u; } v; v.f = f;
  unsigned r = v.u + 0x7FFF + ((v.u >> 16) & 1);
  return (unsigned short)(r >> 16);
}
__device__ __forceinline__ float bf2f(unsigned short h) {
  union { unsigned u; float f; } v; v.u = ((unsigned)h) << 16;
  return v.f;
}

// ------------------------- segment-mean path -------------------------------

__global__ __launch_bounds__(256) void k_count(const int* __restrict__ sub_label,
                                               int* __restrict__ cnt) {
  int i = blockIdx.x * 256 + threadIdx.x;
  if (i < NROW) atomicAdd(&cnt[sub_label[i]], 1);
}

__global__ __launch_bounds__(256) void k_scan(const int* __restrict__ cnt,
                                              int* __restrict__ offs,
                                              int* __restrict__ cursor) {
  __shared__ int part[256];
  int t = threadIdx.x;
  int base = t * 8;
  int local[8];
  int sum = 0;
#pragma unroll
  for (int i = 0; i < 8; i++) {
    int v = (base + i < NSUB) ? cnt[base + i] : 0;
    local[i] = sum;
    sum += v;
  }
  part[t] = sum;
  __syncthreads();
  for (int off = 1; off < 256; off <<= 1) {
    int v = (t >= off) ? part[t - off] : 0;
    __syncthreads();
    part[t] += v;
    __syncthreads();
  }
  int pre = (t == 0) ? 0 : part[t - 1];
#pragma unroll
  for (int i = 0; i < 8; i++) {
    if (base + i < NSUB) {
      int o = pre + local[i];
      offs[base + i] = o;
      cursor[base + i] = o;
    }
  }
  if (t == 255) offs[NSUB] = pre + sum;
}

__global__ __launch_bounds__(256) void k_scatter(const int* __restrict__ sub_label,
                                                 int* __restrict__ cursor,
                                                 int* __restrict__ rowlist) {
  int i = blockIdx.x * 256 + threadIdx.x;
  if (i < NROW) {
    int s = sub_label[i];
    int pos = atomicAdd(&cursor[s], 1);
    rowlist[pos] = i;
  }
}

__global__ __launch_bounds__(256) void k_cluster_sum(const float* __restrict__ features,
                                                     const int* __restrict__ rowlist,
                                                     const int* __restrict__ offs,
                                                     float* __restrict__ submean,
                                                     float* __restrict__ simm,
                                                     float* __restrict__ nums) {
  int s = blockIdx.x;
  int t = threadIdx.x;
  int start = offs[s], end = offs[s + 1];
  float acc[8] = {0, 0, 0, 0, 0, 0, 0, 0};
  int r = start;
  for (; r + 1 < end; r += 2) {
    const float* rowA = features + (size_t)rowlist[r] * DIM + t * 8;
    const float* rowB = features + (size_t)rowlist[r + 1] * DIM + t * 8;
    float4 a0 = *(const float4*)(rowA);
    float4 a1 = *(const float4*)(rowA + 4);
    float4 b0 = *(const float4*)(rowB);
    float4 b1 = *(const float4*)(rowB + 4);
    acc[0] += a0.x + b0.x; acc[1] += a0.y + b0.y;
    acc[2] += a0.z + b0.z; acc[3] += a0.w + b0.w;
    acc[4] += a1.x + b1.x; acc[5] += a1.y + b1.y;
    acc[6] += a1.z + b1.z; acc[7] += a1.w + b1.w;
  }
  if (r < end) {
    const float* row = features + (size_t)rowlist[r] * DIM + t * 8;
    float4 v0 = *(const float4*)(row);
    float4 v1 = *(const float4*)(row + 4);
    acc[0] += v0.x; acc[1] += v0.y; acc[2] += v0.z; acc[3] += v0.w;
    acc[4] += v1.x; acc[5] += v1.y; acc[6] += v1.z; acc[7] += v1.w;
  }
  int cnt = end - start;
  float inv = 1.0f / (float)(cnt > 0 ? cnt : 1);
  float m[8];
  float ss = 0.f;
#pragma unroll
  for (int i = 0; i < 8; i++) { m[i] = acc[i] * inv; ss += m[i] * m[i]; }
  float* outp = submean + (size_t)s * DIM + t * 8;
  *(float4*)(outp)     = make_float4(m[0], m[1], m[2], m[3]);
  *(float4*)(outp + 4) = make_float4(m[4], m[5], m[6], m[7]);
  __shared__ float red[256];
  red[t] = ss;
  __syncthreads();
  for (int s2 = 128; s2 > 0; s2 >>= 1) {
    if (t < s2) red[t] += red[t + s2];
    __syncthreads();
  }
  if (t == 0) {
    simm[s] = red[0];
    nums[s] = (float)cnt;
  }
}

__global__ __launch_bounds__(256) void k_prep(const int* __restrict__ indexes,
                                              const float* __restrict__ features,
                                              const int* __restrict__ sub_label,
                                              const int* __restrict__ knn,
                                              const float* __restrict__ simm,
                                              int* __restrict__ sublabs,
                                              float* __restrict__ norms) {
  int b = blockIdx.x;
  int t = threadIdx.x;
  const float* row = features + (size_t)indexes[b] * DIM;
  float ss = 0.f;
  for (int i = t; i < DIM; i += 256) {
    float v = row[i];
    ss += v * v;
  }
  __shared__ float red[256];
  red[t] = ss;
  __syncthreads();
  for (int s2 = 128; s2 > 0; s2 >>= 1) {
    if (t < s2) red[t] += red[t + s2];
    __syncthreads();
  }
  __shared__ float n0s;
  if (t == 0) n0s = sqrtf(red[0]);
  __syncthreads();
  if (t < KK) {
    int sl = sub_label[knn[b * KK + t]];
    sublabs[b * KK + t] = sl;
    norms[b * KK + t] = (t == 0) ? n0s : sqrtf(simm[sl]);
  }
}

// ------------------ gram via MFMA: A = softmax(X·Xᵀ ∘ wj) -------------------
// One block per sample (512 threads = 8 waves). X rows cast bf16, staged in
// XOR-swizzled LDS; C = X·Xᵀ fp32 via mfma_16x16x32; fp32 softmax epilogue.
__global__ __launch_bounds__(512) void k_gram_mfma(const int* __restrict__ indexes,
                                                   const float* __restrict__ features,
                                                   const float* __restrict__ submean,
                                                   const int* __restrict__ sublabs,
                                                   const float* __restrict__ all_pred,
                                                   float* __restrict__ A) {
  int b = blockIdx.x;
  int t = threadIdx.x;
  int w = t >> 6, lane = t & 63;
  __shared__ unsigned short Xs[64][256];   // 32 KB, chunk^row XOR swizzle
  __shared__ float Cs[64][68];             // fp32 logits
  __shared__ const float* rowp[KK];
  __shared__ float wjs[KK];
  if (t < KK) {
    rowp[t] = (t == 0) ? (features + (size_t)indexes[b] * DIM)
                       : (submean + (size_t)sublabs[b * KK + t] * DIM);
    wjs[t] = expf(all_pred[(size_t)(b * KK + t) * 2 + 1]);
  }
  __syncthreads();

  const int srow = t >> 3;   // staging: 8 threads per row
  const int spart = t & 7;   // 32 cols each
  const int lr = lane & 15, kg = lane >> 4;
  const int rb = w & 3;      // C row-block (16 rows)
  const int cp = w >> 2;     // C col-pair (32 cols)

  f32x4 acc0 = {0.f, 0.f, 0.f, 0.f}, acc1 = {0.f, 0.f, 0.f, 0.f};

  for (int c = 0; c < 8; c++) {   // K chunks of 256
    const float* src = rowp[srow] + c * 256 + spart * 32;
    __syncthreads();  // previous chunk's readers done
#pragma unroll
    for (int i = 0; i < 4; i++) {
      float4 fa = *(const float4*)(src + i * 8);
      float4 fb = *(const float4*)(src + i * 8 + 4);
      bf16x8 hv;
      hv[0] = (short)f2bf(fa.x); hv[1] = (short)f2bf(fa.y);
      hv[2] = (short)f2bf(fa.z); hv[3] = (short)f2bf(fa.w);
      hv[4] = (short)f2bf(fb.x); hv[5] = (short)f2bf(fb.y);
      hv[6] = (short)f2bf(fb.z); hv[7] = (short)f2bf(fb.w);
      int ch = spart * 4 + i;
      *(bf16x8*)&Xs[srow][((ch ^ (srow & 7)) << 3)] = hv;
    }
    __syncthreads();
#pragma unroll
    for (int ks = 0; ks < 8; ks++) {
      const int ch = ks * 4 + kg;
      int Ra = rb * 16 + lr;
      bf16x8 fa = *(const bf16x8*)&Xs[Ra][((ch ^ (Ra & 7)) << 3)];
      int R0 = (cp * 2) * 16 + lr;
      bf16x8 f0 = *(const bf16x8*)&Xs[R0][((ch ^ (R0 & 7)) << 3)];
      int R1 = (cp * 2 + 1) * 16 + lr;
      bf16x8 f1 = *(const bf16x8*)&Xs[R1][((ch ^ (R1 & 7)) << 3)];
      acc0 = __builtin_amdgcn_mfma_f32_16x16x32_bf16(fa, f0, acc0, 0, 0, 0);
      acc1 = __builtin_amdgcn_mfma_f32_16x16x32_bf16(fa, f1, acc1, 0, 0, 0);
    }
  }

  // C fragments -> LDS (col = lane&15, row = kg*4 + reg)
  __syncthreads();
#pragma unroll
  for (int r = 0; r < 4; r++) {
    Cs[rb * 16 + kg * 4 + r][cp * 32 + lr] = acc0[r];
    Cs[rb * 16 + kg * 4 + r][cp * 32 + 16 + lr] = acc1[r];
  }
  __syncthreads();

  // softmax: 8 threads per row (shfl groups of 8 within a wave)
  int row = t >> 3, seg = t & 7;
  float v[8];
  float mx = -1e30f;
#pragma unroll
  for (int i = 0; i < 8; i++) {
    v[i] = Cs[row][seg * 8 + i] * wjs[seg * 8 + i];
    mx = fmaxf(mx, v[i]);
  }
  mx = fmaxf(mx, __shfl_xor(mx, 1));
  mx = fmaxf(mx, __shfl_xor(mx, 2));
  mx = fmaxf(mx, __shfl_xor(mx, 4));
  float sum = 0.f;
#pragma unroll
  for (int i = 0; i < 8; i++) {
    v[i] = expf(v[i] - mx);
    sum += v[i];
  }
  sum += __shfl_xor(sum, 1);
  sum += __shfl_xor(sum, 2);
  sum += __shfl_xor(sum, 4);
  float inv = 1.0f / sum;
  float* outp = A + ((size_t)b * KK + row) * KK + seg * 8;
  *(float4*)(outp)     = make_float4(v[0] * inv, v[1] * inv, v[2] * inv, v[3] * inv);
  *(float4*)(outp + 4) = make_float4(v[4] * inv, v[5] * inv, v[6] * inv, v[7] * inv);
}

// ------------------------------ x normalize (bf16 out) ----------------------
__global__ __launch_bounds__(256) void k_xnorm(const int* __restrict__ indexes,
                                               const float* __restrict__ features,
                                               const float* __restrict__ submean,
                                               const int* __restrict__ sublabs,
                                               const float* __restrict__ norms,
                                               unsigned short* __restrict__ xn) {
  int b = blockIdx.y;
  int d0 = (blockIdx.x * 256 + threadIdx.x) * 2;
  int t = threadIdx.x;
  __shared__ float ninv[KK];
  __shared__ int sl[KK];
  if (t < KK) {
    ninv[t] = 1.0f / norms[b * KK + t];
    sl[t] = sublabs[b * KK + t];
  }
  __syncthreads();
  float2 f0 = *(const float2*)&features[(size_t)indexes[b] * DIM + d0];
  float r0x = f0.x * ninv[0], r0y = f0.y * ninv[0];
#pragma unroll 4
  for (int kk = 0; kk < KK; kk++) {
    float2 val = (kk == 0) ? f0 : *(const float2*)&submean[(size_t)sl[kk] * DIM + d0];
    ushort2 o;
    o.x = f2bf(val.x * ninv[kk] - r0x);
    o.y = f2bf(val.y * ninv[kk] - r0y);
    *(ushort2*)&xn[((size_t)b * KK + kk) * DIM + d0] = o;
  }
}

// ----------- all weight transpose-casts in one launch (2368 tiles) ----------
__global__ __launch_bounds__(256) void k_wt_all(const float* __restrict__ W1,
                                                const float* __restrict__ W2,
                                                const float* __restrict__ Wc1,
                                                unsigned short* __restrict__ W1t,
                                                unsigned short* __restrict__ W2t,
                                                unsigned short* __restrict__ Wc1t) {
  int bid = blockIdx.x;
  const float* src;
  unsigned short* dst;
  int Nsrc, Kdst, ntn, local;
  if (bid < 1024)      { local = bid;        src = W1;                        dst = W1t;                      Nsrc = NHID; Kdst = DIM;  ntn = 16; }
  else if (bid < 2048) { local = bid - 1024; src = W1 + (size_t)DIM * NHID;   dst = W1t + (size_t)NHID * DIM; Nsrc = NHID; Kdst = DIM;  ntn = 16; }
  else if (bid < 2176) { local = bid - 2048; src = W2;                        dst = W2t;                      Nsrc = DOUT; Kdst = NHID; ntn = 8; }
  else if (bid < 2304) { local = bid - 2176; src = W2 + (size_t)NHID * DOUT;  dst = W2t + (size_t)DOUT * NHID;Nsrc = DOUT; Kdst = NHID; ntn = 8; }
  else                 { local = bid - 2304; src = Wc1;                       dst = Wc1t;                     Nsrc = DOUT; Kdst = DOUT; ntn = 8; }
  int n0 = (local % ntn) * 32, k0 = (local / ntn) * 32;
  __shared__ float tile[32][33];
  int c = threadIdx.x & 31, r8 = threadIdx.x >> 5;
#pragma unroll
  for (int i = 0; i < 4; i++) {
    int r = r8 + i * 8;
    tile[r][c] = src[(size_t)(k0 + r) * Nsrc + n0 + c];
  }
  __syncthreads();
#pragma unroll
  for (int i = 0; i < 4; i++) {
    int r = r8 + i * 8;
    dst[(size_t)(n0 + r) * Kdst + k0 + c] = f2bf(tile[c][r]);
  }
}

// -------------- MFMA GEMM: C = epi(X @ Wt^T) ; X[M][KTOT], Wt[NTOT][KTOT] ---
// 128x128 tile, BK=64, 4 waves; T2 swizzle; T1 XCD-aware block swizzle.
// EPI: 0 = raw bf16; 1 = bias+PReLU bf16.
template <int KTOT, int NTOT, int EPI>
__global__ __launch_bounds__(256) void k_gemm_bt(const unsigned short* __restrict__ X,
                                                 const unsigned short* __restrict__ Wt,
                                                 const float* __restrict__ bias,
                                                 const float* __restrict__ pa,
                                                 unsigned short* __restrict__ out) {
  constexpr int GX = NTOT / 128;
  constexpr int NWG = GX * (MM / 128);
  const int tid = threadIdx.x;
  const int w = tid >> 6, lane = tid & 63;
  int orig = blockIdx.y * GX + blockIdx.x;
  int swz = (orig & 7) * (NWG / 8) + (orig >> 3);   // bijective: NWG % 8 == 0
  const int nt = (swz % GX) * 128;
  const int mt = (swz / GX) * 128;
  __shared__ unsigned short As[128 * 64];
  __shared__ unsigned short Bs[128 * 64];

  f32x4 acc[4][4];
#pragma unroll
  for (int m = 0; m < 4; m++)
#pragma unroll
    for (int n = 0; n < 4; n++) acc[m][n] = (f32x4){0.f, 0.f, 0.f, 0.f};

  const int wr = w >> 1, wc = w & 1;
  const int lr = lane & 15, kg = lane >> 4;

  for (int kc = 0; kc < KTOT / 64; kc++) {
    const int k0 = kc * 64;
#pragma unroll
    for (int i = 0; i < 4; i++) {
      int q = (w * 4 + i) * 64 + lane;   // 16B-chunk id in [0,1024)
      int r = q >> 3;                     // tile row
      int cl = (q & 7) ^ (r & 7);         // pre-swizzled source chunk
      __builtin_amdgcn_global_load_lds(
          (const __attribute__((address_space(1))) void*)(X + (size_t)(mt + r) * KTOT + k0 + cl * 8),
          (__attribute__((address_space(3))) void*)(As + (w * 4 + i) * 512), 16, 0, 0);
    }
#pragma unroll
    for (int i = 0; i < 4; i++) {
      int q = (w * 4 + i) * 64 + lane;
      int r = q >> 3;
      int cl = (q & 7) ^ (r & 7);
      __builtin_amdgcn_global_load_lds(
          (const __attribute__((address_space(1))) void*)(Wt + (size_t)(nt + r) * KTOT + k0 + cl * 8),
          (__attribute__((address_space(3))) void*)(Bs + (w * 4 + i) * 512), 16, 0, 0);
    }
    __syncthreads();
#pragma unroll
    for (int ks = 0; ks < 2; ks++) {
      bf16x8 af[4], bfr[4];
      const int ch = ks * 4 + kg;
#pragma unroll
      for (int m = 0; m < 4; m++) {
        int row = wr * 64 + m * 16 + lr;
        af[m] = *(const bf16x8*)&As[row * 64 + ((ch ^ (row & 7)) << 3)];
      }
#pragma unroll
      for (int n = 0; n < 4; n++) {
        int row = wc * 64 + n * 16 + lr;
        bfr[n] = *(const bf16x8*)&Bs[row * 64 + ((ch ^ (row & 7)) << 3)];
      }
#pragma unroll
      for (int m = 0; m < 4; m++)
#pragma unroll
        for (int n = 0; n < 4; n++)
          acc[m][n] = __builtin_amdgcn_mfma_f32_16x16x32_bf16(af[m], bfr[n], acc[m][n], 0, 0, 0);
    }
    __syncthreads();
  }

#pragma unroll
  for (int m = 0; m < 4; m++) {
    int rm = mt + wr * 64 + m * 16 + kg * 4;
#pragma unroll
    for (int n = 0; n < 4; n++) {
      int col = nt + wc * 64 + n * 16 + lr;
      float bv = (EPI == 1) ? bias[col] : 0.f;
      float av = (EPI == 1) ? pa[col] : 0.f;
#pragma unroll
      for (int j = 0; j < 4; j++) {
        float v = acc[m][n][j];
        if (EPI == 1) {
          v += bv;
          v = (v >= 0.f) ? v : av * v;
        }
        out[(size_t)(rm + j) * NTOT + col] = f2bf(v);
      }
    }
  }
}

// -------- combine: out = relu(Za + A@Zb + bias), per-sample small GEMM ------
template <int DD>
__global__ __launch_bounds__(256) void k_combine(const float* __restrict__ A,
                                                 const unsigned short* __restrict__ Z,
                                                 const float* __restrict__ bias,
                                                 unsigned short* __restrict__ out) {
  constexpr int NSTR = 2 * DD;
  int b = blockIdx.y;
  int d = blockIdx.x * 256 + threadIdx.x;
  int t = threadIdx.x;
  __shared__ float At[KK][68];  // At[j][k] = A[b,k,j]
#pragma unroll
  for (int i = 0; i < 16; i++) {
    int v = t + 256 * i;
    int kr = v >> 6;
    int j = v & 63;
    At[j][kr] = A[((size_t)b * KK + kr) * KK + j];
  }
  __syncthreads();
  float acc[KK];
#pragma unroll
  for (int i = 0; i < KK; i++) acc[i] = 0.f;
#pragma unroll 4
  for (int j = 0; j < KK; j++) {
    float xv = bf2f(Z[((size_t)b * KK + j) * NSTR + DD + d]);
#pragma unroll
    for (int k4 = 0; k4 < 16; k4++) {
      float4 a = *(const float4*)&At[j][k4 * 4];
      acc[k4 * 4 + 0] += a.x * xv;
      acc[k4 * 4 + 1] += a.y * xv;
      acc[k4 * 4 + 2] += a.z * xv;
      acc[k4 * 4 + 3] += a.w * xv;
    }
  }
  float bd = bias[d];
#pragma unroll
  for (int kk = 0; kk < KK; kk++) {
    float v = bf2f(Z[((size_t)b * KK + kk) * NSTR + d]) + acc[kk] + bd;
    out[((size_t)b * KK + kk) * DD + d] = f2bf(fmaxf(v, 0.f));
  }
}

// --------- cls2: logits = h@Wc2 + bc2; probs = softmax(logits) --------------
__global__ __launch_bounds__(256) void k_cls2(const unsigned short* __restrict__ h,
                                              const float* __restrict__ Wc2,
                                              const float* __restrict__ bc2,
                                              float* __restrict__ probs) {
  __shared__ float W0[256], W1s[256];
  int t = threadIdx.x;
  W0[t] = Wc2[t * 2 + 0];
  W1s[t] = Wc2[t * 2 + 1];
  __syncthreads();
  int row = blockIdx.x * 64 + (t >> 2);
  int c4 = t & 3;
  const unsigned short* hp = h + (size_t)row * DOUT + c4 * 64;
  float l0 = 0.f, l1 = 0.f;
#pragma unroll
  for (int i = 0; i < 8; i++) {
    bf16x8 v = *(const bf16x8*)(hp + i * 8);
#pragma unroll
    for (int e = 0; e < 8; e++) {
      float x = bf2f((unsigned short)v[e]);
      int c = c4 * 64 + i * 8 + e;
      l0 += x * W0[c];
      l1 += x * W1s[c];
    }
  }
  l0 += __shfl_xor(l0, 1);
  l0 += __shfl_xor(l0, 2);
  l1 += __shfl_xor(l1, 1);
  l1 += __shfl_xor(l1, 2);
  if (c4 == 0) {
    l0 += bc2[0];
    l1 += bc2[1];
    float m = fmaxf(l0, l1);
    float e0 = expf(l0 - m), e1 = expf(l1 - m);
    float inv = 1.0f / (e0 + e1);
    *(float2*)(probs + (size_t)row * 2) = make_float2(e0 * inv, e1 * inv);
  }
}

// ---------------------------------------------------------------------------

extern "C" void kernel_launch(void* const* d_in, const int* in_sizes, int n_in,
                              void* d_out, int out_size, void* d_ws, size_t ws_size,
                              hipStream_t stream) {
  const int* indexes = (const int*)d_in[0];
  const float* features = (const float*)d_in[1];
  const int* sub_label = (const int*)d_in[3];
  const int* knn = (const int*)d_in[6];
  const float* all_pred = (const float*)d_in[7];
  const float* W1 = (const float*)d_in[9];
  const float* b1 = (const float*)d_in[10];
  const float* W2 = (const float*)d_in[11];
  const float* b2 = (const float*)d_in[12];
  const float* Wc1 = (const float*)d_in[13];
  const float* bc1 = (const float*)d_in[14];
  const float* pa = (const float*)d_in[15];
  const float* Wc2 = (const float*)d_in[16];
  const float* bc2 = (const float*)d_in[17];

  float* out = (float*)d_out;
  float* probs = out;                    // [B*K*2]
  float* simm = out + 32768;             // [2000]
  float* submean = out + 34768;          // [2000*2048]
  float* nums = out + 4130768;           // [2000]

  // ---- workspace layout (bytes) ----
  char* ws = (char*)d_ws;
  size_t off = 0;
  unsigned short* xnorm_bf = (unsigned short*)(ws + off); off += (size_t)MM * DIM * 2;        // 67MB
  unsigned short* Z1  = (unsigned short*)(ws + off); off += (size_t)MM * 2 * NHID * 2;        // 33.5MB
  unsigned short* x1  = (unsigned short*)(ws + off); off += (size_t)MM * NHID * 2;            // 16.8MB
  unsigned short* Z2  = (unsigned short*)(ws + off); off += (size_t)MM * 2 * DOUT * 2;        // 16.8MB
  unsigned short* x2  = (unsigned short*)(ws + off); off += (size_t)MM * DOUT * 2;            // 8.4MB
  unsigned short* hbuf = (unsigned short*)(ws + off); off += (size_t)MM * DOUT * 2;           // 8.4MB
  unsigned short* W1tp = (unsigned short*)(ws + off); off += (size_t)(2 * NHID) * DIM * 2;    // 4.2MB
  unsigned short* W2tp = (unsigned short*)(ws + off); off += (size_t)(2 * DOUT) * NHID * 2;   // 0.5MB
  unsigned short* Wc1t = (unsigned short*)(ws + off); off += (size_t)DOUT * DOUT * 2;         // 0.13MB
  float* Abuf = (float*)(ws + off); off += (size_t)MM * KK * 4;                               // 4MB
  int* cnt    = (int*)(ws + off); off += NSUB * 4;
  int* cursor = (int*)(ws + off); off += NSUB * 4;
  int* offs   = (int*)(ws + off); off += (NSUB + 4) * 4;
  int* rowlist = (int*)(ws + off); off += (NROW + 8) * 4;
  int* sublabs = (int*)(ws + off); off += (size_t)MM * 4;
  float* norms = (float*)(ws + off); off += (size_t)MM * 4;

  hipMemsetAsync(cnt, 0, 2 * NSUB * sizeof(int), stream);

  const int nrb = (NROW + 255) / 256;
  k_count<<<nrb, 256, 0, stream>>>(sub_label, cnt);
  k_scan<<<1, 256, 0, stream>>>(cnt, offs, cursor);
  k_scatter<<<nrb, 256, 0, stream>>>(sub_label, cursor, rowlist);
  k_cluster_sum<<<NSUB, 256, 0, stream>>>(features, rowlist, offs, submean, simm, nums);
  k_prep<<<BB, 256, 0, stream>>>(indexes, features, sub_label, knn, simm, sublabs, norms);
  k_gram_mfma<<<BB, 512, 0, stream>>>(indexes, features, submean, sublabs, all_pred, Abuf);

  k_wt_all<<<2368, 256, 0, stream>>>(W1, W2, Wc1, W1tp, W2tp, Wc1t);

  dim3 g4(DIM / 512, BB);
  k_xnorm<<<g4, 256, 0, stream>>>(indexes, features, submean, sublabs, norms, xnorm_bf);

  // layer 1: Z1 = xnorm @ [W1a|W1b]  (M=16384, K=2048, N=1024)
  k_gemm_bt<DIM, 2 * NHID, 0><<<dim3((2 * NHID) / 128, MM / 128), 256, 0, stream>>>(
      xnorm_bf, W1tp, nullptr, nullptr, Z1);
  k_combine<NHID><<<dim3(NHID / 256, BB), 256, 0, stream>>>(Abuf, Z1, b1, x1);

  // layer 2: Z2 = x1 @ [W2a|W2b]  (M=16384, K=512, N=512)
  k_gemm_bt<NHID, 2 * DOUT, 0><<<dim3((2 * DOUT) / 128, MM / 128), 256, 0, stream>>>(
      x1, W2tp, nullptr, nullptr, Z2);
  k_combine<DOUT><<<dim3(DOUT / 256, BB), 256, 0, stream>>>(Abuf, Z2, b2, x2);

  // classifier: h = PReLU(x2 @ Wc1 + bc1)  (M=16384, K=256, N=256)
  k_gemm_bt<DOUT, DOUT, 1><<<dim3(DOUT / 128, MM / 128), 256, 0, stream>>>(
      x2, Wc1t, bc1, pa, hbuf);
  k_cls2<<<MM / 64, 256, 0, stream>>>(hbuf, Wc2, bc2, probs);
}

// Round 5
// 308.904 us; speedup vs baseline: 5.3686x; 1.1886x over previous
//
#include <hip/hip_runtime.h>
#include <hip/hip_bf16.h>

// ---------------------------------------------------------------------------
// Sub_Cluster_Level_GCN — round 4:
//   * layer-1 GEMM factored through unique sub-cluster rows:
//       x[b,k] = u[sl]-r0[b]  =>  Z1 = U1[sl] - R1[b],  U1=[u;r0]@[Wa|Wb]
//     M: 16384 -> 2304 (68.7 GF -> 9.7 GF); xnorm tensor/kernel eliminated.
//   * combine1 gathers from L2-resident UR1 table.
//   * cluster_sum 4-row unroll.
// ---------------------------------------------------------------------------

#define NROW 50000
#define DIM  2048
#define NSUB 2000
#define BB   256
#define KK   64
#define NHID 512
#define DOUT 256
#define MM   (BB * KK)   // 16384 rows
#define MU   2304        // 2000 u-rows + 256 r0-rows + 48 pad

typedef __attribute__((ext_vector_type(8))) short bf16x8;
typedef __attribute__((ext_vector_type(4))) float f32x4;

__device__ __forceinline__ unsigned short f2bf(float f) {
  union { float f; unsigned u; } v; v.f = f;
  unsigned r = v.u + 0x7FFF + ((v.u >> 16) & 1);
  return (unsigned short)(r >> 16);
}
__device__ __forceinline__ float bf2f(unsigned short h) {
  union { unsigned u; float f; } v; v.u = ((unsigned)h) << 16;
  return v.f;
}

// ------------------------- segment-mean path -------------------------------

__global__ __launch_bounds__(256) void k_count(const int* __restrict__ sub_label,
                                               int* __restrict__ cnt) {
  int i = blockIdx.x * 256 + threadIdx.x;
  if (i < NROW) atomicAdd(&cnt[sub_label[i]], 1);
}

__global__ __launch_bounds__(256) void k_scan(const int* __restrict__ cnt,
                                              int* __restrict__ offs,
                                              int* __restrict__ cursor) {
  __shared__ int part[256];
  int t = threadIdx.x;
  int base = t * 8;
  int local[8];
  int sum = 0;
#pragma unroll
  for (int i = 0; i < 8; i++) {
    int v = (base + i < NSUB) ? cnt[base + i] : 0;
    local[i] = sum;
    sum += v;
  }
  part[t] = sum;
  __syncthreads();
  for (int off = 1; off < 256; off <<= 1) {
    int v = (t >= off) ? part[t - off] : 0;
    __syncthreads();
    part[t] += v;
    __syncthreads();
  }
  int pre = (t == 0) ? 0 : part[t - 1];
#pragma unroll
  for (int i = 0; i < 8; i++) {
    if (base + i < NSUB) {
      int o = pre + local[i];
      offs[base + i] = o;
      cursor[base + i] = o;
    }
  }
  if (t == 255) offs[NSUB] = pre + sum;
}

__global__ __launch_bounds__(256) void k_scatter(const int* __restrict__ sub_label,
                                                 int* __restrict__ cursor,
                                                 int* __restrict__ rowlist) {
  int i = blockIdx.x * 256 + threadIdx.x;
  if (i < NROW) {
    int s = sub_label[i];
    int pos = atomicAdd(&cursor[s], 1);
    rowlist[pos] = i;
  }
}

__global__ __launch_bounds__(256) void k_cluster_sum(const float* __restrict__ features,
                                                     const int* __restrict__ rowlist,
                                                     const int* __restrict__ offs,
                                                     float* __restrict__ submean,
                                                     float* __restrict__ simm,
                                                     float* __restrict__ nums) {
  int s = blockIdx.x;
  int t = threadIdx.x;
  int start = offs[s], end = offs[s + 1];
  float acc[8] = {0, 0, 0, 0, 0, 0, 0, 0};
  int r = start;
  for (; r + 3 < end; r += 4) {
    const float* rA = features + (size_t)rowlist[r] * DIM + t * 8;
    const float* rB = features + (size_t)rowlist[r + 1] * DIM + t * 8;
    const float* rC = features + (size_t)rowlist[r + 2] * DIM + t * 8;
    const float* rD = features + (size_t)rowlist[r + 3] * DIM + t * 8;
    float4 a0 = *(const float4*)(rA), a1 = *(const float4*)(rA + 4);
    float4 b0 = *(const float4*)(rB), b1 = *(const float4*)(rB + 4);
    float4 c0 = *(const float4*)(rC), c1 = *(const float4*)(rC + 4);
    float4 d0 = *(const float4*)(rD), d1 = *(const float4*)(rD + 4);
    acc[0] += (a0.x + b0.x) + (c0.x + d0.x);
    acc[1] += (a0.y + b0.y) + (c0.y + d0.y);
    acc[2] += (a0.z + b0.z) + (c0.z + d0.z);
    acc[3] += (a0.w + b0.w) + (c0.w + d0.w);
    acc[4] += (a1.x + b1.x) + (c1.x + d1.x);
    acc[5] += (a1.y + b1.y) + (c1.y + d1.y);
    acc[6] += (a1.z + b1.z) + (c1.z + d1.z);
    acc[7] += (a1.w + b1.w) + (c1.w + d1.w);
  }
  for (; r < end; r++) {
    const float* row = features + (size_t)rowlist[r] * DIM + t * 8;
    float4 v0 = *(const float4*)(row);
    float4 v1 = *(const float4*)(row + 4);
    acc[0] += v0.x; acc[1] += v0.y; acc[2] += v0.z; acc[3] += v0.w;
    acc[4] += v1.x; acc[5] += v1.y; acc[6] += v1.z; acc[7] += v1.w;
  }
  int cnt = end - start;
  float inv = 1.0f / (float)(cnt > 0 ? cnt : 1);
  float m[8];
  float ss = 0.f;
#pragma unroll
  for (int i = 0; i < 8; i++) { m[i] = acc[i] * inv; ss += m[i] * m[i]; }
  float* outp = submean + (size_t)s * DIM + t * 8;
  *(float4*)(outp)     = make_float4(m[0], m[1], m[2], m[3]);
  *(float4*)(outp + 4) = make_float4(m[4], m[5], m[6], m[7]);
  __shared__ float red[256];
  red[t] = ss;
  __syncthreads();
  for (int s2 = 128; s2 > 0; s2 >>= 1) {
    if (t < s2) red[t] += red[t + s2];
    __syncthreads();
  }
  if (t == 0) {
    simm[s] = red[0];
    nums[s] = (float)cnt;
  }
}

__global__ __launch_bounds__(256) void k_prep(const int* __restrict__ indexes,
                                              const float* __restrict__ features,
                                              const int* __restrict__ sub_label,
                                              const int* __restrict__ knn,
                                              const float* __restrict__ simm,
                                              int* __restrict__ sublabs,
                                              float* __restrict__ norms) {
  int b = blockIdx.x;
  int t = threadIdx.x;
  const float* row = features + (size_t)indexes[b] * DIM;
  float ss = 0.f;
  for (int i = t; i < DIM; i += 256) {
    float v = row[i];
    ss += v * v;
  }
  __shared__ float red[256];
  red[t] = ss;
  __syncthreads();
  for (int s2 = 128; s2 > 0; s2 >>= 1) {
    if (t < s2) red[t] += red[t + s2];
    __syncthreads();
  }
  __shared__ float n0s;
  if (t == 0) n0s = sqrtf(red[0]);
  __syncthreads();
  if (t < KK) {
    int sl = sub_label[knn[b * KK + t]];
    sublabs[b * KK + t] = sl;
    norms[b * KK + t] = (t == 0) ? n0s : sqrtf(simm[sl]);
  }
}

// ------------------ gram via MFMA: A = softmax(X·Xᵀ ∘ wj) -------------------
__global__ __launch_bounds__(512) void k_gram_mfma(const int* __restrict__ indexes,
                                                   const float* __restrict__ features,
                                                   const float* __restrict__ submean,
                                                   const int* __restrict__ sublabs,
                                                   const float* __restrict__ all_pred,
                                                   float* __restrict__ A) {
  int b = blockIdx.x;
  int t = threadIdx.x;
  int w = t >> 6, lane = t & 63;
  __shared__ unsigned short Xs[64][256];   // 32 KB, chunk^row XOR swizzle
  __shared__ float Cs[64][68];             // fp32 logits
  __shared__ const float* rowp[KK];
  __shared__ float wjs[KK];
  if (t < KK) {
    rowp[t] = (t == 0) ? (features + (size_t)indexes[b] * DIM)
                       : (submean + (size_t)sublabs[b * KK + t] * DIM);
    wjs[t] = expf(all_pred[(size_t)(b * KK + t) * 2 + 1]);
  }
  __syncthreads();

  const int srow = t >> 3;
  const int spart = t & 7;
  const int lr = lane & 15, kg = lane >> 4;
  const int rb = w & 3;
  const int cp = w >> 2;

  f32x4 acc0 = {0.f, 0.f, 0.f, 0.f}, acc1 = {0.f, 0.f, 0.f, 0.f};

  for (int c = 0; c < 8; c++) {
    const float* src = rowp[srow] + c * 256 + spart * 32;
    __syncthreads();
#pragma unroll
    for (int i = 0; i < 4; i++) {
      float4 fa = *(const float4*)(src + i * 8);
      float4 fb = *(const float4*)(src + i * 8 + 4);
      bf16x8 hv;
      hv[0] = (short)f2bf(fa.x); hv[1] = (short)f2bf(fa.y);
      hv[2] = (short)f2bf(fa.z); hv[3] = (short)f2bf(fa.w);
      hv[4] = (short)f2bf(fb.x); hv[5] = (short)f2bf(fb.y);
      hv[6] = (short)f2bf(fb.z); hv[7] = (short)f2bf(fb.w);
      int ch = spart * 4 + i;
      *(bf16x8*)&Xs[srow][((ch ^ (srow & 7)) << 3)] = hv;
    }
    __syncthreads();
#pragma unroll
    for (int ks = 0; ks < 8; ks++) {
      const int ch = ks * 4 + kg;
      int Ra = rb * 16 + lr;
      bf16x8 fa = *(const bf16x8*)&Xs[Ra][((ch ^ (Ra & 7)) << 3)];
      int R0 = (cp * 2) * 16 + lr;
      bf16x8 f0 = *(const bf16x8*)&Xs[R0][((ch ^ (R0 & 7)) << 3)];
      int R1 = (cp * 2 + 1) * 16 + lr;
      bf16x8 f1 = *(const bf16x8*)&Xs[R1][((ch ^ (R1 & 7)) << 3)];
      acc0 = __builtin_amdgcn_mfma_f32_16x16x32_bf16(fa, f0, acc0, 0, 0, 0);
      acc1 = __builtin_amdgcn_mfma_f32_16x16x32_bf16(fa, f1, acc1, 0, 0, 0);
    }
  }

  __syncthreads();
#pragma unroll
  for (int r = 0; r < 4; r++) {
    Cs[rb * 16 + kg * 4 + r][cp * 32 + lr] = acc0[r];
    Cs[rb * 16 + kg * 4 + r][cp * 32 + 16 + lr] = acc1[r];
  }
  __syncthreads();

  int row = t >> 3, seg = t & 7;
  float v[8];
  float mx = -1e30f;
#pragma unroll
  for (int i = 0; i < 8; i++) {
    v[i] = Cs[row][seg * 8 + i] * wjs[seg * 8 + i];
    mx = fmaxf(mx, v[i]);
  }
  mx = fmaxf(mx, __shfl_xor(mx, 1));
  mx = fmaxf(mx, __shfl_xor(mx, 2));
  mx = fmaxf(mx, __shfl_xor(mx, 4));
  float sum = 0.f;
#pragma unroll
  for (int i = 0; i < 8; i++) {
    v[i] = expf(v[i] - mx);
    sum += v[i];
  }
  sum += __shfl_xor(sum, 1);
  sum += __shfl_xor(sum, 2);
  sum += __shfl_xor(sum, 4);
  float inv = 1.0f / sum;
  float* outp = A + ((size_t)b * KK + row) * KK + seg * 8;
  *(float4*)(outp)     = make_float4(v[0] * inv, v[1] * inv, v[2] * inv, v[3] * inv);
  *(float4*)(outp + 4) = make_float4(v[4] * inv, v[5] * inv, v[6] * inv, v[7] * inv);
}

// --------- u table: rows 0..1999 u[s]; 2000..2255 r0[b]; 2256.. zero --------
__global__ __launch_bounds__(256) void k_ucast(const float* __restrict__ submean,
                                               const float* __restrict__ simm,
                                               const int* __restrict__ indexes,
                                               const float* __restrict__ features,
                                               const float* __restrict__ norms,
                                               unsigned short* __restrict__ u_bf) {
  int row = blockIdx.x;
  int t = threadIdx.x;
  unsigned short* dst = u_bf + (size_t)row * DIM + t * 8;
  if (row >= NSUB + BB) {
    bf16x8 z = {0, 0, 0, 0, 0, 0, 0, 0};
    *(bf16x8*)dst = z;
    return;
  }
  const float* src;
  float scale;
  if (row < NSUB) {
    float s2 = simm[row];
    scale = (s2 > 0.f) ? (1.0f / sqrtf(s2)) : 0.f;
    src = submean + (size_t)row * DIM + t * 8;
  } else {
    int b = row - NSUB;
    scale = 1.0f / norms[b * KK];
    src = features + (size_t)indexes[b] * DIM + t * 8;
  }
  float4 v0 = *(const float4*)(src);
  float4 v1 = *(const float4*)(src + 4);
  bf16x8 o;
  o[0] = (short)f2bf(v0.x * scale); o[1] = (short)f2bf(v0.y * scale);
  o[2] = (short)f2bf(v0.z * scale); o[3] = (short)f2bf(v0.w * scale);
  o[4] = (short)f2bf(v1.x * scale); o[5] = (short)f2bf(v1.y * scale);
  o[6] = (short)f2bf(v1.z * scale); o[7] = (short)f2bf(v1.w * scale);
  *(bf16x8*)dst = o;
}

// ----------- all weight transpose-casts in one launch (2368 tiles) ----------
__global__ __launch_bounds__(256) void k_wt_all(const float* __restrict__ W1,
                                                const float* __restrict__ W2,
                                                const float* __restrict__ Wc1,
                                                unsigned short* __restrict__ W1t,
                                                unsigned short* __restrict__ W2t,
                                                unsigned short* __restrict__ Wc1t) {
  int bid = blockIdx.x;
  const float* src;
  unsigned short* dst;
  int Nsrc, Kdst, ntn, local;
  if (bid < 1024)      { local = bid;        src = W1;                        dst = W1t;                      Nsrc = NHID; Kdst = DIM;  ntn = 16; }
  else if (bid < 2048) { local = bid - 1024; src = W1 + (size_t)DIM * NHID;   dst = W1t + (size_t)NHID * DIM; Nsrc = NHID; Kdst = DIM;  ntn = 16; }
  else if (bid < 2176) { local = bid - 2048; src = W2;                        dst = W2t;                      Nsrc = DOUT; Kdst = NHID; ntn = 8; }
  else if (bid < 2304) { local = bid - 2176; src = W2 + (size_t)NHID * DOUT;  dst = W2t + (size_t)DOUT * NHID;Nsrc = DOUT; Kdst = NHID; ntn = 8; }
  else                 { local = bid - 2304; src = Wc1;                       dst = Wc1t;                     Nsrc = DOUT; Kdst = DOUT; ntn = 8; }
  int n0 = (local % ntn) * 32, k0 = (local / ntn) * 32;
  __shared__ float tile[32][33];
  int c = threadIdx.x & 31, r8 = threadIdx.x >> 5;
#pragma unroll
  for (int i = 0; i < 4; i++) {
    int r = r8 + i * 8;
    tile[r][c] = src[(size_t)(k0 + r) * Nsrc + n0 + c];
  }
  __syncthreads();
#pragma unroll
  for (int i = 0; i < 4; i++) {
    int r = r8 + i * 8;
    dst[(size_t)(n0 + r) * Kdst + k0 + c] = f2bf(tile[c][r]);
  }
}

// -------------- MFMA GEMM: C = epi(X @ Wt^T) ; X[MROWS][KTOT] ---------------
// 128x128 tile, BK=64, 4 waves; T2 swizzle; T1 XCD-aware block swizzle.
template <int KTOT, int NTOT, int MROWS, int EPI>
__global__ __launch_bounds__(256) void k_gemm_bt(const unsigned short* __restrict__ X,
                                                 const unsigned short* __restrict__ Wt,
                                                 const float* __restrict__ bias,
                                                 const float* __restrict__ pa,
                                                 unsigned short* __restrict__ out) {
  constexpr int GX = NTOT / 128;
  constexpr int NWG = GX * (MROWS / 128);
  static_assert(NWG % 8 == 0, "swizzle needs NWG % 8 == 0");
  const int tid = threadIdx.x;
  const int w = tid >> 6, lane = tid & 63;
  int orig = blockIdx.y * GX + blockIdx.x;
  int swz = (orig & 7) * (NWG / 8) + (orig >> 3);
  const int nt = (swz % GX) * 128;
  const int mt = (swz / GX) * 128;
  __shared__ unsigned short As[128 * 64];
  __shared__ unsigned short Bs[128 * 64];

  f32x4 acc[4][4];
#pragma unroll
  for (int m = 0; m < 4; m++)
#pragma unroll
    for (int n = 0; n < 4; n++) acc[m][n] = (f32x4){0.f, 0.f, 0.f, 0.f};

  const int wr = w >> 1, wc = w & 1;
  const int lr = lane & 15, kg = lane >> 4;

  for (int kc = 0; kc < KTOT / 64; kc++) {
    const int k0 = kc * 64;
#pragma unroll
    for (int i = 0; i < 4; i++) {
      int q = (w * 4 + i) * 64 + lane;
      int r = q >> 3;
      int cl = (q & 7) ^ (r & 7);
      __builtin_amdgcn_global_load_lds(
          (const __attribute__((address_space(1))) void*)(X + (size_t)(mt + r) * KTOT + k0 + cl * 8),
          (__attribute__((address_space(3))) void*)(As + (w * 4 + i) * 512), 16, 0, 0);
    }
#pragma unroll
    for (int i = 0; i < 4; i++) {
      int q = (w * 4 + i) * 64 + lane;
      int r = q >> 3;
      int cl = (q & 7) ^ (r & 7);
      __builtin_amdgcn_global_load_lds(
          (const __attribute__((address_space(1))) void*)(Wt + (size_t)(nt + r) * KTOT + k0 + cl * 8),
          (__attribute__((address_space(3))) void*)(Bs + (w * 4 + i) * 512), 16, 0, 0);
    }
    __syncthreads();
#pragma unroll
    for (int ks = 0; ks < 2; ks++) {
      bf16x8 af[4], bfr[4];
      const int ch = ks * 4 + kg;
#pragma unroll
      for (int m = 0; m < 4; m++) {
        int row = wr * 64 + m * 16 + lr;
        af[m] = *(const bf16x8*)&As[row * 64 + ((ch ^ (row & 7)) << 3)];
      }
#pragma unroll
      for (int n = 0; n < 4; n++) {
        int row = wc * 64 + n * 16 + lr;
        bfr[n] = *(const bf16x8*)&Bs[row * 64 + ((ch ^ (row & 7)) << 3)];
      }
#pragma unroll
      for (int m = 0; m < 4; m++)
#pragma unroll
        for (int n = 0; n < 4; n++)
          acc[m][n] = __builtin_amdgcn_mfma_f32_16x16x32_bf16(af[m], bfr[n], acc[m][n], 0, 0, 0);
    }
    __syncthreads();
  }

#pragma unroll
  for (int m = 0; m < 4; m++) {
    int rm = mt + wr * 64 + m * 16 + kg * 4;
#pragma unroll
    for (int n = 0; n < 4; n++) {
      int col = nt + wc * 64 + n * 16 + lr;
      float bv = (EPI == 1) ? bias[col] : 0.f;
      float av = (EPI == 1) ? pa[col] : 0.f;
#pragma unroll
      for (int j = 0; j < 4; j++) {
        float v = acc[m][n][j];
        if (EPI == 1) {
          v += bv;
          v = (v >= 0.f) ? v : av * v;
        }
        out[(size_t)(rm + j) * NTOT + col] = f2bf(v);
      }
    }
  }
}

// ---- combine1: x1[b,k] = relu( (k>0)(U1a[sl_k]-R1a) + Σ_{j>0}A[k,j]U1b[sl_j]
//                               - (Σ_{j>0}A[k,j])·R1b + bias ) ---------------
// UR [MU][2*DD] bf16 (a = cols 0..DD-1, b = DD..2DD-1); out bf16 [MM][DD]
template <int DD>
__global__ __launch_bounds__(256) void k_combine_u(const float* __restrict__ A,
                                                   const unsigned short* __restrict__ UR,
                                                   const int* __restrict__ sublabs,
                                                   const float* __restrict__ bias,
                                                   unsigned short* __restrict__ out) {
  constexpr int NSTR = 2 * DD;
  int b = blockIdx.y;
  int d = blockIdx.x * 256 + threadIdx.x;
  int t = threadIdx.x;
  __shared__ float At[KK][68];  // At[j][k] = A[b,k,j]
  __shared__ float rs[KK];      // row-sum over j>=1
  __shared__ int sl[KK];
  if (t < KK) sl[t] = sublabs[b * KK + t];
#pragma unroll
  for (int i = 0; i < 16; i++) {
    int v = t + 256 * i;
    int kr = v >> 6;
    int j = v & 63;
    At[j][kr] = A[((size_t)b * KK + kr) * KK + j];
  }
  __syncthreads();
  if (t < KK) {
    float s = 0.f;
    for (int j = 1; j < KK; j++) s += At[j][t];
    rs[t] = s;
  }
  __syncthreads();

  float acc[KK];
#pragma unroll
  for (int i = 0; i < KK; i++) acc[i] = 0.f;
#pragma unroll 4
  for (int j = 1; j < KK; j++) {
    float xv = bf2f(UR[(size_t)sl[j] * NSTR + DD + d]);
#pragma unroll
    for (int k4 = 0; k4 < 16; k4++) {
      float4 a = *(const float4*)&At[j][k4 * 4];
      acc[k4 * 4 + 0] += a.x * xv;
      acc[k4 * 4 + 1] += a.y * xv;
      acc[k4 * 4 + 2] += a.z * xv;
      acc[k4 * 4 + 3] += a.w * xv;
    }
  }
  const unsigned short* Rrow = UR + (size_t)(NSUB + b) * NSTR;
  float Ra = bf2f(Rrow[d]);
  float Rb = bf2f(Rrow[DD + d]);
  float bd = bias[d];
#pragma unroll 4
  for (int kk = 0; kk < KK; kk++) {
    float za = (kk == 0) ? 0.f : (bf2f(UR[(size_t)sl[kk] * NSTR + d]) - Ra);
    float v = za + acc[kk] - rs[kk] * Rb + bd;
    out[((size_t)b * KK + kk) * DD + d] = f2bf(fmaxf(v, 0.f));
  }
}

// -------- combine2: out = relu(Za + A@Zb + bias) from Z [MM][2*DD] ----------
template <int DD>
__global__ __launch_bounds__(256) void k_combine(const float* __restrict__ A,
                                                 const unsigned short* __restrict__ Z,
                                                 const float* __restrict__ bias,
                                                 unsigned short* __restrict__ out) {
  constexpr int NSTR = 2 * DD;
  int b = blockIdx.y;
  int d = blockIdx.x * 256 + threadIdx.x;
  int t = threadIdx.x;
  __shared__ float At[KK][68];
#pragma unroll
  for (int i = 0; i < 16; i++) {
    int v = t + 256 * i;
    int kr = v >> 6;
    int j = v & 63;
    At[j][kr] = A[((size_t)b * KK + kr) * KK + j];
  }
  __syncthreads();
  float acc[KK];
#pragma unroll
  for (int i = 0; i < KK; i++) acc[i] = 0.f;
#pragma unroll 4
  for (int j = 0; j < KK; j++) {
    float xv = bf2f(Z[((size_t)b * KK + j) * NSTR + DD + d]);
#pragma unroll
    for (int k4 = 0; k4 < 16; k4++) {
      float4 a = *(const float4*)&At[j][k4 * 4];
      acc[k4 * 4 + 0] += a.x * xv;
      acc[k4 * 4 + 1] += a.y * xv;
      acc[k4 * 4 + 2] += a.z * xv;
      acc[k4 * 4 + 3] += a.w * xv;
    }
  }
  float bd = bias[d];
#pragma unroll
  for (int kk = 0; kk < KK; kk++) {
    float v = bf2f(Z[((size_t)b * KK + kk) * NSTR + d]) + acc[kk] + bd;
    out[((size_t)b * KK + kk) * DD + d] = f2bf(fmaxf(v, 0.f));
  }
}

// --------- cls2: logits = h@Wc2 + bc2; probs = softmax(logits) --------------
__global__ __launch_bounds__(256) void k_cls2(const unsigned short* __restrict__ h,
                                              const float* __restrict__ Wc2,
                                              const float* __restrict__ bc2,
                                              float* __restrict__ probs) {
  __shared__ float W0[256], W1s[256];
  int t = threadIdx.x;
  W0[t] = Wc2[t * 2 + 0];
  W1s[t] = Wc2[t * 2 + 1];
  __syncthreads();
  int row = blockIdx.x * 64 + (t >> 2);
  int c4 = t & 3;
  const unsigned short* hp = h + (size_t)row * DOUT + c4 * 64;
  float l0 = 0.f, l1 = 0.f;
#pragma unroll
  for (int i = 0; i < 8; i++) {
    bf16x8 v = *(const bf16x8*)(hp + i * 8);
#pragma unroll
    for (int e = 0; e < 8; e++) {
      float x = bf2f((unsigned short)v[e]);
      int c = c4 * 64 + i * 8 + e;
      l0 += x * W0[c];
      l1 += x * W1s[c];
    }
  }
  l0 += __shfl_xor(l0, 1);
  l0 += __shfl_xor(l0, 2);
  l1 += __shfl_xor(l1, 1);
  l1 += __shfl_xor(l1, 2);
  if (c4 == 0) {
    l0 += bc2[0];
    l1 += bc2[1];
    float m = fmaxf(l0, l1);
    float e0 = expf(l0 - m), e1 = expf(l1 - m);
    float inv = 1.0f / (e0 + e1);
    *(float2*)(probs + (size_t)row * 2) = make_float2(e0 * inv, e1 * inv);
  }
}

// ---------------------------------------------------------------------------

extern "C" void kernel_launch(void* const* d_in, const int* in_sizes, int n_in,
                              void* d_out, int out_size, void* d_ws, size_t ws_size,
                              hipStream_t stream) {
  const int* indexes = (const int*)d_in[0];
  const float* features = (const float*)d_in[1];
  const int* sub_label = (const int*)d_in[3];
  const int* knn = (const int*)d_in[6];
  const float* all_pred = (const float*)d_in[7];
  const float* W1 = (const float*)d_in[9];
  const float* b1 = (const float*)d_in[10];
  const float* W2 = (const float*)d_in[11];
  const float* b2 = (const float*)d_in[12];
  const float* Wc1 = (const float*)d_in[13];
  const float* bc1 = (const float*)d_in[14];
  const float* pa = (const float*)d_in[15];
  const float* Wc2 = (const float*)d_in[16];
  const float* bc2 = (const float*)d_in[17];

  float* out = (float*)d_out;
  float* probs = out;                    // [B*K*2]
  float* simm = out + 32768;             // [2000]
  float* submean = out + 34768;          // [2000*2048]
  float* nums = out + 4130768;           // [2000]

  // ---- workspace layout (bytes) ----
  char* ws = (char*)d_ws;
  size_t off = 0;
  unsigned short* u_bf = (unsigned short*)(ws + off); off += (size_t)MU * DIM * 2;            // 9.4MB
  unsigned short* UR1  = (unsigned short*)(ws + off); off += (size_t)MU * 2 * NHID * 2;       // 4.7MB
  unsigned short* x1   = (unsigned short*)(ws + off); off += (size_t)MM * NHID * 2;           // 16.8MB
  unsigned short* Z2   = (unsigned short*)(ws + off); off += (size_t)MM * 2 * DOUT * 2;       // 16.8MB
  unsigned short* x2   = (unsigned short*)(ws + off); off += (size_t)MM * DOUT * 2;           // 8.4MB
  unsigned short* hbuf = (unsigned short*)(ws + off); off += (size_t)MM * DOUT * 2;           // 8.4MB
  unsigned short* W1tp = (unsigned short*)(ws + off); off += (size_t)(2 * NHID) * DIM * 2;    // 4.2MB
  unsigned short* W2tp = (unsigned short*)(ws + off); off += (size_t)(2 * DOUT) * NHID * 2;   // 0.5MB
  unsigned short* Wc1t = (unsigned short*)(ws + off); off += (size_t)DOUT * DOUT * 2;         // 0.13MB
  float* Abuf = (float*)(ws + off); off += (size_t)MM * KK * 4;                               // 4MB
  int* cnt    = (int*)(ws + off); off += NSUB * 4;
  int* cursor = (int*)(ws + off); off += NSUB * 4;
  int* offs   = (int*)(ws + off); off += (NSUB + 4) * 4;
  int* rowlist = (int*)(ws + off); off += (NROW + 8) * 4;
  int* sublabs = (int*)(ws + off); off += (size_t)MM * 4;
  float* norms = (float*)(ws + off); off += (size_t)MM * 4;

  hipMemsetAsync(cnt, 0, 2 * NSUB * sizeof(int), stream);

  const int nrb = (NROW + 255) / 256;
  k_count<<<nrb, 256, 0, stream>>>(sub_label, cnt);
  k_scan<<<1, 256, 0, stream>>>(cnt, offs, cursor);
  k_scatter<<<nrb, 256, 0, stream>>>(sub_label, cursor, rowlist);
  k_cluster_sum<<<NSUB, 256, 0, stream>>>(features, rowlist, offs, submean, simm, nums);
  k_prep<<<BB, 256, 0, stream>>>(indexes, features, sub_label, knn, simm, sublabs, norms);
  k_gram_mfma<<<BB, 512, 0, stream>>>(indexes, features, submean, sublabs, all_pred, Abuf);

  k_wt_all<<<2368, 256, 0, stream>>>(W1, W2, Wc1, W1tp, W2tp, Wc1t);
  k_ucast<<<MU, 256, 0, stream>>>(submean, simm, indexes, features, norms, u_bf);

  // layer 1 (factored): UR1 = [u; r0] @ [W1a|W1b]  (M=2304, K=2048, N=1024)
  k_gemm_bt<DIM, 2 * NHID, MU, 0><<<dim3((2 * NHID) / 128, MU / 128), 256, 0, stream>>>(
      u_bf, W1tp, nullptr, nullptr, UR1);
  k_combine_u<NHID><<<dim3(NHID / 256, BB), 256, 0, stream>>>(Abuf, UR1, sublabs, b1, x1);

  // layer 2: Z2 = x1 @ [W2a|W2b]  (M=16384, K=512, N=512)
  k_gemm_bt<NHID, 2 * DOUT, MM, 0><<<dim3((2 * DOUT) / 128, MM / 128), 256, 0, stream>>>(
      x1, W2tp, nullptr, nullptr, Z2);
  k_combine<DOUT><<<dim3(DOUT / 256, BB), 256, 0, stream>>>(Abuf, Z2, b2, x2);

  // classifier: h = PReLU(x2 @ Wc1 + bc1)  (M=16384, K=256, N=256)
  k_gemm_bt<DOUT, DOUT, MM, 1><<<dim3(DOUT / 128, MM / 128), 256, 0, stream>>>(
      x2, Wc1t, bc1, pa, hbuf);
  k_cls2<<<MM / 64, 256, 0, stream>>>(hbuf, Wc2, bc2, probs);
}

// Round 6
// 256.540 us; speedup vs baseline: 6.4644x; 1.2041x over previous
//
#include <hip/hip_runtime.h>
#include <hip/hip_bf16.h>

// ---------------------------------------------------------------------------
// Sub_Cluster_Level_GCN — round 5:
//   * combine1/combine2 -> per-sample MFMA (A cast bf16, B gathered transposed)
//   * gemm3+cls2 fused (PReLU + 2-col dot + softmax in epilogue; hbuf gone)
//   * cluster_sum column-split (2000x2); simm/nums folded into ucast
// ---------------------------------------------------------------------------

#define NROW 50000
#define DIM  2048
#define NSUB 2000
#define BB   256
#define KK   64
#define NHID 512
#define DOUT 256
#define MM   (BB * KK)   // 16384 rows
#define MU   2304        // 2000 u-rows + 256 r0-rows + 48 pad

typedef __attribute__((ext_vector_type(8))) short bf16x8;
typedef __attribute__((ext_vector_type(4))) float f32x4;

__device__ __forceinline__ unsigned short f2bf(float f) {
  union { float f; unsigned u; } v; v.f = f;
  unsigned r = v.u + 0x7FFF + ((v.u >> 16) & 1);
  return (unsigned short)(r >> 16);
}
__device__ __forceinline__ float bf2f(unsigned short h) {
  union { unsigned u; float f; } v; v.u = ((unsigned)h) << 16;
  return v.f;
}

// ------------------------- segment-mean path -------------------------------

__global__ __launch_bounds__(256) void k_count(const int* __restrict__ sub_label,
                                               int* __restrict__ cnt) {
  int i = blockIdx.x * 256 + threadIdx.x;
  if (i < NROW) atomicAdd(&cnt[sub_label[i]], 1);
}

__global__ __launch_bounds__(256) void k_scan(const int* __restrict__ cnt,
                                              int* __restrict__ offs,
                                              int* __restrict__ cursor) {
  __shared__ int part[256];
  int t = threadIdx.x;
  int base = t * 8;
  int local[8];
  int sum = 0;
#pragma unroll
  for (int i = 0; i < 8; i++) {
    int v = (base + i < NSUB) ? cnt[base + i] : 0;
    local[i] = sum;
    sum += v;
  }
  part[t] = sum;
  __syncthreads();
  for (int off = 1; off < 256; off <<= 1) {
    int v = (t >= off) ? part[t - off] : 0;
    __syncthreads();
    part[t] += v;
    __syncthreads();
  }
  int pre = (t == 0) ? 0 : part[t - 1];
#pragma unroll
  for (int i = 0; i < 8; i++) {
    if (base + i < NSUB) {
      int o = pre + local[i];
      offs[base + i] = o;
      cursor[base + i] = o;
    }
  }
  if (t == 255) offs[NSUB] = pre + sum;
}

__global__ __launch_bounds__(256) void k_scatter(const int* __restrict__ sub_label,
                                                 int* __restrict__ cursor,
                                                 int* __restrict__ rowlist) {
  int i = blockIdx.x * 256 + threadIdx.x;
  if (i < NROW) {
    int s = sub_label[i];
    int pos = atomicAdd(&cursor[s], 1);
    rowlist[pos] = i;
  }
}

// grid (NSUB, 2): block (cluster, column-half). Writes mean only.
__global__ __launch_bounds__(256) void k_cluster_sum(const float* __restrict__ features,
                                                     const int* __restrict__ rowlist,
                                                     const int* __restrict__ offs,
                                                     float* __restrict__ submean) {
  int s = blockIdx.x;
  int col = blockIdx.y * 1024 + threadIdx.x * 4;
  int start = offs[s], end = offs[s + 1];
  float4 acc = make_float4(0.f, 0.f, 0.f, 0.f);
  int r = start;
  for (; r + 3 < end; r += 4) {
    float4 a = *(const float4*)(features + (size_t)rowlist[r] * DIM + col);
    float4 b = *(const float4*)(features + (size_t)rowlist[r + 1] * DIM + col);
    float4 c = *(const float4*)(features + (size_t)rowlist[r + 2] * DIM + col);
    float4 d = *(const float4*)(features + (size_t)rowlist[r + 3] * DIM + col);
    acc.x += (a.x + b.x) + (c.x + d.x);
    acc.y += (a.y + b.y) + (c.y + d.y);
    acc.z += (a.z + b.z) + (c.z + d.z);
    acc.w += (a.w + b.w) + (c.w + d.w);
  }
  for (; r < end; r++) {
    float4 a = *(const float4*)(features + (size_t)rowlist[r] * DIM + col);
    acc.x += a.x; acc.y += a.y; acc.z += a.z; acc.w += a.w;
  }
  int cnt = end - start;
  float inv = 1.0f / (float)(cnt > 0 ? cnt : 1);
  acc.x *= inv; acc.y *= inv; acc.z *= inv; acc.w *= inv;
  *(float4*)(submean + (size_t)s * DIM + col) = acc;
}

// prep: norms0[b] = ||features[idx_b]||, sublabs[b,k]
__global__ __launch_bounds__(256) void k_prep(const int* __restrict__ indexes,
                                              const float* __restrict__ features,
                                              const int* __restrict__ sub_label,
                                              const int* __restrict__ knn,
                                              int* __restrict__ sublabs,
                                              float* __restrict__ norms0) {
  int b = blockIdx.x;
  int t = threadIdx.x;
  const float* row = features + (size_t)indexes[b] * DIM;
  float ss = 0.f;
  for (int i = t; i < DIM; i += 256) {
    float v = row[i];
    ss += v * v;
  }
  __shared__ float red[256];
  red[t] = ss;
  __syncthreads();
  for (int s2 = 128; s2 > 0; s2 >>= 1) {
    if (t < s2) red[t] += red[t + s2];
    __syncthreads();
  }
  if (t == 0) norms0[b] = sqrtf(red[0]);
  if (t < KK) sublabs[b * KK + t] = sub_label[knn[b * KK + t]];
}

// ------------------ gram via MFMA: A = softmax(X·Xᵀ ∘ wj) -------------------
__global__ __launch_bounds__(512) void k_gram_mfma(const int* __restrict__ indexes,
                                                   const float* __restrict__ features,
                                                   const float* __restrict__ submean,
                                                   const int* __restrict__ sublabs,
                                                   const float* __restrict__ all_pred,
                                                   float* __restrict__ A) {
  int b = blockIdx.x;
  int t = threadIdx.x;
  int w = t >> 6, lane = t & 63;
  __shared__ unsigned short Xs[64][256];   // 32 KB, chunk^row XOR swizzle
  __shared__ float Cs[64][68];             // fp32 logits
  __shared__ const float* rowp[KK];
  __shared__ float wjs[KK];
  if (t < KK) {
    rowp[t] = (t == 0) ? (features + (size_t)indexes[b] * DIM)
                       : (submean + (size_t)sublabs[b * KK + t] * DIM);
    wjs[t] = expf(all_pred[(size_t)(b * KK + t) * 2 + 1]);
  }
  __syncthreads();

  const int srow = t >> 3;
  const int spart = t & 7;
  const int lr = lane & 15, kg = lane >> 4;
  const int rb = w & 3;
  const int cp = w >> 2;

  f32x4 acc0 = {0.f, 0.f, 0.f, 0.f}, acc1 = {0.f, 0.f, 0.f, 0.f};

  for (int c = 0; c < 8; c++) {
    const float* src = rowp[srow] + c * 256 + spart * 32;
    __syncthreads();
#pragma unroll
    for (int i = 0; i < 4; i++) {
      float4 fa = *(const float4*)(src + i * 8);
      float4 fb = *(const float4*)(src + i * 8 + 4);
      bf16x8 hv;
      hv[0] = (short)f2bf(fa.x); hv[1] = (short)f2bf(fa.y);
      hv[2] = (short)f2bf(fa.z); hv[3] = (short)f2bf(fa.w);
      hv[4] = (short)f2bf(fb.x); hv[5] = (short)f2bf(fb.y);
      hv[6] = (short)f2bf(fb.z); hv[7] = (short)f2bf(fb.w);
      int ch = spart * 4 + i;
      *(bf16x8*)&Xs[srow][((ch ^ (srow & 7)) << 3)] = hv;
    }
    __syncthreads();
#pragma unroll
    for (int ks = 0; ks < 8; ks++) {
      const int ch = ks * 4 + kg;
      int Ra = rb * 16 + lr;
      bf16x8 fa = *(const bf16x8*)&Xs[Ra][((ch ^ (Ra & 7)) << 3)];
      int R0 = (cp * 2) * 16 + lr;
      bf16x8 f0 = *(const bf16x8*)&Xs[R0][((ch ^ (R0 & 7)) << 3)];
      int R1 = (cp * 2 + 1) * 16 + lr;
      bf16x8 f1 = *(const bf16x8*)&Xs[R1][((ch ^ (R1 & 7)) << 3)];
      acc0 = __builtin_amdgcn_mfma_f32_16x16x32_bf16(fa, f0, acc0, 0, 0, 0);
      acc1 = __builtin_amdgcn_mfma_f32_16x16x32_bf16(fa, f1, acc1, 0, 0, 0);
    }
  }

  __syncthreads();
#pragma unroll
  for (int r = 0; r < 4; r++) {
    Cs[rb * 16 + kg * 4 + r][cp * 32 + lr] = acc0[r];
    Cs[rb * 16 + kg * 4 + r][cp * 32 + 16 + lr] = acc1[r];
  }
  __syncthreads();

  int row = t >> 3, seg = t & 7;
  float v[8];
  float mx = -1e30f;
#pragma unroll
  for (int i = 0; i < 8; i++) {
    v[i] = Cs[row][seg * 8 + i] * wjs[seg * 8 + i];
    mx = fmaxf(mx, v[i]);
  }
  mx = fmaxf(mx, __shfl_xor(mx, 1));
  mx = fmaxf(mx, __shfl_xor(mx, 2));
  mx = fmaxf(mx, __shfl_xor(mx, 4));
  float sum = 0.f;
#pragma unroll
  for (int i = 0; i < 8; i++) {
    v[i] = expf(v[i] - mx);
    sum += v[i];
  }
  sum += __shfl_xor(sum, 1);
  sum += __shfl_xor(sum, 2);
  sum += __shfl_xor(sum, 4);
  float inv = 1.0f / sum;
  float* outp = A + ((size_t)b * KK + row) * KK + seg * 8;
  *(float4*)(outp)     = make_float4(v[0] * inv, v[1] * inv, v[2] * inv, v[3] * inv);
  *(float4*)(outp + 4) = make_float4(v[4] * inv, v[5] * inv, v[6] * inv, v[7] * inv);
}

// --------- u table + simm + nums: rows 0..1999 u[s]; 2000..2255 r0[b] -------
__global__ __launch_bounds__(256) void k_ucast(const float* __restrict__ submean,
                                               const int* __restrict__ cnt,
                                               const int* __restrict__ indexes,
                                               const float* __restrict__ features,
                                               const float* __restrict__ norms0,
                                               unsigned short* __restrict__ u_bf,
                                               float* __restrict__ simm,
                                               float* __restrict__ nums) {
  int row = blockIdx.x;
  int t = threadIdx.x;
  unsigned short* dst = u_bf + (size_t)row * DIM + t * 8;
  if (row >= NSUB + BB) {
    bf16x8 z = {0, 0, 0, 0, 0, 0, 0, 0};
    *(bf16x8*)dst = z;
    return;
  }
  float scale;
  float4 v0, v1;
  if (row < NSUB) {
    const float* src = submean + (size_t)row * DIM + t * 8;
    v0 = *(const float4*)(src);
    v1 = *(const float4*)(src + 4);
    float ss = v0.x * v0.x + v0.y * v0.y + v0.z * v0.z + v0.w * v0.w +
               v1.x * v1.x + v1.y * v1.y + v1.z * v1.z + v1.w * v1.w;
    __shared__ float red[256];
    red[t] = ss;
    __syncthreads();
    for (int s2 = 128; s2 > 0; s2 >>= 1) {
      if (t < s2) red[t] += red[t + s2];
      __syncthreads();
    }
    float tot = red[0];
    if (t == 0) {
      simm[row] = tot;
      nums[row] = (float)cnt[row];
    }
    scale = (tot > 0.f) ? (1.0f / sqrtf(tot)) : 0.f;
  } else {
    int b = row - NSUB;
    scale = 1.0f / norms0[b];
    const float* src = features + (size_t)indexes[b] * DIM + t * 8;
    v0 = *(const float4*)(src);
    v1 = *(const float4*)(src + 4);
  }
  bf16x8 o;
  o[0] = (short)f2bf(v0.x * scale); o[1] = (short)f2bf(v0.y * scale);
  o[2] = (short)f2bf(v0.z * scale); o[3] = (short)f2bf(v0.w * scale);
  o[4] = (short)f2bf(v1.x * scale); o[5] = (short)f2bf(v1.y * scale);
  o[6] = (short)f2bf(v1.z * scale); o[7] = (short)f2bf(v1.w * scale);
  *(bf16x8*)dst = o;
}

// ----------- all weight transpose-casts in one launch (2368 tiles) ----------
__global__ __launch_bounds__(256) void k_wt_all(const float* __restrict__ W1,
                                                const float* __restrict__ W2,
                                                const float* __restrict__ Wc1,
                                                unsigned short* __restrict__ W1t,
                                                unsigned short* __restrict__ W2t,
                                                unsigned short* __restrict__ Wc1t) {
  int bid = blockIdx.x;
  const float* src;
  unsigned short* dst;
  int Nsrc, Kdst, ntn, local;
  if (bid < 1024)      { local = bid;        src = W1;                        dst = W1t;                      Nsrc = NHID; Kdst = DIM;  ntn = 16; }
  else if (bid < 2048) { local = bid - 1024; src = W1 + (size_t)DIM * NHID;   dst = W1t + (size_t)NHID * DIM; Nsrc = NHID; Kdst = DIM;  ntn = 16; }
  else if (bid < 2176) { local = bid - 2048; src = W2;                        dst = W2t;                      Nsrc = DOUT; Kdst = NHID; ntn = 8; }
  else if (bid < 2304) { local = bid - 2176; src = W2 + (size_t)NHID * DOUT;  dst = W2t + (size_t)DOUT * NHID;Nsrc = DOUT; Kdst = NHID; ntn = 8; }
  else                 { local = bid - 2304; src = Wc1;                       dst = Wc1t;                     Nsrc = DOUT; Kdst = DOUT; ntn = 8; }
  int n0 = (local % ntn) * 32, k0 = (local / ntn) * 32;
  __shared__ float tile[32][33];
  int c = threadIdx.x & 31, r8 = threadIdx.x >> 5;
#pragma unroll
  for (int i = 0; i < 4; i++) {
    int r = r8 + i * 8;
    tile[r][c] = src[(size_t)(k0 + r) * Nsrc + n0 + c];
  }
  __syncthreads();
#pragma unroll
  for (int i = 0; i < 4; i++) {
    int r = r8 + i * 8;
    dst[(size_t)(n0 + r) * Kdst + k0 + c] = f2bf(tile[c][r]);
  }
}

// -------------- MFMA GEMM: C = X @ Wt^T ; X[MROWS][KTOT], Wt[NTOT][KTOT] ----
template <int KTOT, int NTOT, int MROWS>
__global__ __launch_bounds__(256) void k_gemm_bt(const unsigned short* __restrict__ X,
                                                 const unsigned short* __restrict__ Wt,
                                                 unsigned short* __restrict__ out) {
  constexpr int GX = NTOT / 128;
  constexpr int NWG = GX * (MROWS / 128);
  static_assert(NWG % 8 == 0, "swizzle needs NWG % 8 == 0");
  const int tid = threadIdx.x;
  const int w = tid >> 6, lane = tid & 63;
  int orig = blockIdx.y * GX + blockIdx.x;
  int swz = (orig & 7) * (NWG / 8) + (orig >> 3);
  const int nt = (swz % GX) * 128;
  const int mt = (swz / GX) * 128;
  __shared__ unsigned short As[128 * 64];
  __shared__ unsigned short Bs[128 * 64];

  f32x4 acc[4][4];
#pragma unroll
  for (int m = 0; m < 4; m++)
#pragma unroll
    for (int n = 0; n < 4; n++) acc[m][n] = (f32x4){0.f, 0.f, 0.f, 0.f};

  const int wr = w >> 1, wc = w & 1;
  const int lr = lane & 15, kg = lane >> 4;

  for (int kc = 0; kc < KTOT / 64; kc++) {
    const int k0 = kc * 64;
#pragma unroll
    for (int i = 0; i < 4; i++) {
      int q = (w * 4 + i) * 64 + lane;
      int r = q >> 3;
      int cl = (q & 7) ^ (r & 7);
      __builtin_amdgcn_global_load_lds(
          (const __attribute__((address_space(1))) void*)(X + (size_t)(mt + r) * KTOT + k0 + cl * 8),
          (__attribute__((address_space(3))) void*)(As + (w * 4 + i) * 512), 16, 0, 0);
    }
#pragma unroll
    for (int i = 0; i < 4; i++) {
      int q = (w * 4 + i) * 64 + lane;
      int r = q >> 3;
      int cl = (q & 7) ^ (r & 7);
      __builtin_amdgcn_global_load_lds(
          (const __attribute__((address_space(1))) void*)(Wt + (size_t)(nt + r) * KTOT + k0 + cl * 8),
          (__attribute__((address_space(3))) void*)(Bs + (w * 4 + i) * 512), 16, 0, 0);
    }
    __syncthreads();
#pragma unroll
    for (int ks = 0; ks < 2; ks++) {
      bf16x8 af[4], bfr[4];
      const int ch = ks * 4 + kg;
#pragma unroll
      for (int m = 0; m < 4; m++) {
        int row = wr * 64 + m * 16 + lr;
        af[m] = *(const bf16x8*)&As[row * 64 + ((ch ^ (row & 7)) << 3)];
      }
#pragma unroll
      for (int n = 0; n < 4; n++) {
        int row = wc * 64 + n * 16 + lr;
        bfr[n] = *(const bf16x8*)&Bs[row * 64 + ((ch ^ (row & 7)) << 3)];
      }
#pragma unroll
      for (int m = 0; m < 4; m++)
#pragma unroll
        for (int n = 0; n < 4; n++)
          acc[m][n] = __builtin_amdgcn_mfma_f32_16x16x32_bf16(af[m], bfr[n], acc[m][n], 0, 0, 0);
    }
    __syncthreads();
  }

#pragma unroll
  for (int m = 0; m < 4; m++) {
    int rm = mt + wr * 64 + m * 16 + kg * 4;
#pragma unroll
    for (int n = 0; n < 4; n++) {
      int col = nt + wc * 64 + n * 16 + lr;
#pragma unroll
      for (int j = 0; j < 4; j++)
        out[(size_t)(rm + j) * NTOT + col] = f2bf(acc[m][n][j]);
    }
  }
}

// ------------- combine via MFMA: out = relu(Za + P@Bg + bias) ---------------
// L1: P[k][0]=-rs[k], P[k][j>=1]=A[k][j]; Bg[d][0]=Rb[d], Bg[d][j]=U1b[sl_j][d];
//     Za = (k>0)(U1a[sl_k][d] - Ra[d]).
// L2: P=A full; Bg[d][j]=Z[b*64+j][DD+d]; Za = Z[b*64+k][d].
template <int DD, bool L1>
__global__ __launch_bounds__(256) void k_combine_mfma(const float* __restrict__ A,
                                                      const unsigned short* __restrict__ Z,
                                                      const int* __restrict__ sublabs,
                                                      const float* __restrict__ bias,
                                                      unsigned short* __restrict__ out) {
  constexpr int NSTR = 2 * DD;
  const int b = blockIdx.y;
  const int dblk = blockIdx.x * 128;
  const int t = threadIdx.x;
  const int w = t >> 6, lane = t & 63;
  const int lr = lane & 15, kg = lane >> 4;

  __shared__ unsigned short Pl[64][80];    // [k][j], 160B row stride (16B-mult)
  __shared__ unsigned short Bl[128][80];   // [d][j]
  __shared__ unsigned short Ag[64][136];   // [k][d] (L1), 272B stride
  __shared__ float Raf[128];
  __shared__ int slh[64];
  __shared__ float red[64][4];

  if (L1 && t < 64) slh[t] = sublabs[b * KK + t];
  __syncthreads();

  // --- P build ---
  {
    int pk = t & 63, pp = t >> 6;
    const float* Arow = A + ((size_t)b * KK + pk) * KK;
    float part = 0.f;
#pragma unroll
    for (int e = 0; e < 16; e++) {
      int j = pp * 16 + e;
      float av = Arow[j];
      if (!L1 || j > 0) {
        Pl[pk][j] = f2bf(av);
        if (L1) part += av;
      }
    }
    if (L1) red[pk][pp] = part;
  }
  // --- B gather (transposed [d][j]) ---
  {
    int gj = t >> 2, gc0 = t & 3;
    size_t brow;
    if (L1) brow = (gj == 0) ? (size_t)(NSUB + b) : (size_t)slh[gj];
    else    brow = (size_t)b * KK + gj;
    const unsigned short* Bp = Z + brow * NSTR + DD + dblk;
#pragma unroll
    for (int it = 0; it < 4; it++) {
      int c = gc0 + it * 4;
      bf16x8 v = *(const bf16x8*)(Bp + c * 8);
#pragma unroll
      for (int e = 0; e < 8; e++) Bl[c * 8 + e][gj] = v[e];
    }
  }
  // --- Za gather (L1): Ag[k][d] + Ra ---
  if (L1) {
    int ak = t >> 2, ac0 = t & 3;
    const unsigned short* Ap = Z + (size_t)slh[ak] * NSTR + dblk;
#pragma unroll
    for (int it = 0; it < 4; it++) {
      int c = ac0 + it * 4;
      *(bf16x8*)&Ag[ak][c * 8] = *(const bf16x8*)(Ap + c * 8);
    }
    if (t < 128) Raf[t] = bf2f(Z[(size_t)(NSUB + b) * NSTR + dblk + t]);
  }
  __syncthreads();
  if (L1 && t < 64) {
    float rs = red[t][0] + red[t][1] + red[t][2] + red[t][3];
    Pl[t][0] = f2bf(-rs);
  }
  __syncthreads();

  // --- MFMA: C[k][d] ---
  f32x4 acc[4][2];
#pragma unroll
  for (int m = 0; m < 4; m++)
#pragma unroll
    for (int n = 0; n < 2; n++) acc[m][n] = (f32x4){0.f, 0.f, 0.f, 0.f};
#pragma unroll
  for (int ks = 0; ks < 2; ks++) {
    const int ch = ks * 4 + kg;
    bf16x8 af[4], bfr[2];
#pragma unroll
    for (int m = 0; m < 4; m++) af[m] = *(const bf16x8*)&Pl[m * 16 + lr][ch * 8];
#pragma unroll
    for (int n = 0; n < 2; n++) {
      int rowd = w * 32 + n * 16 + lr;
      bfr[n] = *(const bf16x8*)&Bl[rowd][ch * 8];
    }
#pragma unroll
    for (int m = 0; m < 4; m++)
#pragma unroll
      for (int n = 0; n < 2; n++)
        acc[m][n] = __builtin_amdgcn_mfma_f32_16x16x32_bf16(af[m], bfr[n], acc[m][n], 0, 0, 0);
  }

  // --- epilogue ---
#pragma unroll
  for (int m = 0; m < 4; m++) {
#pragma unroll
    for (int n = 0; n < 2; n++) {
      int dcol = w * 32 + n * 16 + lr;
      float bd = bias[dblk + dcol];
#pragma unroll
      for (int j = 0; j < 4; j++) {
        int k = m * 16 + kg * 4 + j;
        float v = acc[m][n][j] + bd;
        if (L1) {
          if (k > 0) v += bf2f(Ag[k][dcol]) - Raf[dcol];
        } else {
          v += bf2f(Z[((size_t)b * KK + k) * NSTR + dblk + dcol]);
        }
        out[((size_t)b * KK + k) * DD + dblk + dcol] = f2bf(fmaxf(v, 0.f));
      }
    }
  }
}

// ---- fused classifier: probs = softmax( PReLU(x2@Wc1+bc1) @ Wc2 + bc2 ) ----
// 512 threads, tile 128 x 256 (full N), K=256.
__global__ __launch_bounds__(512) void k_cls_fused(const unsigned short* __restrict__ X,
                                                   const unsigned short* __restrict__ Wt,
                                                   const float* __restrict__ bc1,
                                                   const float* __restrict__ pa,
                                                   const float* __restrict__ Wc2,
                                                   const float* __restrict__ bc2,
                                                   float* __restrict__ probs) {
  const int t = threadIdx.x;
  const int w = t >> 6, lane = t & 63;
  const int lr = lane & 15, kg = lane >> 4;
  const int wr = w >> 2, wc = w & 3;
  const int mt = blockIdx.x * 128;
  __shared__ unsigned short As[128 * 64];
  __shared__ unsigned short Bs[256 * 64];
  __shared__ float Lred[128][4][2];

  f32x4 acc[4][4];
#pragma unroll
  for (int m = 0; m < 4; m++)
#pragma unroll
    for (int n = 0; n < 4; n++) acc[m][n] = (f32x4){0.f, 0.f, 0.f, 0.f};

  for (int kc = 0; kc < 4; kc++) {
    const int k0 = kc * 64;
#pragma unroll
    for (int i = 0; i < 2; i++) {
      int q = (w * 2 + i) * 64 + lane;
      int r = q >> 3;
      int cl = (q & 7) ^ (r & 7);
      __builtin_amdgcn_global_load_lds(
          (const __attribute__((address_space(1))) void*)(X + (size_t)(mt + r) * DOUT + k0 + cl * 8),
          (__attribute__((address_space(3))) void*)(As + (w * 2 + i) * 512), 16, 0, 0);
    }
#pragma unroll
    for (int i = 0; i < 4; i++) {
      int q = (w * 4 + i) * 64 + lane;
      int r = q >> 3;
      int cl = (q & 7) ^ (r & 7);
      __builtin_amdgcn_global_load_lds(
          (const __attribute__((address_space(1))) void*)(Wt + (size_t)r * DOUT + k0 + cl * 8),
          (__attribute__((address_space(3))) void*)(Bs + (w * 4 + i) * 512), 16, 0, 0);
    }
    __syncthreads();
#pragma unroll
    for (int ks = 0; ks < 2; ks++) {
      bf16x8 af[4], bfr[4];
      const int ch = ks * 4 + kg;
#pragma unroll
      for (int m = 0; m < 4; m++) {
        int row = wr * 64 + m * 16 + lr;
        af[m] = *(const bf16x8*)&As[row * 64 + ((ch ^ (row & 7)) << 3)];
      }
#pragma unroll
      for (int n = 0; n < 4; n++) {
        int row = wc * 64 + n * 16 + lr;
        bfr[n] = *(const bf16x8*)&Bs[row * 64 + ((ch ^ (row & 7)) << 3)];
      }
#pragma unroll
      for (int m = 0; m < 4; m++)
#pragma unroll
        for (int n = 0; n < 4; n++)
          acc[m][n] = __builtin_amdgcn_mfma_f32_16x16x32_bf16(af[m], bfr[n], acc[m][n], 0, 0, 0);
    }
    __syncthreads();
  }

  // epilogue: bias+PReLU, dot with Wc2 cols, reduce
  float bc1v[4], pav[4], w0v[4], w1v[4];
#pragma unroll
  for (int n = 0; n < 4; n++) {
    int col = wc * 64 + n * 16 + lr;
    bc1v[n] = bc1[col];
    pav[n] = pa[col];
    w0v[n] = Wc2[col * 2 + 0];
    w1v[n] = Wc2[col * 2 + 1];
  }
#pragma unroll
  for (int m = 0; m < 4; m++) {
#pragma unroll
    for (int j = 0; j < 4; j++) {
      float p0 = 0.f, p1 = 0.f;
#pragma unroll
      for (int n = 0; n < 4; n++) {
        float h = acc[m][n][j] + bc1v[n];
        h = (h >= 0.f) ? h : pav[n] * h;
        p0 += h * w0v[n];
        p1 += h * w1v[n];
      }
      p0 += __shfl_xor(p0, 1); p1 += __shfl_xor(p1, 1);
      p0 += __shfl_xor(p0, 2); p1 += __shfl_xor(p1, 2);
      p0 += __shfl_xor(p0, 4); p1 += __shfl_xor(p1, 4);
      p0 += __shfl_xor(p0, 8); p1 += __shfl_xor(p1, 8);
      if (lr == 0) {
        int rowl = wr * 64 + m * 16 + kg * 4 + j;
        Lred[rowl][wc][0] = p0;
        Lred[rowl][wc][1] = p1;
      }
    }
  }
  __syncthreads();
  if (t < 128) {
    float l0 = Lred[t][0][0] + Lred[t][1][0] + Lred[t][2][0] + Lred[t][3][0] + bc2[0];
    float l1 = Lred[t][0][1] + Lred[t][1][1] + Lred[t][2][1] + Lred[t][3][1] + bc2[1];
    float m = fmaxf(l0, l1);
    float e0 = expf(l0 - m), e1 = expf(l1 - m);
    float inv = 1.0f / (e0 + e1);
    *(float2*)(probs + (size_t)(mt + t) * 2) = make_float2(e0 * inv, e1 * inv);
  }
}

// ---------------------------------------------------------------------------

extern "C" void kernel_launch(void* const* d_in, const int* in_sizes, int n_in,
                              void* d_out, int out_size, void* d_ws, size_t ws_size,
                              hipStream_t stream) {
  const int* indexes = (const int*)d_in[0];
  const float* features = (const float*)d_in[1];
  const int* sub_label = (const int*)d_in[3];
  const int* knn = (const int*)d_in[6];
  const float* all_pred = (const float*)d_in[7];
  const float* W1 = (const float*)d_in[9];
  const float* b1 = (const float*)d_in[10];
  const float* W2 = (const float*)d_in[11];
  const float* b2 = (const float*)d_in[12];
  const float* Wc1 = (const float*)d_in[13];
  const float* bc1 = (const float*)d_in[14];
  const float* pa = (const float*)d_in[15];
  const float* Wc2 = (const float*)d_in[16];
  const float* bc2 = (const float*)d_in[17];

  float* out = (float*)d_out;
  float* probs = out;                    // [B*K*2]
  float* simm = out + 32768;             // [2000]
  float* submean = out + 34768;          // [2000*2048]
  float* nums = out + 4130768;           // [2000]

  // ---- workspace layout (bytes) ----
  char* ws = (char*)d_ws;
  size_t off = 0;
  unsigned short* u_bf = (unsigned short*)(ws + off); off += (size_t)MU * DIM * 2;            // 9.4MB
  unsigned short* UR1  = (unsigned short*)(ws + off); off += (size_t)MU * 2 * NHID * 2;       // 4.7MB
  unsigned short* x1   = (unsigned short*)(ws + off); off += (size_t)MM * NHID * 2;           // 16.8MB
  unsigned short* Z2   = (unsigned short*)(ws + off); off += (size_t)MM * 2 * DOUT * 2;       // 16.8MB
  unsigned short* x2   = (unsigned short*)(ws + off); off += (size_t)MM * DOUT * 2;           // 8.4MB
  unsigned short* W1tp = (unsigned short*)(ws + off); off += (size_t)(2 * NHID) * DIM * 2;    // 4.2MB
  unsigned short* W2tp = (unsigned short*)(ws + off); off += (size_t)(2 * DOUT) * NHID * 2;   // 0.5MB
  unsigned short* Wc1t = (unsigned short*)(ws + off); off += (size_t)DOUT * DOUT * 2;         // 0.13MB
  float* Abuf = (float*)(ws + off); off += (size_t)MM * KK * 4;                               // 4MB
  int* cnt    = (int*)(ws + off); off += NSUB * 4;
  int* cursor = (int*)(ws + off); off += NSUB * 4;
  int* offs   = (int*)(ws + off); off += (NSUB + 4) * 4;
  int* rowlist = (int*)(ws + off); off += (NROW + 8) * 4;
  int* sublabs = (int*)(ws + off); off += (size_t)MM * 4;
  float* norms0 = (float*)(ws + off); off += (size_t)BB * 4;

  hipMemsetAsync(cnt, 0, 2 * NSUB * sizeof(int), stream);

  const int nrb = (NROW + 255) / 256;
  k_count<<<nrb, 256, 0, stream>>>(sub_label, cnt);
  k_scan<<<1, 256, 0, stream>>>(cnt, offs, cursor);
  k_scatter<<<nrb, 256, 0, stream>>>(sub_label, cursor, rowlist);
  k_cluster_sum<<<dim3(NSUB, 2), 256, 0, stream>>>(features, rowlist, offs, submean);
  k_prep<<<BB, 256, 0, stream>>>(indexes, features, sub_label, knn, sublabs, norms0);
  k_gram_mfma<<<BB, 512, 0, stream>>>(indexes, features, submean, sublabs, all_pred, Abuf);

  k_wt_all<<<2368, 256, 0, stream>>>(W1, W2, Wc1, W1tp, W2tp, Wc1t);
  k_ucast<<<MU, 256, 0, stream>>>(submean, cnt, indexes, features, norms0, u_bf, simm, nums);

  // layer 1 (factored): UR1 = [u; r0] @ [W1a|W1b]  (M=2304, K=2048, N=1024)
  k_gemm_bt<DIM, 2 * NHID, MU><<<dim3((2 * NHID) / 128, MU / 128), 256, 0, stream>>>(
      u_bf, W1tp, UR1);
  k_combine_mfma<NHID, true><<<dim3(NHID / 128, BB), 256, 0, stream>>>(
      Abuf, UR1, sublabs, b1, x1);

  // layer 2: Z2 = x1 @ [W2a|W2b]  (M=16384, K=512, N=512)
  k_gemm_bt<NHID, 2 * DOUT, MM><<<dim3((2 * DOUT) / 128, MM / 128), 256, 0, stream>>>(
      x1, W2tp, Z2);
  k_combine_mfma<DOUT, false><<<dim3(DOUT / 128, BB), 256, 0, stream>>>(
      Abuf, Z2, sublabs, b2, x2);

  // fused classifier
  k_cls_fused<<<MM / 128, 512, 0, stream>>>(x2, Wc1t, bc1, pa, Wc2, bc2, probs);
}

// Round 7
// 234.481 us; speedup vs baseline: 7.0725x; 1.0941x over previous
//
#include <hip/hip_runtime.h>
#include <hip/hip_bf16.h>

// ---------------------------------------------------------------------------
// Sub_Cluster_Level_GCN — round 6:
//   * gram reads bf16 u-table via global_load_lds (zero-VALU staging);
//     logits = (u_k·u_j)·n_k·n_j recovered in fp32 epilogue
//   * gemm2+combine2 fused per-sample (Z2 never hits HBM)
// ---------------------------------------------------------------------------

#define NROW 50000
#define DIM  2048
#define NSUB 2000
#define BB   256
#define KK   64
#define NHID 512
#define DOUT 256
#define MM   (BB * KK)   // 16384 rows
#define MU   2304        // 2000 u-rows + 256 r0-rows + 48 pad

typedef __attribute__((ext_vector_type(8))) short bf16x8;
typedef __attribute__((ext_vector_type(4))) float f32x4;

__device__ __forceinline__ unsigned short f2bf(float f) {
  union { float f; unsigned u; } v; v.f = f;
  unsigned r = v.u + 0x7FFF + ((v.u >> 16) & 1);
  return (unsigned short)(r >> 16);
}
__device__ __forceinline__ float bf2f(unsigned short h) {
  union { unsigned u; float f; } v; v.u = ((unsigned)h) << 16;
  return v.f;
}

// ------------------------- segment-mean path -------------------------------

__global__ __launch_bounds__(256) void k_count(const int* __restrict__ sub_label,
                                               int* __restrict__ cnt) {
  int i = blockIdx.x * 256 + threadIdx.x;
  if (i < NROW) atomicAdd(&cnt[sub_label[i]], 1);
}

__global__ __launch_bounds__(256) void k_scan(const int* __restrict__ cnt,
                                              int* __restrict__ offs,
                                              int* __restrict__ cursor) {
  __shared__ int part[256];
  int t = threadIdx.x;
  int base = t * 8;
  int local[8];
  int sum = 0;
#pragma unroll
  for (int i = 0; i < 8; i++) {
    int v = (base + i < NSUB) ? cnt[base + i] : 0;
    local[i] = sum;
    sum += v;
  }
  part[t] = sum;
  __syncthreads();
  for (int off = 1; off < 256; off <<= 1) {
    int v = (t >= off) ? part[t - off] : 0;
    __syncthreads();
    part[t] += v;
    __syncthreads();
  }
  int pre = (t == 0) ? 0 : part[t - 1];
#pragma unroll
  for (int i = 0; i < 8; i++) {
    if (base + i < NSUB) {
      int o = pre + local[i];
      offs[base + i] = o;
      cursor[base + i] = o;
    }
  }
  if (t == 255) offs[NSUB] = pre + sum;
}

__global__ __launch_bounds__(256) void k_scatter(const int* __restrict__ sub_label,
                                                 int* __restrict__ cursor,
                                                 int* __restrict__ rowlist) {
  int i = blockIdx.x * 256 + threadIdx.x;
  if (i < NROW) {
    int s = sub_label[i];
    int pos = atomicAdd(&cursor[s], 1);
    rowlist[pos] = i;
  }
}

// grid (NSUB, 2): block (cluster, column-half). Writes mean only.
__global__ __launch_bounds__(256) void k_cluster_sum(const float* __restrict__ features,
                                                     const int* __restrict__ rowlist,
                                                     const int* __restrict__ offs,
                                                     float* __restrict__ submean) {
  int s = blockIdx.x;
  int col = blockIdx.y * 1024 + threadIdx.x * 4;
  int start = offs[s], end = offs[s + 1];
  float4 acc = make_float4(0.f, 0.f, 0.f, 0.f);
  int r = start;
  for (; r + 3 < end; r += 4) {
    float4 a = *(const float4*)(features + (size_t)rowlist[r] * DIM + col);
    float4 b = *(const float4*)(features + (size_t)rowlist[r + 1] * DIM + col);
    float4 c = *(const float4*)(features + (size_t)rowlist[r + 2] * DIM + col);
    float4 d = *(const float4*)(features + (size_t)rowlist[r + 3] * DIM + col);
    acc.x += (a.x + b.x) + (c.x + d.x);
    acc.y += (a.y + b.y) + (c.y + d.y);
    acc.z += (a.z + b.z) + (c.z + d.z);
    acc.w += (a.w + b.w) + (c.w + d.w);
  }
  for (; r < end; r++) {
    float4 a = *(const float4*)(features + (size_t)rowlist[r] * DIM + col);
    acc.x += a.x; acc.y += a.y; acc.z += a.z; acc.w += a.w;
  }
  int cnt = end - start;
  float inv = 1.0f / (float)(cnt > 0 ? cnt : 1);
  acc.x *= inv; acc.y *= inv; acc.z *= inv; acc.w *= inv;
  *(float4*)(submean + (size_t)s * DIM + col) = acc;
}

// prep: norms0[b] = ||features[idx_b]||, sublabs[b,k]
__global__ __launch_bounds__(256) void k_prep(const int* __restrict__ indexes,
                                              const float* __restrict__ features,
                                              const int* __restrict__ sub_label,
                                              const int* __restrict__ knn,
                                              int* __restrict__ sublabs,
                                              float* __restrict__ norms0) {
  int b = blockIdx.x;
  int t = threadIdx.x;
  const float* row = features + (size_t)indexes[b] * DIM;
  float ss = 0.f;
  for (int i = t; i < DIM; i += 256) {
    float v = row[i];
    ss += v * v;
  }
  __shared__ float red[256];
  red[t] = ss;
  __syncthreads();
  for (int s2 = 128; s2 > 0; s2 >>= 1) {
    if (t < s2) red[t] += red[t + s2];
    __syncthreads();
  }
  if (t == 0) norms0[b] = sqrtf(red[0]);
  if (t < KK) sublabs[b * KK + t] = sub_label[knn[b * KK + t]];
}

// --------- u table + simm + nums: rows 0..1999 u[s]; 2000..2255 r0[b] -------
__global__ __launch_bounds__(256) void k_ucast(const float* __restrict__ submean,
                                               const int* __restrict__ cnt,
                                               const int* __restrict__ indexes,
                                               const float* __restrict__ features,
                                               const float* __restrict__ norms0,
                                               unsigned short* __restrict__ u_bf,
                                               float* __restrict__ simm,
                                               float* __restrict__ nums) {
  int row = blockIdx.x;
  int t = threadIdx.x;
  unsigned short* dst = u_bf + (size_t)row * DIM + t * 8;
  if (row >= NSUB + BB) {
    bf16x8 z = {0, 0, 0, 0, 0, 0, 0, 0};
    *(bf16x8*)dst = z;
    return;
  }
  float scale;
  float4 v0, v1;
  if (row < NSUB) {
    const float* src = submean + (size_t)row * DIM + t * 8;
    v0 = *(const float4*)(src);
    v1 = *(const float4*)(src + 4);
    float ss = v0.x * v0.x + v0.y * v0.y + v0.z * v0.z + v0.w * v0.w +
               v1.x * v1.x + v1.y * v1.y + v1.z * v1.z + v1.w * v1.w;
    __shared__ float red[256];
    red[t] = ss;
    __syncthreads();
    for (int s2 = 128; s2 > 0; s2 >>= 1) {
      if (t < s2) red[t] += red[t + s2];
      __syncthreads();
    }
    float tot = red[0];
    if (t == 0) {
      simm[row] = tot;
      nums[row] = (float)cnt[row];
    }
    scale = (tot > 0.f) ? (1.0f / sqrtf(tot)) : 0.f;
  } else {
    int b = row - NSUB;
    scale = 1.0f / norms0[b];
    const float* src = features + (size_t)indexes[b] * DIM + t * 8;
    v0 = *(const float4*)(src);
    v1 = *(const float4*)(src + 4);
  }
  bf16x8 o;
  o[0] = (short)f2bf(v0.x * scale); o[1] = (short)f2bf(v0.y * scale);
  o[2] = (short)f2bf(v0.z * scale); o[3] = (short)f2bf(v0.w * scale);
  o[4] = (short)f2bf(v1.x * scale); o[5] = (short)f2bf(v1.y * scale);
  o[6] = (short)f2bf(v1.z * scale); o[7] = (short)f2bf(v1.w * scale);
  *(bf16x8*)dst = o;
}

// ------ gram via MFMA from u_bf: A = softmax( (u_k·u_j)·n_k·n_j ∘ wj ) ------
// 512 threads; staging via global_load_lds (linear LDS, pre-swizzled source).
__global__ __launch_bounds__(512) void k_gram_mfma(const unsigned short* __restrict__ u_bf,
                                                   const int* __restrict__ sublabs,
                                                   const float* __restrict__ simm,
                                                   const float* __restrict__ norms0,
                                                   const float* __restrict__ all_pred,
                                                   float* __restrict__ A) {
  int b = blockIdx.x;
  int t = threadIdx.x;
  int w = t >> 6, lane = t & 63;
  __shared__ unsigned short Xs[64][256];   // 32 KB, chunk^row XOR swizzle
  __shared__ float Cs[64][68];
  __shared__ int slr[64];
  __shared__ float nks[64], wjs[64];
  if (t < 64) {
    int sl = (t == 0) ? 0 : sublabs[b * KK + t];
    slr[t] = (t == 0) ? (NSUB + b) : sl;
    float s2 = (t == 0) ? 0.f : simm[sl];
    nks[t] = (t == 0) ? norms0[b] : ((s2 > 0.f) ? sqrtf(s2) : 0.f);
    wjs[t] = expf(all_pred[(size_t)(b * KK + t) * 2 + 1]);
  }
  __syncthreads();

  const int lr = lane & 15, kg = lane >> 4;
  const int rb = w & 3;      // C row-block (16 rows)
  const int cp = w >> 2;     // C col-pair (32 cols)

  // per-lane staging geometry (constant over chunks)
  int rloc[4], clsw[4];
#pragma unroll
  for (int i = 0; i < 4; i++) {
    rloc[i] = w * 8 + i * 2 + (lane >> 5);
    clsw[i] = (lane & 31) ^ (rloc[i] & 7);
  }

  f32x4 acc0 = {0.f, 0.f, 0.f, 0.f}, acc1 = {0.f, 0.f, 0.f, 0.f};

  for (int c = 0; c < 8; c++) {   // K chunks of 256 bf16
    if (c) __syncthreads();       // previous chunk's readers done
#pragma unroll
    for (int i = 0; i < 4; i++) {
      const unsigned short* src =
          u_bf + (size_t)slr[rloc[i]] * DIM + c * 256 + clsw[i] * 8;
      __builtin_amdgcn_global_load_lds(
          (const __attribute__((address_space(1))) void*)src,
          (__attribute__((address_space(3))) void*)(&Xs[w * 8 + i * 2][0]), 16, 0, 0);
    }
    __syncthreads();
#pragma unroll
    for (int ks = 0; ks < 8; ks++) {
      const int ch = ks * 4 + kg;
      int Ra = rb * 16 + lr;
      bf16x8 fa = *(const bf16x8*)&Xs[Ra][((ch ^ (Ra & 7)) << 3)];
      int R0 = (cp * 2) * 16 + lr;
      bf16x8 f0 = *(const bf16x8*)&Xs[R0][((ch ^ (R0 & 7)) << 3)];
      int R1 = (cp * 2 + 1) * 16 + lr;
      bf16x8 f1 = *(const bf16x8*)&Xs[R1][((ch ^ (R1 & 7)) << 3)];
      acc0 = __builtin_amdgcn_mfma_f32_16x16x32_bf16(fa, f0, acc0, 0, 0, 0);
      acc1 = __builtin_amdgcn_mfma_f32_16x16x32_bf16(fa, f1, acc1, 0, 0, 0);
    }
  }

  __syncthreads();
#pragma unroll
  for (int r = 0; r < 4; r++) {
    Cs[rb * 16 + kg * 4 + r][cp * 32 + lr] = acc0[r];
    Cs[rb * 16 + kg * 4 + r][cp * 32 + 16 + lr] = acc1[r];
  }
  __syncthreads();

  int row = t >> 3, seg = t & 7;
  float nr = nks[row];
  float v[8];
  float mx = -1e30f;
#pragma unroll
  for (int i = 0; i < 8; i++) {
    int j = seg * 8 + i;
    v[i] = Cs[row][j] * nr * nks[j] * wjs[j];
    mx = fmaxf(mx, v[i]);
  }
  mx = fmaxf(mx, __shfl_xor(mx, 1));
  mx = fmaxf(mx, __shfl_xor(mx, 2));
  mx = fmaxf(mx, __shfl_xor(mx, 4));
  float sum = 0.f;
#pragma unroll
  for (int i = 0; i < 8; i++) {
    v[i] = expf(v[i] - mx);
    sum += v[i];
  }
  sum += __shfl_xor(sum, 1);
  sum += __shfl_xor(sum, 2);
  sum += __shfl_xor(sum, 4);
  float inv = 1.0f / sum;
  float* outp = A + ((size_t)b * KK + row) * KK + seg * 8;
  *(float4*)(outp)     = make_float4(v[0] * inv, v[1] * inv, v[2] * inv, v[3] * inv);
  *(float4*)(outp + 4) = make_float4(v[4] * inv, v[5] * inv, v[6] * inv, v[7] * inv);
}

// ----------- all weight transpose-casts in one launch (2368 tiles) ----------
__global__ __launch_bounds__(256) void k_wt_all(const float* __restrict__ W1,
                                                const float* __restrict__ W2,
                                                const float* __restrict__ Wc1,
                                                unsigned short* __restrict__ W1t,
                                                unsigned short* __restrict__ W2t,
                                                unsigned short* __restrict__ Wc1t) {
  int bid = blockIdx.x;
  const float* src;
  unsigned short* dst;
  int Nsrc, Kdst, ntn, local;
  if (bid < 1024)      { local = bid;        src = W1;                        dst = W1t;                      Nsrc = NHID; Kdst = DIM;  ntn = 16; }
  else if (bid < 2048) { local = bid - 1024; src = W1 + (size_t)DIM * NHID;   dst = W1t + (size_t)NHID * DIM; Nsrc = NHID; Kdst = DIM;  ntn = 16; }
  else if (bid < 2176) { local = bid - 2048; src = W2;                        dst = W2t;                      Nsrc = DOUT; Kdst = NHID; ntn = 8; }
  else if (bid < 2304) { local = bid - 2176; src = W2 + (size_t)NHID * DOUT;  dst = W2t + (size_t)DOUT * NHID;Nsrc = DOUT; Kdst = NHID; ntn = 8; }
  else                 { local = bid - 2304; src = Wc1;                       dst = Wc1t;                     Nsrc = DOUT; Kdst = DOUT; ntn = 8; }
  int n0 = (local % ntn) * 32, k0 = (local / ntn) * 32;
  __shared__ float tile[32][33];
  int c = threadIdx.x & 31, r8 = threadIdx.x >> 5;
#pragma unroll
  for (int i = 0; i < 4; i++) {
    int r = r8 + i * 8;
    tile[r][c] = src[(size_t)(k0 + r) * Nsrc + n0 + c];
  }
  __syncthreads();
#pragma unroll
  for (int i = 0; i < 4; i++) {
    int r = r8 + i * 8;
    dst[(size_t)(n0 + r) * Kdst + k0 + c] = f2bf(tile[c][r]);
  }
}

// -------------- MFMA GEMM: C = X @ Wt^T ; X[MROWS][KTOT], Wt[NTOT][KTOT] ----
template <int KTOT, int NTOT, int MROWS>
__global__ __launch_bounds__(256) void k_gemm_bt(const unsigned short* __restrict__ X,
                                                 const unsigned short* __restrict__ Wt,
                                                 unsigned short* __restrict__ out) {
  constexpr int GX = NTOT / 128;
  constexpr int NWG = GX * (MROWS / 128);
  static_assert(NWG % 8 == 0, "swizzle needs NWG % 8 == 0");
  const int tid = threadIdx.x;
  const int w = tid >> 6, lane = tid & 63;
  int orig = blockIdx.y * GX + blockIdx.x;
  int swz = (orig & 7) * (NWG / 8) + (orig >> 3);
  const int nt = (swz % GX) * 128;
  const int mt = (swz / GX) * 128;
  __shared__ unsigned short As[128 * 64];
  __shared__ unsigned short Bs[128 * 64];

  f32x4 acc[4][4];
#pragma unroll
  for (int m = 0; m < 4; m++)
#pragma unroll
    for (int n = 0; n < 4; n++) acc[m][n] = (f32x4){0.f, 0.f, 0.f, 0.f};

  const int wr = w >> 1, wc = w & 1;
  const int lr = lane & 15, kg = lane >> 4;

  for (int kc = 0; kc < KTOT / 64; kc++) {
    const int k0 = kc * 64;
#pragma unroll
    for (int i = 0; i < 4; i++) {
      int q = (w * 4 + i) * 64 + lane;
      int r = q >> 3;
      int cl = (q & 7) ^ (r & 7);
      __builtin_amdgcn_global_load_lds(
          (const __attribute__((address_space(1))) void*)(X + (size_t)(mt + r) * KTOT + k0 + cl * 8),
          (__attribute__((address_space(3))) void*)(As + (w * 4 + i) * 512), 16, 0, 0);
    }
#pragma unroll
    for (int i = 0; i < 4; i++) {
      int q = (w * 4 + i) * 64 + lane;
      int r = q >> 3;
      int cl = (q & 7) ^ (r & 7);
      __builtin_amdgcn_global_load_lds(
          (const __attribute__((address_space(1))) void*)(Wt + (size_t)(nt + r) * KTOT + k0 + cl * 8),
          (__attribute__((address_space(3))) void*)(Bs + (w * 4 + i) * 512), 16, 0, 0);
    }
    __syncthreads();
#pragma unroll
    for (int ks = 0; ks < 2; ks++) {
      bf16x8 af[4], bfr[4];
      const int ch = ks * 4 + kg;
#pragma unroll
      for (int m = 0; m < 4; m++) {
        int row = wr * 64 + m * 16 + lr;
        af[m] = *(const bf16x8*)&As[row * 64 + ((ch ^ (row & 7)) << 3)];
      }
#pragma unroll
      for (int n = 0; n < 4; n++) {
        int row = wc * 64 + n * 16 + lr;
        bfr[n] = *(const bf16x8*)&Bs[row * 64 + ((ch ^ (row & 7)) << 3)];
      }
#pragma unroll
      for (int m = 0; m < 4; m++)
#pragma unroll
        for (int n = 0; n < 4; n++)
          acc[m][n] = __builtin_amdgcn_mfma_f32_16x16x32_bf16(af[m], bfr[n], acc[m][n], 0, 0, 0);
    }
    __syncthreads();
  }

#pragma unroll
  for (int m = 0; m < 4; m++) {
    int rm = mt + wr * 64 + m * 16 + kg * 4;
#pragma unroll
    for (int n = 0; n < 4; n++) {
      int col = nt + wc * 64 + n * 16 + lr;
#pragma unroll
      for (int j = 0; j < 4; j++)
        out[(size_t)(rm + j) * NTOT + col] = f2bf(acc[m][n][j]);
    }
  }
}

// ------------- combine1 via MFMA: x1 = relu(Za + P@Bg + bias) ---------------
// P[k][0]=-rs[k], P[k][j>=1]=A[k][j]; Bg[d][0]=Rb[d], Bg[d][j]=U1b[sl_j][d];
// Za = (k>0)(U1a[sl_k][d] - Ra[d]).
template <int DD>
__global__ __launch_bounds__(256) void k_combine1(const float* __restrict__ A,
                                                  const unsigned short* __restrict__ Z,
                                                  const int* __restrict__ sublabs,
                                                  const float* __restrict__ bias,
                                                  unsigned short* __restrict__ out) {
  constexpr int NSTR = 2 * DD;
  const int b = blockIdx.y;
  const int dblk = blockIdx.x * 128;
  const int t = threadIdx.x;
  const int w = t >> 6, lane = t & 63;
  const int lr = lane & 15, kg = lane >> 4;

  __shared__ unsigned short Pl[64][80];
  __shared__ unsigned short Bl[128][80];
  __shared__ unsigned short Ag[64][136];
  __shared__ float Raf[128];
  __shared__ int slh[64];
  __shared__ float red[64][4];

  if (t < 64) slh[t] = sublabs[b * KK + t];
  __syncthreads();

  {
    int pk = t & 63, pp = t >> 6;
    const float* Arow = A + ((size_t)b * KK + pk) * KK;
    float part = 0.f;
#pragma unroll
    for (int e = 0; e < 16; e++) {
      int j = pp * 16 + e;
      float av = Arow[j];
      if (j > 0) {
        Pl[pk][j] = f2bf(av);
        part += av;
      }
    }
    red[pk][pp] = part;
  }
  {
    int gj = t >> 2, gc0 = t & 3;
    size_t brow = (gj == 0) ? (size_t)(NSUB + b) : (size_t)slh[gj];
    const unsigned short* Bp = Z + brow * NSTR + DD + dblk;
#pragma unroll
    for (int it = 0; it < 4; it++) {
      int c = gc0 + it * 4;
      bf16x8 v = *(const bf16x8*)(Bp + c * 8);
#pragma unroll
      for (int e = 0; e < 8; e++) Bl[c * 8 + e][gj] = v[e];
    }
  }
  {
    int ak = t >> 2, ac0 = t & 3;
    const unsigned short* Ap = Z + (size_t)slh[ak] * NSTR + dblk;
#pragma unroll
    for (int it = 0; it < 4; it++) {
      int c = ac0 + it * 4;
      *(bf16x8*)&Ag[ak][c * 8] = *(const bf16x8*)(Ap + c * 8);
    }
    if (t < 128) Raf[t] = bf2f(Z[(size_t)(NSUB + b) * NSTR + dblk + t]);
  }
  __syncthreads();
  if (t < 64) {
    float rs = red[t][0] + red[t][1] + red[t][2] + red[t][3];
    Pl[t][0] = f2bf(-rs);
  }
  __syncthreads();

  f32x4 acc[4][2];
#pragma unroll
  for (int m = 0; m < 4; m++)
#pragma unroll
    for (int n = 0; n < 2; n++) acc[m][n] = (f32x4){0.f, 0.f, 0.f, 0.f};
#pragma unroll
  for (int ks = 0; ks < 2; ks++) {
    const int ch = ks * 4 + kg;
    bf16x8 af[4], bfr[2];
#pragma unroll
    for (int m = 0; m < 4; m++) af[m] = *(const bf16x8*)&Pl[m * 16 + lr][ch * 8];
#pragma unroll
    for (int n = 0; n < 2; n++) {
      int rowd = w * 32 + n * 16 + lr;
      bfr[n] = *(const bf16x8*)&Bl[rowd][ch * 8];
    }
#pragma unroll
    for (int m = 0; m < 4; m++)
#pragma unroll
      for (int n = 0; n < 2; n++)
        acc[m][n] = __builtin_amdgcn_mfma_f32_16x16x32_bf16(af[m], bfr[n], acc[m][n], 0, 0, 0);
  }

#pragma unroll
  for (int m = 0; m < 4; m++) {
#pragma unroll
    for (int n = 0; n < 2; n++) {
      int dcol = w * 32 + n * 16 + lr;
      float bd = bias[dblk + dcol];
#pragma unroll
      for (int j = 0; j < 4; j++) {
        int k = m * 16 + kg * 4 + j;
        float v = acc[m][n][j] + bd;
        if (k > 0) v += bf2f(Ag[k][dcol]) - Raf[dcol];
        out[((size_t)b * KK + k) * DD + dblk + dcol] = f2bf(fmaxf(v, 0.f));
      }
    }
  }
}

// ---- fused layer 2: x2 = relu(Z2a + A@Z2b + b2), Z2 = x1_b @ [W2a|W2b]^T ----
// One block per sample; 512 threads = 8 waves. Z2 stays in LDS.
__global__ __launch_bounds__(512) void k_l2fused(const unsigned short* __restrict__ x1,
                                                 const unsigned short* __restrict__ W2tp,
                                                 const float* __restrict__ A,
                                                 const float* __restrict__ b2,
                                                 unsigned short* __restrict__ x2) {
  __shared__ char lds[79872];
  unsigned short* Xs = (unsigned short*)lds;             // phase A: [64][64]   8KB
  unsigned short* Ws = (unsigned short*)(lds + 8192);    // phase A: [512][64] 64KB
  unsigned short* Pl = (unsigned short*)lds;             // phase B: [64][72]
  unsigned short* Za = (unsigned short*)(lds + 9216);    // phase B: [64][264]
  unsigned short* Zb = (unsigned short*)(lds + 43008);   // phase B: [256][72] (T)
  const int b = blockIdx.x;
  const int t = threadIdx.x;
  const int w = t >> 6, lane = t & 63;
  const int lr = lane & 15, kg = lane >> 4;
  const int wr = w >> 2, wc = w & 3;   // wr: M-half, wc: N-quarter

  f32x4 acc[2][8];
#pragma unroll
  for (int m = 0; m < 2; m++)
#pragma unroll
    for (int n = 0; n < 8; n++) acc[m][n] = (f32x4){0.f, 0.f, 0.f, 0.f};

  for (int kc = 0; kc < 8; kc++) {
    const int k0 = kc * 64;
    if (kc) __syncthreads();
    {
      int r = w * 8 + (lane >> 3);
      int cl = (lane & 7) ^ (r & 7);
      __builtin_amdgcn_global_load_lds(
          (const __attribute__((address_space(1))) void*)(x1 + ((size_t)b * KK + r) * NHID + k0 + cl * 8),
          (__attribute__((address_space(3))) void*)(Xs + w * 512), 16, 0, 0);
    }
#pragma unroll
    for (int i = 0; i < 8; i++) {
      int r = w * 64 + i * 8 + (lane >> 3);
      int cl = (lane & 7) ^ (r & 7);
      __builtin_amdgcn_global_load_lds(
          (const __attribute__((address_space(1))) void*)(W2tp + (size_t)r * NHID + k0 + cl * 8),
          (__attribute__((address_space(3))) void*)(Ws + (w * 64 + i * 8) * 64), 16, 0, 0);
    }
    __syncthreads();
#pragma unroll
    for (int ks = 0; ks < 2; ks++) {
      const int ch = ks * 4 + kg;
      bf16x8 af[2], bfr[8];
#pragma unroll
      for (int m = 0; m < 2; m++) {
        int row = wr * 32 + m * 16 + lr;
        af[m] = *(const bf16x8*)&Xs[row * 64 + ((ch ^ (row & 7)) << 3)];
      }
#pragma unroll
      for (int n = 0; n < 8; n++) {
        int row = wc * 128 + n * 16 + lr;
        bfr[n] = *(const bf16x8*)&Ws[row * 64 + ((ch ^ (row & 7)) << 3)];
      }
#pragma unroll
      for (int m = 0; m < 2; m++)
#pragma unroll
        for (int n = 0; n < 8; n++)
          acc[m][n] = __builtin_amdgcn_mfma_f32_16x16x32_bf16(af[m], bfr[n], acc[m][n], 0, 0, 0);
    }
  }
  __syncthreads();   // phase A LDS dead

  // scatter Z2 fragments: cols <256 -> Za [k][d]; cols >=256 -> Zb [d][k] (T)
#pragma unroll
  for (int m = 0; m < 2; m++) {
#pragma unroll
    for (int n = 0; n < 8; n++) {
      int col = wc * 128 + n * 16 + lr;
#pragma unroll
      for (int j = 0; j < 4; j++) {
        int row = wr * 32 + m * 16 + kg * 4 + j;
        unsigned short hv = f2bf(acc[m][n][j]);
        if (col < 256) Za[row * 264 + col] = hv;
        else           Zb[(col - 256) * 72 + row] = hv;
      }
    }
  }
  // P = bf16(A[b]) : thread t covers row t>>3, cols (t&7)*8..+7
  {
    const float* Ap = A + (size_t)b * KK * KK + t * 8;
    float4 f0 = *(const float4*)(Ap);
    float4 f1 = *(const float4*)(Ap + 4);
    bf16x8 hv;
    hv[0] = (short)f2bf(f0.x); hv[1] = (short)f2bf(f0.y);
    hv[2] = (short)f2bf(f0.z); hv[3] = (short)f2bf(f0.w);
    hv[4] = (short)f2bf(f1.x); hv[5] = (short)f2bf(f1.y);
    hv[6] = (short)f2bf(f1.z); hv[7] = (short)f2bf(f1.w);
    *(bf16x8*)&Pl[(t >> 3) * 72 + (t & 7) * 8] = hv;
  }
  __syncthreads();

  // out[k][d] = P @ ZbT ; wave w owns d block w*32
  f32x4 acc2[4][2];
#pragma unroll
  for (int m = 0; m < 4; m++)
#pragma unroll
    for (int n = 0; n < 2; n++) acc2[m][n] = (f32x4){0.f, 0.f, 0.f, 0.f};
#pragma unroll
  for (int ks = 0; ks < 2; ks++) {
    const int ch = ks * 4 + kg;
    bf16x8 af[4], bfr[2];
#pragma unroll
    for (int m = 0; m < 4; m++) af[m] = *(const bf16x8*)&Pl[(m * 16 + lr) * 72 + ch * 8];
#pragma unroll
    for (int n = 0; n < 2; n++) bfr[n] = *(const bf16x8*)&Zb[(w * 32 + n * 16 + lr) * 72 + ch * 8];
#pragma unroll
    for (int m = 0; m < 4; m++)
#pragma unroll
      for (int n = 0; n < 2; n++)
        acc2[m][n] = __builtin_amdgcn_mfma_f32_16x16x32_bf16(af[m], bfr[n], acc2[m][n], 0, 0, 0);
  }

#pragma unroll
  for (int m = 0; m < 4; m++) {
#pragma unroll
    for (int n = 0; n < 2; n++) {
      int d = w * 32 + n * 16 + lr;
      float bd = b2[d];
#pragma unroll
      for (int j = 0; j < 4; j++) {
        int k = m * 16 + kg * 4 + j;
        float v = acc2[m][n][j] + bf2f(Za[k * 264 + d]) + bd;
        x2[((size_t)b * KK + k) * DOUT + d] = f2bf(fmaxf(v, 0.f));
      }
    }
  }
}

// ---- fused classifier: probs = softmax( PReLU(x2@Wc1+bc1) @ Wc2 + bc2 ) ----
__global__ __launch_bounds__(512) void k_cls_fused(const unsigned short* __restrict__ X,
                                                   const unsigned short* __restrict__ Wt,
                                                   const float* __restrict__ bc1,
                                                   const float* __restrict__ pa,
                                                   const float* __restrict__ Wc2,
                                                   const float* __restrict__ bc2,
                                                   float* __restrict__ probs) {
  const int t = threadIdx.x;
  const int w = t >> 6, lane = t & 63;
  const int lr = lane & 15, kg = lane >> 4;
  const int wr = w >> 2, wc = w & 3;
  const int mt = blockIdx.x * 128;
  __shared__ unsigned short As[128 * 64];
  __shared__ unsigned short Bs[256 * 64];
  __shared__ float Lred[128][4][2];

  f32x4 acc[4][4];
#pragma unroll
  for (int m = 0; m < 4; m++)
#pragma unroll
    for (int n = 0; n < 4; n++) acc[m][n] = (f32x4){0.f, 0.f, 0.f, 0.f};

  for (int kc = 0; kc < 4; kc++) {
    const int k0 = kc * 64;
#pragma unroll
    for (int i = 0; i < 2; i++) {
      int q = (w * 2 + i) * 64 + lane;
      int r = q >> 3;
      int cl = (q & 7) ^ (r & 7);
      __builtin_amdgcn_global_load_lds(
          (const __attribute__((address_space(1))) void*)(X + (size_t)(mt + r) * DOUT + k0 + cl * 8),
          (__attribute__((address_space(3))) void*)(As + (w * 2 + i) * 512), 16, 0, 0);
    }
#pragma unroll
    for (int i = 0; i < 4; i++) {
      int q = (w * 4 + i) * 64 + lane;
      int r = q >> 3;
      int cl = (q & 7) ^ (r & 7);
      __builtin_amdgcn_global_load_lds(
          (const __attribute__((address_space(1))) void*)(Wt + (size_t)r * DOUT + k0 + cl * 8),
          (__attribute__((address_space(3))) void*)(Bs + (w * 4 + i) * 512), 16, 0, 0);
    }
    __syncthreads();
#pragma unroll
    for (int ks = 0; ks < 2; ks++) {
      bf16x8 af[4], bfr[4];
      const int ch = ks * 4 + kg;
#pragma unroll
      for (int m = 0; m < 4; m++) {
        int row = wr * 64 + m * 16 + lr;
        af[m] = *(const bf16x8*)&As[row * 64 + ((ch ^ (row & 7)) << 3)];
      }
#pragma unroll
      for (int n = 0; n < 4; n++) {
        int row = wc * 64 + n * 16 + lr;
        bfr[n] = *(const bf16x8*)&Bs[row * 64 + ((ch ^ (row & 7)) << 3)];
      }
#pragma unroll
      for (int m = 0; m < 4; m++)
#pragma unroll
        for (int n = 0; n < 4; n++)
          acc[m][n] = __builtin_amdgcn_mfma_f32_16x16x32_bf16(af[m], bfr[n], acc[m][n], 0, 0, 0);
    }
    __syncthreads();
  }

  float bc1v[4], pav[4], w0v[4], w1v[4];
#pragma unroll
  for (int n = 0; n < 4; n++) {
    int col = wc * 64 + n * 16 + lr;
    bc1v[n] = bc1[col];
    pav[n] = pa[col];
    w0v[n] = Wc2[col * 2 + 0];
    w1v[n] = Wc2[col * 2 + 1];
  }
#pragma unroll
  for (int m = 0; m < 4; m++) {
#pragma unroll
    for (int j = 0; j < 4; j++) {
      float p0 = 0.f, p1 = 0.f;
#pragma unroll
      for (int n = 0; n < 4; n++) {
        float h = acc[m][n][j] + bc1v[n];
        h = (h >= 0.f) ? h : pav[n] * h;
        p0 += h * w0v[n];
        p1 += h * w1v[n];
      }
      p0 += __shfl_xor(p0, 1); p1 += __shfl_xor(p1, 1);
      p0 += __shfl_xor(p0, 2); p1 += __shfl_xor(p1, 2);
      p0 += __shfl_xor(p0, 4); p1 += __shfl_xor(p1, 4);
      p0 += __shfl_xor(p0, 8); p1 += __shfl_xor(p1, 8);
      if (lr == 0) {
        int rowl = wr * 64 + m * 16 + kg * 4 + j;
        Lred[rowl][wc][0] = p0;
        Lred[rowl][wc][1] = p1;
      }
    }
  }
  __syncthreads();
  if (t < 128) {
    float l0 = Lred[t][0][0] + Lred[t][1][0] + Lred[t][2][0] + Lred[t][3][0] + bc2[0];
    float l1 = Lred[t][0][1] + Lred[t][1][1] + Lred[t][2][1] + Lred[t][3][1] + bc2[1];
    float m = fmaxf(l0, l1);
    float e0 = expf(l0 - m), e1 = expf(l1 - m);
    float inv = 1.0f / (e0 + e1);
    *(float2*)(probs + (size_t)(mt + t) * 2) = make_float2(e0 * inv, e1 * inv);
  }
}

// ---------------------------------------------------------------------------

extern "C" void kernel_launch(void* const* d_in, const int* in_sizes, int n_in,
                              void* d_out, int out_size, void* d_ws, size_t ws_size,
                              hipStream_t stream) {
  const int* indexes = (const int*)d_in[0];
  const float* features = (const float*)d_in[1];
  const int* sub_label = (const int*)d_in[3];
  const int* knn = (const int*)d_in[6];
  const float* all_pred = (const float*)d_in[7];
  const float* W1 = (const float*)d_in[9];
  const float* b1 = (const float*)d_in[10];
  const float* W2 = (const float*)d_in[11];
  const float* b2 = (const float*)d_in[12];
  const float* Wc1 = (const float*)d_in[13];
  const float* bc1 = (const float*)d_in[14];
  const float* pa = (const float*)d_in[15];
  const float* Wc2 = (const float*)d_in[16];
  const float* bc2 = (const float*)d_in[17];

  float* out = (float*)d_out;
  float* probs = out;                    // [B*K*2]
  float* simm = out + 32768;             // [2000]
  float* submean = out + 34768;          // [2000*2048]
  float* nums = out + 4130768;           // [2000]

  // ---- workspace layout (bytes) ----
  char* ws = (char*)d_ws;
  size_t off = 0;
  unsigned short* u_bf = (unsigned short*)(ws + off); off += (size_t)MU * DIM * 2;            // 9.4MB
  unsigned short* UR1  = (unsigned short*)(ws + off); off += (size_t)MU * 2 * NHID * 2;       // 4.7MB
  unsigned short* x1   = (unsigned short*)(ws + off); off += (size_t)MM * NHID * 2;           // 16.8MB
  unsigned short* x2   = (unsigned short*)(ws + off); off += (size_t)MM * DOUT * 2;           // 8.4MB
  unsigned short* W1tp = (unsigned short*)(ws + off); off += (size_t)(2 * NHID) * DIM * 2;    // 4.2MB
  unsigned short* W2tp = (unsigned short*)(ws + off); off += (size_t)(2 * DOUT) * NHID * 2;   // 0.5MB
  unsigned short* Wc1t = (unsigned short*)(ws + off); off += (size_t)DOUT * DOUT * 2;         // 0.13MB
  float* Abuf = (float*)(ws + off); off += (size_t)MM * KK * 4;                               // 4MB
  int* cnt    = (int*)(ws + off); off += NSUB * 4;
  int* cursor = (int*)(ws + off); off += NSUB * 4;
  int* offs   = (int*)(ws + off); off += (NSUB + 4) * 4;
  int* rowlist = (int*)(ws + off); off += (NROW + 8) * 4;
  int* sublabs = (int*)(ws + off); off += (size_t)MM * 4;
  float* norms0 = (float*)(ws + off); off += (size_t)BB * 4;

  hipMemsetAsync(cnt, 0, 2 * NSUB * sizeof(int), stream);

  const int nrb = (NROW + 255) / 256;
  k_count<<<nrb, 256, 0, stream>>>(sub_label, cnt);
  k_scan<<<1, 256, 0, stream>>>(cnt, offs, cursor);
  k_scatter<<<nrb, 256, 0, stream>>>(sub_label, cursor, rowlist);
  k_cluster_sum<<<dim3(NSUB, 2), 256, 0, stream>>>(features, rowlist, offs, submean);
  k_prep<<<BB, 256, 0, stream>>>(indexes, features, sub_label, knn, sublabs, norms0);
  k_wt_all<<<2368, 256, 0, stream>>>(W1, W2, Wc1, W1tp, W2tp, Wc1t);
  k_ucast<<<MU, 256, 0, stream>>>(submean, cnt, indexes, features, norms0, u_bf, simm, nums);
  k_gram_mfma<<<BB, 512, 0, stream>>>(u_bf, sublabs, simm, norms0, all_pred, Abuf);

  // layer 1 (factored): UR1 = [u; r0] @ [W1a|W1b]  (M=2304, K=2048, N=1024)
  k_gemm_bt<DIM, 2 * NHID, MU><<<dim3((2 * NHID) / 128, MU / 128), 256, 0, stream>>>(
      u_bf, W1tp, UR1);
  k_combine1<NHID><<<dim3(NHID / 128, BB), 256, 0, stream>>>(
      Abuf, UR1, sublabs, b1, x1);

  // layer 2 fused: x2 = relu(Z2a + A@Z2b + b2), Z2 in LDS
  k_l2fused<<<BB, 512, 0, stream>>>(x1, W2tp, Abuf, b2, x2);

  // fused classifier
  k_cls_fused<<<MM / 128, 512, 0, stream>>>(x2, Wc1t, bc1, pa, Wc2, bc2, probs);
}

// Round 8
// 207.249 us; speedup vs baseline: 8.0018x; 1.1314x over previous
//
#include <hip/hip_runtime.h>
#include <hip/hip_bf16.h>

// ---------------------------------------------------------------------------
// Sub_Cluster_Level_GCN — round 7: launch-count consolidation
//   * count/scan/scatter -> single bucketed k_build (CAP=128)
//   * cluster_sum full-row, directly emits submean + simm + nums + u_bf rows
//   * prep gone (r0 norm in misc kernel; sublabs gathered by gram)
//   * wt transposes + r0-cast fused (block-range dispatch)
//   * gram + gemm1 fused (400 blocks, 512 thr) — fills idle CUs
// ---------------------------------------------------------------------------

#define NROW 50000
#define DIM  2048
#define NSUB 2000
#define BB   256
#define KK   64
#define NHID 512
#define DOUT 256
#define MM   (BB * KK)   // 16384
#define MU   2304        // 2000 u + 256 r0 + 48 pad
#define CAP  128         // rowlist bucket capacity (max cluster ~50 @ λ=25)

typedef __attribute__((ext_vector_type(8))) short bf16x8;
typedef __attribute__((ext_vector_type(4))) float f32x4;

__device__ __forceinline__ unsigned short f2bf(float f) {
  union { float f; unsigned u; } v; v.f = f;
  unsigned r = v.u + 0x7FFF + ((v.u >> 16) & 1);
  return (unsigned short)(r >> 16);
}
__device__ __forceinline__ float bf2f(unsigned short h) {
  union { unsigned u; float f; } v; v.u = ((unsigned)h) << 16;
  return v.f;
}

// ---------------- build: bucketed rowlist in one pass -----------------------
__global__ __launch_bounds__(256) void k_build(const int* __restrict__ sub_label,
                                               int* __restrict__ cnt,
                                               int* __restrict__ rowlist) {
  int i = blockIdx.x * 256 + threadIdx.x;
  if (i < NROW) {
    int s = sub_label[i];
    int pos = atomicAdd(&cnt[s], 1);
    rowlist[(s << 7) + pos] = i;
  }
}

// ------- cluster_sum: mean + simm + nums + normalized bf16 u-row ------------
__global__ __launch_bounds__(256) void k_cluster_sum(const float* __restrict__ features,
                                                     const int* __restrict__ rowlist,
                                                     const int* __restrict__ cnt,
                                                     float* __restrict__ submean,
                                                     float* __restrict__ simm,
                                                     float* __restrict__ nums,
                                                     unsigned short* __restrict__ u_bf) {
  int s = blockIdx.x;
  int t = threadIdx.x;
  int n = cnt[s];
  const int* rl = rowlist + (s << 7);
  float acc[8] = {0, 0, 0, 0, 0, 0, 0, 0};
  int r = 0;
  for (; r + 3 < n; r += 4) {
    const float* rA = features + (size_t)rl[r] * DIM + t * 8;
    const float* rB = features + (size_t)rl[r + 1] * DIM + t * 8;
    const float* rC = features + (size_t)rl[r + 2] * DIM + t * 8;
    const float* rD = features + (size_t)rl[r + 3] * DIM + t * 8;
    float4 a0 = *(const float4*)(rA), a1 = *(const float4*)(rA + 4);
    float4 b0 = *(const float4*)(rB), b1 = *(const float4*)(rB + 4);
    float4 c0 = *(const float4*)(rC), c1 = *(const float4*)(rC + 4);
    float4 d0 = *(const float4*)(rD), d1 = *(const float4*)(rD + 4);
    acc[0] += (a0.x + b0.x) + (c0.x + d0.x);
    acc[1] += (a0.y + b0.y) + (c0.y + d0.y);
    acc[2] += (a0.z + b0.z) + (c0.z + d0.z);
    acc[3] += (a0.w + b0.w) + (c0.w + d0.w);
    acc[4] += (a1.x + b1.x) + (c1.x + d1.x);
    acc[5] += (a1.y + b1.y) + (c1.y + d1.y);
    acc[6] += (a1.z + b1.z) + (c1.z + d1.z);
    acc[7] += (a1.w + b1.w) + (c1.w + d1.w);
  }
  for (; r < n; r++) {
    const float* row = features + (size_t)rl[r] * DIM + t * 8;
    float4 v0 = *(const float4*)(row);
    float4 v1 = *(const float4*)(row + 4);
    acc[0] += v0.x; acc[1] += v0.y; acc[2] += v0.z; acc[3] += v0.w;
    acc[4] += v1.x; acc[5] += v1.y; acc[6] += v1.z; acc[7] += v1.w;
  }
  float inv = 1.0f / (float)(n > 0 ? n : 1);
  float m[8];
  float ss = 0.f;
#pragma unroll
  for (int i = 0; i < 8; i++) { m[i] = acc[i] * inv; ss += m[i] * m[i]; }
  float* outp = submean + (size_t)s * DIM + t * 8;
  *(float4*)(outp)     = make_float4(m[0], m[1], m[2], m[3]);
  *(float4*)(outp + 4) = make_float4(m[4], m[5], m[6], m[7]);
  __shared__ float red[256];
  red[t] = ss;
  __syncthreads();
  for (int s2 = 128; s2 > 0; s2 >>= 1) {
    if (t < s2) red[t] += red[t + s2];
    __syncthreads();
  }
  float tot = red[0];
  if (t == 0) {
    simm[s] = tot;
    nums[s] = (float)n;
  }
  float scale = (tot > 0.f) ? (1.0f / sqrtf(tot)) : 0.f;
  bf16x8 o;
  o[0] = (short)f2bf(m[0] * scale); o[1] = (short)f2bf(m[1] * scale);
  o[2] = (short)f2bf(m[2] * scale); o[3] = (short)f2bf(m[3] * scale);
  o[4] = (short)f2bf(m[4] * scale); o[5] = (short)f2bf(m[5] * scale);
  o[6] = (short)f2bf(m[6] * scale); o[7] = (short)f2bf(m[7] * scale);
  *(bf16x8*)(u_bf + (size_t)s * DIM + t * 8) = o;
}

// ------- misc: W transposes (2368 tiles) + r0 cast/norm (304 rows) ----------
__global__ __launch_bounds__(256) void k_misc(const float* __restrict__ W1,
                                              const float* __restrict__ W2,
                                              const float* __restrict__ Wc1,
                                              unsigned short* __restrict__ W1t,
                                              unsigned short* __restrict__ W2t,
                                              unsigned short* __restrict__ Wc1t,
                                              const int* __restrict__ indexes,
                                              const float* __restrict__ features,
                                              unsigned short* __restrict__ u_bf,
                                              float* __restrict__ norms0) {
  int bid = blockIdx.x;
  int t = threadIdx.x;
  if (bid >= 2368) {
    int row = bid - 2368;              // 0..303
    unsigned short* dst = u_bf + (size_t)(NSUB + row) * DIM + t * 8;
    if (row >= BB) {
      bf16x8 z = {0, 0, 0, 0, 0, 0, 0, 0};
      *(bf16x8*)dst = z;
      return;
    }
    const float* src = features + (size_t)indexes[row] * DIM + t * 8;
    float4 v0 = *(const float4*)(src);
    float4 v1 = *(const float4*)(src + 4);
    float ss = v0.x * v0.x + v0.y * v0.y + v0.z * v0.z + v0.w * v0.w +
               v1.x * v1.x + v1.y * v1.y + v1.z * v1.z + v1.w * v1.w;
    __shared__ float red[256];
    red[t] = ss;
    __syncthreads();
    for (int s2 = 128; s2 > 0; s2 >>= 1) {
      if (t < s2) red[t] += red[t + s2];
      __syncthreads();
    }
    float nrm = sqrtf(red[0]);
    if (t == 0) norms0[row] = nrm;
    float scale = 1.0f / nrm;
    bf16x8 o;
    o[0] = (short)f2bf(v0.x * scale); o[1] = (short)f2bf(v0.y * scale);
    o[2] = (short)f2bf(v0.z * scale); o[3] = (short)f2bf(v0.w * scale);
    o[4] = (short)f2bf(v1.x * scale); o[5] = (short)f2bf(v1.y * scale);
    o[6] = (short)f2bf(v1.z * scale); o[7] = (short)f2bf(v1.w * scale);
    *(bf16x8*)dst = o;
    return;
  }
  const float* src;
  unsigned short* dst;
  int Nsrc, Kdst, ntn, local;
  if (bid < 1024)      { local = bid;        src = W1;                        dst = W1t;                      Nsrc = NHID; Kdst = DIM;  ntn = 16; }
  else if (bid < 2048) { local = bid - 1024; src = W1 + (size_t)DIM * NHID;   dst = W1t + (size_t)NHID * DIM; Nsrc = NHID; Kdst = DIM;  ntn = 16; }
  else if (bid < 2176) { local = bid - 2048; src = W2;                        dst = W2t;                      Nsrc = DOUT; Kdst = NHID; ntn = 8; }
  else if (bid < 2304) { local = bid - 2176; src = W2 + (size_t)NHID * DOUT;  dst = W2t + (size_t)DOUT * NHID;Nsrc = DOUT; Kdst = NHID; ntn = 8; }
  else                 { local = bid - 2304; src = Wc1;                       dst = Wc1t;                     Nsrc = DOUT; Kdst = DOUT; ntn = 8; }
  int n0 = (local % ntn) * 32, k0 = (local / ntn) * 32;
  __shared__ float tile[32][33];
  int c = t & 31, r8 = t >> 5;
#pragma unroll
  for (int i = 0; i < 4; i++) {
    int r = r8 + i * 8;
    tile[r][c] = src[(size_t)(k0 + r) * Nsrc + n0 + c];
  }
  __syncthreads();
#pragma unroll
  for (int i = 0; i < 4; i++) {
    int r = r8 + i * 8;
    dst[(size_t)(n0 + r) * Kdst + k0 + c] = f2bf(tile[c][r]);
  }
}

// ------- fused gram (256 blocks) + gemm1 (144 tiles), 512 threads -----------
// blocks [0,144): UR1 = u_bf @ W1tp^T (M=2304,K=2048,N=1024), 8 waves 2Mx4N
// blocks [144,400): gram sample b: A = softmax((u_k·u_j)·n_k·n_j ∘ wj),
//                   also gathers+writes sublabs.
#define NGEMM 144
__global__ __launch_bounds__(512) void k_gram_gemm(const unsigned short* __restrict__ u_bf,
                                                   const unsigned short* __restrict__ W1tp,
                                                   unsigned short* __restrict__ UR1,
                                                   const int* __restrict__ sub_label,
                                                   const int* __restrict__ knn,
                                                   const float* __restrict__ simm,
                                                   const float* __restrict__ norms0,
                                                   const float* __restrict__ all_pred,
                                                   float* __restrict__ A,
                                                   int* __restrict__ sublabs) {
  __shared__ char big[32768];
  __shared__ int slr[64];
  __shared__ float nks[64], wjs[64];
  const int t = threadIdx.x;
  const int w = t >> 6, lane = t & 63;
  const int lr = lane & 15, kg = lane >> 4;

  if (blockIdx.x < NGEMM) {
    // ---------------- gemm1 tile ----------------
    constexpr int KTOT = DIM;
    constexpr int NTOT = 2 * NHID;
    unsigned short* As = (unsigned short*)big;            // [128][64]
    unsigned short* Bs = (unsigned short*)(big + 16384);  // [128][64]
    int orig = blockIdx.x;
    int swz = (orig & 7) * (NGEMM / 8) + (orig >> 3);
    const int nt = (swz & 7) * 128;       // 8 N-tiles
    const int mt = (swz >> 3) * 128;      // 18 M-tiles
    const int wr = w >> 2, wc = w & 3;

    f32x4 acc[4][2];
#pragma unroll
    for (int m = 0; m < 4; m++)
#pragma unroll
      for (int n = 0; n < 2; n++) acc[m][n] = (f32x4){0.f, 0.f, 0.f, 0.f};

    for (int kc = 0; kc < KTOT / 64; kc++) {
      const int k0 = kc * 64;
#pragma unroll
      for (int i = 0; i < 2; i++) {
        int q = (w * 2 + i) * 64 + lane;
        int r = q >> 3;
        int cl = (q & 7) ^ (r & 7);
        __builtin_amdgcn_global_load_lds(
            (const __attribute__((address_space(1))) void*)(u_bf + (size_t)(mt + r) * KTOT + k0 + cl * 8),
            (__attribute__((address_space(3))) void*)(As + (w * 2 + i) * 512), 16, 0, 0);
      }
#pragma unroll
      for (int i = 0; i < 2; i++) {
        int q = (w * 2 + i) * 64 + lane;
        int r = q >> 3;
        int cl = (q & 7) ^ (r & 7);
        __builtin_amdgcn_global_load_lds(
            (const __attribute__((address_space(1))) void*)(W1tp + (size_t)(nt + r) * KTOT + k0 + cl * 8),
            (__attribute__((address_space(3))) void*)(Bs + (w * 2 + i) * 512), 16, 0, 0);
      }
      __syncthreads();
#pragma unroll
      for (int ks = 0; ks < 2; ks++) {
        bf16x8 af[4], bfr[2];
        const int ch = ks * 4 + kg;
#pragma unroll
        for (int m = 0; m < 4; m++) {
          int row = wr * 64 + m * 16 + lr;
          af[m] = *(const bf16x8*)&As[row * 64 + ((ch ^ (row & 7)) << 3)];
        }
#pragma unroll
        for (int n = 0; n < 2; n++) {
          int row = wc * 32 + n * 16 + lr;
          bfr[n] = *(const bf16x8*)&Bs[row * 64 + ((ch ^ (row & 7)) << 3)];
        }
#pragma unroll
        for (int m = 0; m < 4; m++)
#pragma unroll
          for (int n = 0; n < 2; n++)
            acc[m][n] = __builtin_amdgcn_mfma_f32_16x16x32_bf16(af[m], bfr[n], acc[m][n], 0, 0, 0);
      }
      __syncthreads();
    }
#pragma unroll
    for (int m = 0; m < 4; m++) {
      int rm = mt + wr * 64 + m * 16 + kg * 4;
#pragma unroll
      for (int n = 0; n < 2; n++) {
        int col = nt + wc * 32 + n * 16 + lr;
#pragma unroll
        for (int j = 0; j < 4; j++)
          UR1[(size_t)(rm + j) * NTOT + col] = f2bf(acc[m][n][j]);
      }
    }
    return;
  }

  // ---------------- gram sample ----------------
  int b = blockIdx.x - NGEMM;
  unsigned short* Xs = (unsigned short*)big;   // [64][256] swizzled
  if (t < 64) {
    int sl = (t == 0) ? 0 : sub_label[knn[b * KK + t]];
    if (t > 0) sublabs[b * KK + t] = sl;
    else sublabs[b * KK] = sub_label[knn[b * KK]];
    slr[t] = (t == 0) ? (NSUB + b) : sl;
    float s2 = (t == 0) ? 0.f : simm[sl];
    nks[t] = (t == 0) ? norms0[b] : ((s2 > 0.f) ? sqrtf(s2) : 0.f);
    wjs[t] = expf(all_pred[(size_t)(b * KK + t) * 2 + 1]);
  }
  __syncthreads();

  const int rb = w & 3;
  const int cp = w >> 2;
  int rloc[4], clsw[4];
#pragma unroll
  for (int i = 0; i < 4; i++) {
    rloc[i] = w * 8 + i * 2 + (lane >> 5);
    clsw[i] = (lane & 31) ^ (rloc[i] & 7);
  }

  f32x4 acc0 = {0.f, 0.f, 0.f, 0.f}, acc1 = {0.f, 0.f, 0.f, 0.f};
  for (int c = 0; c < 8; c++) {
    if (c) __syncthreads();
#pragma unroll
    for (int i = 0; i < 4; i++) {
      const unsigned short* src =
          u_bf + (size_t)slr[rloc[i]] * DIM + c * 256 + clsw[i] * 8;
      __builtin_amdgcn_global_load_lds(
          (const __attribute__((address_space(1))) void*)src,
          (__attribute__((address_space(3))) void*)(Xs + (w * 8 + i * 2) * 256), 16, 0, 0);
    }
    __syncthreads();
#pragma unroll
    for (int ks = 0; ks < 8; ks++) {
      const int ch = ks * 4 + kg;
      int Ra = rb * 16 + lr;
      bf16x8 fa = *(const bf16x8*)&Xs[Ra * 256 + ((ch ^ (Ra & 7)) << 3)];
      int R0 = (cp * 2) * 16 + lr;
      bf16x8 f0 = *(const bf16x8*)&Xs[R0 * 256 + ((ch ^ (R0 & 7)) << 3)];
      int R1 = (cp * 2 + 1) * 16 + lr;
      bf16x8 f1 = *(const bf16x8*)&Xs[R1 * 256 + ((ch ^ (R1 & 7)) << 3)];
      acc0 = __builtin_amdgcn_mfma_f32_16x16x32_bf16(fa, f0, acc0, 0, 0, 0);
      acc1 = __builtin_amdgcn_mfma_f32_16x16x32_bf16(fa, f1, acc1, 0, 0, 0);
    }
  }

  __syncthreads();
  float* Cs = (float*)big;   // [64][68] — aliases Xs (dead now)
#pragma unroll
  for (int r = 0; r < 4; r++) {
    Cs[(rb * 16 + kg * 4 + r) * 68 + cp * 32 + lr] = acc0[r];
    Cs[(rb * 16 + kg * 4 + r) * 68 + cp * 32 + 16 + lr] = acc1[r];
  }
  __syncthreads();

  int row = t >> 3, seg = t & 7;
  float nr = nks[row];
  float v[8];
  float mx = -1e30f;
#pragma unroll
  for (int i = 0; i < 8; i++) {
    int j = seg * 8 + i;
    v[i] = Cs[row * 68 + j] * nr * nks[j] * wjs[j];
    mx = fmaxf(mx, v[i]);
  }
  mx = fmaxf(mx, __shfl_xor(mx, 1));
  mx = fmaxf(mx, __shfl_xor(mx, 2));
  mx = fmaxf(mx, __shfl_xor(mx, 4));
  float sum = 0.f;
#pragma unroll
  for (int i = 0; i < 8; i++) {
    v[i] = expf(v[i] - mx);
    sum += v[i];
  }
  sum += __shfl_xor(sum, 1);
  sum += __shfl_xor(sum, 2);
  sum += __shfl_xor(sum, 4);
  float inv = 1.0f / sum;
  float* outp = A + ((size_t)b * KK + row) * KK + seg * 8;
  *(float4*)(outp)     = make_float4(v[0] * inv, v[1] * inv, v[2] * inv, v[3] * inv);
  *(float4*)(outp + 4) = make_float4(v[4] * inv, v[5] * inv, v[6] * inv, v[7] * inv);
}

// ------------- combine1 via MFMA: x1 = relu(Za + P@Bg + bias) ---------------
template <int DD>
__global__ __launch_bounds__(256) void k_combine1(const float* __restrict__ A,
                                                  const unsigned short* __restrict__ Z,
                                                  const int* __restrict__ sublabs,
                                                  const float* __restrict__ bias,
                                                  unsigned short* __restrict__ out) {
  constexpr int NSTR = 2 * DD;
  const int b = blockIdx.y;
  const int dblk = blockIdx.x * 128;
  const int t = threadIdx.x;
  const int w = t >> 6, lane = t & 63;
  const int lr = lane & 15, kg = lane >> 4;

  __shared__ unsigned short Pl[64][80];
  __shared__ unsigned short Bl[128][80];
  __shared__ unsigned short Ag[64][136];
  __shared__ float Raf[128];
  __shared__ int slh[64];
  __shared__ float red[64][4];

  if (t < 64) slh[t] = sublabs[b * KK + t];
  __syncthreads();

  {
    int pk = t & 63, pp = t >> 6;
    const float* Arow = A + ((size_t)b * KK + pk) * KK;
    float part = 0.f;
#pragma unroll
    for (int e = 0; e < 16; e++) {
      int j = pp * 16 + e;
      float av = Arow[j];
      if (j > 0) {
        Pl[pk][j] = f2bf(av);
        part += av;
      }
    }
    red[pk][pp] = part;
  }
  {
    int gj = t >> 2, gc0 = t & 3;
    size_t brow = (gj == 0) ? (size_t)(NSUB + b) : (size_t)slh[gj];
    const unsigned short* Bp = Z + brow * NSTR + DD + dblk;
#pragma unroll
    for (int it = 0; it < 4; it++) {
      int c = gc0 + it * 4;
      bf16x8 v = *(const bf16x8*)(Bp + c * 8);
#pragma unroll
      for (int e = 0; e < 8; e++) Bl[c * 8 + e][gj] = v[e];
    }
  }
  {
    int ak = t >> 2, ac0 = t & 3;
    const unsigned short* Ap = Z + (size_t)slh[ak] * NSTR + dblk;
#pragma unroll
    for (int it = 0; it < 4; it++) {
      int c = ac0 + it * 4;
      *(bf16x8*)&Ag[ak][c * 8] = *(const bf16x8*)(Ap + c * 8);
    }
    if (t < 128) Raf[t] = bf2f(Z[(size_t)(NSUB + b) * NSTR + dblk + t]);
  }
  __syncthreads();
  if (t < 64) {
    float rs = red[t][0] + red[t][1] + red[t][2] + red[t][3];
    Pl[t][0] = f2bf(-rs);
  }
  __syncthreads();

  f32x4 acc[4][2];
#pragma unroll
  for (int m = 0; m < 4; m++)
#pragma unroll
    for (int n = 0; n < 2; n++) acc[m][n] = (f32x4){0.f, 0.f, 0.f, 0.f};
#pragma unroll
  for (int ks = 0; ks < 2; ks++) {
    const int ch = ks * 4 + kg;
    bf16x8 af[4], bfr[2];
#pragma unroll
    for (int m = 0; m < 4; m++) af[m] = *(const bf16x8*)&Pl[m * 16 + lr][ch * 8];
#pragma unroll
    for (int n = 0; n < 2; n++) {
      int rowd = w * 32 + n * 16 + lr;
      bfr[n] = *(const bf16x8*)&Bl[rowd][ch * 8];
    }
#pragma unroll
    for (int m = 0; m < 4; m++)
#pragma unroll
      for (int n = 0; n < 2; n++)
        acc[m][n] = __builtin_amdgcn_mfma_f32_16x16x32_bf16(af[m], bfr[n], acc[m][n], 0, 0, 0);
  }

#pragma unroll
  for (int m = 0; m < 4; m++) {
#pragma unroll
    for (int n = 0; n < 2; n++) {
      int dcol = w * 32 + n * 16 + lr;
      float bd = bias[dblk + dcol];
#pragma unroll
      for (int j = 0; j < 4; j++) {
        int k = m * 16 + kg * 4 + j;
        float v = acc[m][n][j] + bd;
        if (k > 0) v += bf2f(Ag[k][dcol]) - Raf[dcol];
        out[((size_t)b * KK + k) * DD + dblk + dcol] = f2bf(fmaxf(v, 0.f));
      }
    }
  }
}

// ---- fused layer 2: x2 = relu(Z2a + A@Z2b + b2), Z2 = x1_b @ [W2a|W2b]^T ----
__global__ __launch_bounds__(512) void k_l2fused(const unsigned short* __restrict__ x1,
                                                 const unsigned short* __restrict__ W2tp,
                                                 const float* __restrict__ A,
                                                 const float* __restrict__ b2,
                                                 unsigned short* __restrict__ x2) {
  __shared__ char lds[79872];
  unsigned short* Xs = (unsigned short*)lds;
  unsigned short* Ws = (unsigned short*)(lds + 8192);
  unsigned short* Pl = (unsigned short*)lds;
  unsigned short* Za = (unsigned short*)(lds + 9216);
  unsigned short* Zb = (unsigned short*)(lds + 43008);
  const int b = blockIdx.x;
  const int t = threadIdx.x;
  const int w = t >> 6, lane = t & 63;
  const int lr = lane & 15, kg = lane >> 4;
  const int wr = w >> 2, wc = w & 3;

  f32x4 acc[2][8];
#pragma unroll
  for (int m = 0; m < 2; m++)
#pragma unroll
    for (int n = 0; n < 8; n++) acc[m][n] = (f32x4){0.f, 0.f, 0.f, 0.f};

  for (int kc = 0; kc < 8; kc++) {
    const int k0 = kc * 64;
    if (kc) __syncthreads();
    {
      int r = w * 8 + (lane >> 3);
      int cl = (lane & 7) ^ (r & 7);
      __builtin_amdgcn_global_load_lds(
          (const __attribute__((address_space(1))) void*)(x1 + ((size_t)b * KK + r) * NHID + k0 + cl * 8),
          (__attribute__((address_space(3))) void*)(Xs + w * 512), 16, 0, 0);
    }
#pragma unroll
    for (int i = 0; i < 8; i++) {
      int r = w * 64 + i * 8 + (lane >> 3);
      int cl = (lane & 7) ^ (r & 7);
      __builtin_amdgcn_global_load_lds(
          (const __attribute__((address_space(1))) void*)(W2tp + (size_t)r * NHID + k0 + cl * 8),
          (__attribute__((address_space(3))) void*)(Ws + (w * 64 + i * 8) * 64), 16, 0, 0);
    }
    __syncthreads();
#pragma unroll
    for (int ks = 0; ks < 2; ks++) {
      const int ch = ks * 4 + kg;
      bf16x8 af[2], bfr[8];
#pragma unroll
      for (int m = 0; m < 2; m++) {
        int row = wr * 32 + m * 16 + lr;
        af[m] = *(const bf16x8*)&Xs[row * 64 + ((ch ^ (row & 7)) << 3)];
      }
#pragma unroll
      for (int n = 0; n < 8; n++) {
        int row = wc * 128 + n * 16 + lr;
        bfr[n] = *(const bf16x8*)&Ws[row * 64 + ((ch ^ (row & 7)) << 3)];
      }
#pragma unroll
      for (int m = 0; m < 2; m++)
#pragma unroll
        for (int n = 0; n < 8; n++)
          acc[m][n] = __builtin_amdgcn_mfma_f32_16x16x32_bf16(af[m], bfr[n], acc[m][n], 0, 0, 0);
    }
  }
  __syncthreads();

#pragma unroll
  for (int m = 0; m < 2; m++) {
#pragma unroll
    for (int n = 0; n < 8; n++) {
      int col = wc * 128 + n * 16 + lr;
#pragma unroll
      for (int j = 0; j < 4; j++) {
        int row = wr * 32 + m * 16 + kg * 4 + j;
        unsigned short hv = f2bf(acc[m][n][j]);
        if (col < 256) Za[row * 264 + col] = hv;
        else           Zb[(col - 256) * 72 + row] = hv;
      }
    }
  }
  {
    const float* Ap = A + (size_t)b * KK * KK + t * 8;
    float4 f0 = *(const float4*)(Ap);
    float4 f1 = *(const float4*)(Ap + 4);
    bf16x8 hv;
    hv[0] = (short)f2bf(f0.x); hv[1] = (short)f2bf(f0.y);
    hv[2] = (short)f2bf(f0.z); hv[3] = (short)f2bf(f0.w);
    hv[4] = (short)f2bf(f1.x); hv[5] = (short)f2bf(f1.y);
    hv[6] = (short)f2bf(f1.z); hv[7] = (short)f2bf(f1.w);
    *(bf16x8*)&Pl[(t >> 3) * 72 + (t & 7) * 8] = hv;
  }
  __syncthreads();

  f32x4 acc2[4][2];
#pragma unroll
  for (int m = 0; m < 4; m++)
#pragma unroll
    for (int n = 0; n < 2; n++) acc2[m][n] = (f32x4){0.f, 0.f, 0.f, 0.f};
#pragma unroll
  for (int ks = 0; ks < 2; ks++) {
    const int ch = ks * 4 + kg;
    bf16x8 af[4], bfr[2];
#pragma unroll
    for (int m = 0; m < 4; m++) af[m] = *(const bf16x8*)&Pl[(m * 16 + lr) * 72 + ch * 8];
#pragma unroll
    for (int n = 0; n < 2; n++) bfr[n] = *(const bf16x8*)&Zb[(w * 32 + n * 16 + lr) * 72 + ch * 8];
#pragma unroll
    for (int m = 0; m < 4; m++)
#pragma unroll
      for (int n = 0; n < 2; n++)
        acc2[m][n] = __builtin_amdgcn_mfma_f32_16x16x32_bf16(af[m], bfr[n], acc2[m][n], 0, 0, 0);
  }

#pragma unroll
  for (int m = 0; m < 4; m++) {
#pragma unroll
    for (int n = 0; n < 2; n++) {
      int d = w * 32 + n * 16 + lr;
      float bd = b2[d];
#pragma unroll
      for (int j = 0; j < 4; j++) {
        int k = m * 16 + kg * 4 + j;
        float v = acc2[m][n][j] + bf2f(Za[k * 264 + d]) + bd;
        x2[((size_t)b * KK + k) * DOUT + d] = f2bf(fmaxf(v, 0.f));
      }
    }
  }
}

// ---- fused classifier: probs = softmax( PReLU(x2@Wc1+bc1) @ Wc2 + bc2 ) ----
__global__ __launch_bounds__(512) void k_cls_fused(const unsigned short* __restrict__ X,
                                                   const unsigned short* __restrict__ Wt,
                                                   const float* __restrict__ bc1,
                                                   const float* __restrict__ pa,
                                                   const float* __restrict__ Wc2,
                                                   const float* __restrict__ bc2,
                                                   float* __restrict__ probs) {
  const int t = threadIdx.x;
  const int w = t >> 6, lane = t & 63;
  const int lr = lane & 15, kg = lane >> 4;
  const int wr = w >> 2, wc = w & 3;
  const int mt = blockIdx.x * 128;
  __shared__ unsigned short As[128 * 64];
  __shared__ unsigned short Bs[256 * 64];
  __shared__ float Lred[128][4][2];

  f32x4 acc[4][4];
#pragma unroll
  for (int m = 0; m < 4; m++)
#pragma unroll
    for (int n = 0; n < 4; n++) acc[m][n] = (f32x4){0.f, 0.f, 0.f, 0.f};

  for (int kc = 0; kc < 4; kc++) {
    const int k0 = kc * 64;
#pragma unroll
    for (int i = 0; i < 2; i++) {
      int q = (w * 2 + i) * 64 + lane;
      int r = q >> 3;
      int cl = (q & 7) ^ (r & 7);
      __builtin_amdgcn_global_load_lds(
          (const __attribute__((address_space(1))) void*)(X + (size_t)(mt + r) * DOUT + k0 + cl * 8),
          (__attribute__((address_space(3))) void*)(As + (w * 2 + i) * 512), 16, 0, 0);
    }
#pragma unroll
    for (int i = 0; i < 4; i++) {
      int q = (w * 4 + i) * 64 + lane;
      int r = q >> 3;
      int cl = (q & 7) ^ (r & 7);
      __builtin_amdgcn_global_load_lds(
          (const __attribute__((address_space(1))) void*)(Wt + (size_t)r * DOUT + k0 + cl * 8),
          (__attribute__((address_space(3))) void*)(Bs + (w * 4 + i) * 512), 16, 0, 0);
    }
    __syncthreads();
#pragma unroll
    for (int ks = 0; ks < 2; ks++) {
      bf16x8 af[4], bfr[4];
      const int ch = ks * 4 + kg;
#pragma unroll
      for (int m = 0; m < 4; m++) {
        int row = wr * 64 + m * 16 + lr;
        af[m] = *(const bf16x8*)&As[row * 64 + ((ch ^ (row & 7)) << 3)];
      }
#pragma unroll
      for (int n = 0; n < 4; n++) {
        int row = wc * 64 + n * 16 + lr;
        bfr[n] = *(const bf16x8*)&Bs[row * 64 + ((ch ^ (row & 7)) << 3)];
      }
#pragma unroll
      for (int m = 0; m < 4; m++)
#pragma unroll
        for (int n = 0; n < 4; n++)
          acc[m][n] = __builtin_amdgcn_mfma_f32_16x16x32_bf16(af[m], bfr[n], acc[m][n], 0, 0, 0);
    }
    __syncthreads();
  }

  float bc1v[4], pav[4], w0v[4], w1v[4];
#pragma unroll
  for (int n = 0; n < 4; n++) {
    int col = wc * 64 + n * 16 + lr;
    bc1v[n] = bc1[col];
    pav[n] = pa[col];
    w0v[n] = Wc2[col * 2 + 0];
    w1v[n] = Wc2[col * 2 + 1];
  }
#pragma unroll
  for (int m = 0; m < 4; m++) {
#pragma unroll
    for (int j = 0; j < 4; j++) {
      float p0 = 0.f, p1 = 0.f;
#pragma unroll
      for (int n = 0; n < 4; n++) {
        float h = acc[m][n][j] + bc1v[n];
        h = (h >= 0.f) ? h : pav[n] * h;
        p0 += h * w0v[n];
        p1 += h * w1v[n];
      }
      p0 += __shfl_xor(p0, 1); p1 += __shfl_xor(p1, 1);
      p0 += __shfl_xor(p0, 2); p1 += __shfl_xor(p1, 2);
      p0 += __shfl_xor(p0, 4); p1 += __shfl_xor(p1, 4);
      p0 += __shfl_xor(p0, 8); p1 += __shfl_xor(p1, 8);
      if (lr == 0) {
        int rowl = wr * 64 + m * 16 + kg * 4 + j;
        Lred[rowl][wc][0] = p0;
        Lred[rowl][wc][1] = p1;
      }
    }
  }
  __syncthreads();
  if (t < 128) {
    float l0 = Lred[t][0][0] + Lred[t][1][0] + Lred[t][2][0] + Lred[t][3][0] + bc2[0];
    float l1 = Lred[t][0][1] + Lred[t][1][1] + Lred[t][2][1] + Lred[t][3][1] + bc2[1];
    float m = fmaxf(l0, l1);
    float e0 = expf(l0 - m), e1 = expf(l1 - m);
    float inv = 1.0f / (e0 + e1);
    *(float2*)(probs + (size_t)(mt + t) * 2) = make_float2(e0 * inv, e1 * inv);
  }
}

// ---------------------------------------------------------------------------

extern "C" void kernel_launch(void* const* d_in, const int* in_sizes, int n_in,
                              void* d_out, int out_size, void* d_ws, size_t ws_size,
                              hipStream_t stream) {
  const int* indexes = (const int*)d_in[0];
  const float* features = (const float*)d_in[1];
  const int* sub_label = (const int*)d_in[3];
  const int* knn = (const int*)d_in[6];
  const float* all_pred = (const float*)d_in[7];
  const float* W1 = (const float*)d_in[9];
  const float* b1 = (const float*)d_in[10];
  const float* W2 = (const float*)d_in[11];
  const float* b2 = (const float*)d_in[12];
  const float* Wc1 = (const float*)d_in[13];
  const float* bc1 = (const float*)d_in[14];
  const float* pa = (const float*)d_in[15];
  const float* Wc2 = (const float*)d_in[16];
  const float* bc2 = (const float*)d_in[17];

  float* out = (float*)d_out;
  float* probs = out;                    // [B*K*2]
  float* simm = out + 32768;             // [2000]
  float* submean = out + 34768;          // [2000*2048]
  float* nums = out + 4130768;           // [2000]

  // ---- workspace layout (bytes) ----
  char* ws = (char*)d_ws;
  size_t off = 0;
  unsigned short* u_bf = (unsigned short*)(ws + off); off += (size_t)MU * DIM * 2;            // 9.4MB
  unsigned short* UR1  = (unsigned short*)(ws + off); off += (size_t)MU * 2 * NHID * 2;       // 4.7MB
  unsigned short* x1   = (unsigned short*)(ws + off); off += (size_t)MM * NHID * 2;           // 16.8MB
  unsigned short* x2   = (unsigned short*)(ws + off); off += (size_t)MM * DOUT * 2;           // 8.4MB
  unsigned short* W1tp = (unsigned short*)(ws + off); off += (size_t)(2 * NHID) * DIM * 2;    // 4.2MB
  unsigned short* W2tp = (unsigned short*)(ws + off); off += (size_t)(2 * DOUT) * NHID * 2;   // 0.5MB
  unsigned short* Wc1t = (unsigned short*)(ws + off); off += (size_t)DOUT * DOUT * 2;         // 0.13MB
  float* Abuf = (float*)(ws + off); off += (size_t)MM * KK * 4;                               // 4MB
  int* cnt     = (int*)(ws + off); off += NSUB * 4;
  int* rowlist = (int*)(ws + off); off += (size_t)NSUB * CAP * 4;                             // 1MB
  int* sublabs = (int*)(ws + off); off += (size_t)MM * 4;
  float* norms0 = (float*)(ws + off); off += (size_t)BB * 4;

  hipMemsetAsync(cnt, 0, NSUB * sizeof(int), stream);

  const int nrb = (NROW + 255) / 256;
  k_build<<<nrb, 256, 0, stream>>>(sub_label, cnt, rowlist);
  k_misc<<<2368 + 304, 256, 0, stream>>>(W1, W2, Wc1, W1tp, W2tp, Wc1t,
                                         indexes, features, u_bf, norms0);
  k_cluster_sum<<<NSUB, 256, 0, stream>>>(features, rowlist, cnt,
                                          submean, simm, nums, u_bf);
  k_gram_gemm<<<NGEMM + BB, 512, 0, stream>>>(u_bf, W1tp, UR1, sub_label, knn,
                                              simm, norms0, all_pred, Abuf, sublabs);
  k_combine1<NHID><<<dim3(NHID / 128, BB), 256, 0, stream>>>(
      Abuf, UR1, sublabs, b1, x1);
  k_l2fused<<<BB, 512, 0, stream>>>(x1, W2tp, Abuf, b2, x2);
  k_cls_fused<<<MM / 128, 512, 0, stream>>>(x2, Wc1t, bc1, pa, Wc2, bc2, probs);
}

// Round 9
// 198.972 us; speedup vs baseline: 8.3347x; 1.0416x over previous
//
#include <hip/hip_runtime.h>
#include <hip/hip_bf16.h>

// ---------------------------------------------------------------------------
// Sub_Cluster_Level_GCN — round 8:
//   * combine1 + l2fused fused into k_l12fused (x1 lives in LDS, 128KB)
//   * k_build + k_misc fused (block-range dispatch)
//   5 kernels + 1 memset total.
// ---------------------------------------------------------------------------

#define NROW 50000
#define DIM  2048
#define NSUB 2000
#define BB   256
#define KK   64
#define NHID 512
#define DOUT 256
#define MM   (BB * KK)   // 16384
#define MU   2304        // 2000 u + 256 r0 + 48 pad
#define CAP  128

typedef __attribute__((ext_vector_type(8))) short bf16x8;
typedef __attribute__((ext_vector_type(4))) float f32x4;

__device__ __forceinline__ unsigned short f2bf(float f) {
  union { float f; unsigned u; } v; v.f = f;
  unsigned r = v.u + 0x7FFF + ((v.u >> 16) & 1);
  return (unsigned short)(r >> 16);
}
__device__ __forceinline__ float bf2f(unsigned short h) {
  union { unsigned u; float f; } v; v.u = ((unsigned)h) << 16;
  return v.f;
}

// ---- build (196 blocks) + W transposes (2368) + r0 cast (304) --------------
__global__ __launch_bounds__(256) void k_build_misc(const int* __restrict__ sub_label,
                                                    int* __restrict__ cnt,
                                                    int* __restrict__ rowlist,
                                                    const float* __restrict__ W1,
                                                    const float* __restrict__ W2,
                                                    const float* __restrict__ Wc1,
                                                    unsigned short* __restrict__ W1t,
                                                    unsigned short* __restrict__ W2t,
                                                    unsigned short* __restrict__ Wc1t,
                                                    const int* __restrict__ indexes,
                                                    const float* __restrict__ features,
                                                    unsigned short* __restrict__ u_bf,
                                                    float* __restrict__ norms0) {
  int bid = blockIdx.x;
  int t = threadIdx.x;
  if (bid < 196) {
    int i = bid * 256 + t;
    if (i < NROW) {
      int s = sub_label[i];
      int pos = atomicAdd(&cnt[s], 1);
      rowlist[(s << 7) + pos] = i;
    }
    return;
  }
  bid -= 196;
  if (bid >= 2368) {
    int row = bid - 2368;              // 0..303
    unsigned short* dst = u_bf + (size_t)(NSUB + row) * DIM + t * 8;
    if (row >= BB) {
      bf16x8 z = {0, 0, 0, 0, 0, 0, 0, 0};
      *(bf16x8*)dst = z;
      return;
    }
    const float* src = features + (size_t)indexes[row] * DIM + t * 8;
    float4 v0 = *(const float4*)(src);
    float4 v1 = *(const float4*)(src + 4);
    float ss = v0.x * v0.x + v0.y * v0.y + v0.z * v0.z + v0.w * v0.w +
               v1.x * v1.x + v1.y * v1.y + v1.z * v1.z + v1.w * v1.w;
    __shared__ float red[256];
    red[t] = ss;
    __syncthreads();
    for (int s2 = 128; s2 > 0; s2 >>= 1) {
      if (t < s2) red[t] += red[t + s2];
      __syncthreads();
    }
    float nrm = sqrtf(red[0]);
    if (t == 0) norms0[row] = nrm;
    float scale = 1.0f / nrm;
    bf16x8 o;
    o[0] = (short)f2bf(v0.x * scale); o[1] = (short)f2bf(v0.y * scale);
    o[2] = (short)f2bf(v0.z * scale); o[3] = (short)f2bf(v0.w * scale);
    o[4] = (short)f2bf(v1.x * scale); o[5] = (short)f2bf(v1.y * scale);
    o[6] = (short)f2bf(v1.z * scale); o[7] = (short)f2bf(v1.w * scale);
    *(bf16x8*)dst = o;
    return;
  }
  const float* src;
  unsigned short* dst;
  int Nsrc, Kdst, ntn, local;
  if (bid < 1024)      { local = bid;        src = W1;                        dst = W1t;                      Nsrc = NHID; Kdst = DIM;  ntn = 16; }
  else if (bid < 2048) { local = bid - 1024; src = W1 + (size_t)DIM * NHID;   dst = W1t + (size_t)NHID * DIM; Nsrc = NHID; Kdst = DIM;  ntn = 16; }
  else if (bid < 2176) { local = bid - 2048; src = W2;                        dst = W2t;                      Nsrc = DOUT; Kdst = NHID; ntn = 8; }
  else if (bid < 2304) { local = bid - 2176; src = W2 + (size_t)NHID * DOUT;  dst = W2t + (size_t)DOUT * NHID;Nsrc = DOUT; Kdst = NHID; ntn = 8; }
  else                 { local = bid - 2304; src = Wc1;                       dst = Wc1t;                     Nsrc = DOUT; Kdst = DOUT; ntn = 8; }
  int n0 = (local % ntn) * 32, k0 = (local / ntn) * 32;
  __shared__ float tile[32][33];
  int c = t & 31, r8 = t >> 5;
#pragma unroll
  for (int i = 0; i < 4; i++) {
    int r = r8 + i * 8;
    tile[r][c] = src[(size_t)(k0 + r) * Nsrc + n0 + c];
  }
  __syncthreads();
#pragma unroll
  for (int i = 0; i < 4; i++) {
    int r = r8 + i * 8;
    dst[(size_t)(n0 + r) * Kdst + k0 + c] = f2bf(tile[c][r]);
  }
}

// ------- cluster_sum: mean + simm + nums + normalized bf16 u-row ------------
__global__ __launch_bounds__(256) void k_cluster_sum(const float* __restrict__ features,
                                                     const int* __restrict__ rowlist,
                                                     const int* __restrict__ cnt,
                                                     float* __restrict__ submean,
                                                     float* __restrict__ simm,
                                                     float* __restrict__ nums,
                                                     unsigned short* __restrict__ u_bf) {
  int s = blockIdx.x;
  int t = threadIdx.x;
  int n = cnt[s];
  const int* rl = rowlist + (s << 7);
  float acc[8] = {0, 0, 0, 0, 0, 0, 0, 0};
  int r = 0;
  for (; r + 3 < n; r += 4) {
    const float* rA = features + (size_t)rl[r] * DIM + t * 8;
    const float* rB = features + (size_t)rl[r + 1] * DIM + t * 8;
    const float* rC = features + (size_t)rl[r + 2] * DIM + t * 8;
    const float* rD = features + (size_t)rl[r + 3] * DIM + t * 8;
    float4 a0 = *(const float4*)(rA), a1 = *(const float4*)(rA + 4);
    float4 b0 = *(const float4*)(rB), b1 = *(const float4*)(rB + 4);
    float4 c0 = *(const float4*)(rC), c1 = *(const float4*)(rC + 4);
    float4 d0 = *(const float4*)(rD), d1 = *(const float4*)(rD + 4);
    acc[0] += (a0.x + b0.x) + (c0.x + d0.x);
    acc[1] += (a0.y + b0.y) + (c0.y + d0.y);
    acc[2] += (a0.z + b0.z) + (c0.z + d0.z);
    acc[3] += (a0.w + b0.w) + (c0.w + d0.w);
    acc[4] += (a1.x + b1.x) + (c1.x + d1.x);
    acc[5] += (a1.y + b1.y) + (c1.y + d1.y);
    acc[6] += (a1.z + b1.z) + (c1.z + d1.z);
    acc[7] += (a1.w + b1.w) + (c1.w + d1.w);
  }
  for (; r < n; r++) {
    const float* row = features + (size_t)rl[r] * DIM + t * 8;
    float4 v0 = *(const float4*)(row);
    float4 v1 = *(const float4*)(row + 4);
    acc[0] += v0.x; acc[1] += v0.y; acc[2] += v0.z; acc[3] += v0.w;
    acc[4] += v1.x; acc[5] += v1.y; acc[6] += v1.z; acc[7] += v1.w;
  }
  float inv = 1.0f / (float)(n > 0 ? n : 1);
  float m[8];
  float ss = 0.f;
#pragma unroll
  for (int i = 0; i < 8; i++) { m[i] = acc[i] * inv; ss += m[i] * m[i]; }
  float* outp = submean + (size_t)s * DIM + t * 8;
  *(float4*)(outp)     = make_float4(m[0], m[1], m[2], m[3]);
  *(float4*)(outp + 4) = make_float4(m[4], m[5], m[6], m[7]);
  __shared__ float red[256];
  red[t] = ss;
  __syncthreads();
  for (int s2 = 128; s2 > 0; s2 >>= 1) {
    if (t < s2) red[t] += red[t + s2];
    __syncthreads();
  }
  float tot = red[0];
  if (t == 0) {
    simm[s] = tot;
    nums[s] = (float)n;
  }
  float scale = (tot > 0.f) ? (1.0f / sqrtf(tot)) : 0.f;
  bf16x8 o;
  o[0] = (short)f2bf(m[0] * scale); o[1] = (short)f2bf(m[1] * scale);
  o[2] = (short)f2bf(m[2] * scale); o[3] = (short)f2bf(m[3] * scale);
  o[4] = (short)f2bf(m[4] * scale); o[5] = (short)f2bf(m[5] * scale);
  o[6] = (short)f2bf(m[6] * scale); o[7] = (short)f2bf(m[7] * scale);
  *(bf16x8*)(u_bf + (size_t)s * DIM + t * 8) = o;
}

// ------- fused gram (256 blocks) + gemm1 (144 tiles), 512 threads -----------
#define NGEMM 144
__global__ __launch_bounds__(512) void k_gram_gemm(const unsigned short* __restrict__ u_bf,
                                                   const unsigned short* __restrict__ W1tp,
                                                   unsigned short* __restrict__ UR1,
                                                   const int* __restrict__ sub_label,
                                                   const int* __restrict__ knn,
                                                   const float* __restrict__ simm,
                                                   const float* __restrict__ norms0,
                                                   const float* __restrict__ all_pred,
                                                   float* __restrict__ A,
                                                   int* __restrict__ sublabs) {
  __shared__ char big[32768];
  __shared__ int slr[64];
  __shared__ float nks[64], wjs[64];
  const int t = threadIdx.x;
  const int w = t >> 6, lane = t & 63;
  const int lr = lane & 15, kg = lane >> 4;

  if (blockIdx.x < NGEMM) {
    constexpr int KTOT = DIM;
    constexpr int NTOT = 2 * NHID;
    unsigned short* As = (unsigned short*)big;
    unsigned short* Bs = (unsigned short*)(big + 16384);
    int orig = blockIdx.x;
    int swz = (orig & 7) * (NGEMM / 8) + (orig >> 3);
    const int nt = (swz & 7) * 128;
    const int mt = (swz >> 3) * 128;
    const int wr = w >> 2, wc = w & 3;

    f32x4 acc[4][2];
#pragma unroll
    for (int m = 0; m < 4; m++)
#pragma unroll
      for (int n = 0; n < 2; n++) acc[m][n] = (f32x4){0.f, 0.f, 0.f, 0.f};

    for (int kc = 0; kc < KTOT / 64; kc++) {
      const int k0 = kc * 64;
#pragma unroll
      for (int i = 0; i < 2; i++) {
        int q = (w * 2 + i) * 64 + lane;
        int r = q >> 3;
        int cl = (q & 7) ^ (r & 7);
        __builtin_amdgcn_global_load_lds(
            (const __attribute__((address_space(1))) void*)(u_bf + (size_t)(mt + r) * KTOT + k0 + cl * 8),
            (__attribute__((address_space(3))) void*)(As + (w * 2 + i) * 512), 16, 0, 0);
      }
#pragma unroll
      for (int i = 0; i < 2; i++) {
        int q = (w * 2 + i) * 64 + lane;
        int r = q >> 3;
        int cl = (q & 7) ^ (r & 7);
        __builtin_amdgcn_global_load_lds(
            (const __attribute__((address_space(1))) void*)(W1tp + (size_t)(nt + r) * KTOT + k0 + cl * 8),
            (__attribute__((address_space(3))) void*)(Bs + (w * 2 + i) * 512), 16, 0, 0);
      }
      __syncthreads();
#pragma unroll
      for (int ks = 0; ks < 2; ks++) {
        bf16x8 af[4], bfr[2];
        const int ch = ks * 4 + kg;
#pragma unroll
        for (int m = 0; m < 4; m++) {
          int row = wr * 64 + m * 16 + lr;
          af[m] = *(const bf16x8*)&As[row * 64 + ((ch ^ (row & 7)) << 3)];
        }
#pragma unroll
        for (int n = 0; n < 2; n++) {
          int row = wc * 32 + n * 16 + lr;
          bfr[n] = *(const bf16x8*)&Bs[row * 64 + ((ch ^ (row & 7)) << 3)];
        }
#pragma unroll
        for (int m = 0; m < 4; m++)
#pragma unroll
          for (int n = 0; n < 2; n++)
            acc[m][n] = __builtin_amdgcn_mfma_f32_16x16x32_bf16(af[m], bfr[n], acc[m][n], 0, 0, 0);
      }
      __syncthreads();
    }
#pragma unroll
    for (int m = 0; m < 4; m++) {
      int rm = mt + wr * 64 + m * 16 + kg * 4;
#pragma unroll
      for (int n = 0; n < 2; n++) {
        int col = nt + wc * 32 + n * 16 + lr;
#pragma unroll
        for (int j = 0; j < 4; j++)
          UR1[(size_t)(rm + j) * NTOT + col] = f2bf(acc[m][n][j]);
      }
    }
    return;
  }

  int b = blockIdx.x - NGEMM;
  unsigned short* Xs = (unsigned short*)big;
  if (t < 64) {
    int sl = sub_label[knn[b * KK + t]];
    sublabs[b * KK + t] = sl;
    slr[t] = (t == 0) ? (NSUB + b) : sl;
    float s2 = (t == 0) ? 0.f : simm[sl];
    nks[t] = (t == 0) ? norms0[b] : ((s2 > 0.f) ? sqrtf(s2) : 0.f);
    wjs[t] = expf(all_pred[(size_t)(b * KK + t) * 2 + 1]);
  }
  __syncthreads();

  const int rb = w & 3;
  const int cp = w >> 2;
  int rloc[4], clsw[4];
#pragma unroll
  for (int i = 0; i < 4; i++) {
    rloc[i] = w * 8 + i * 2 + (lane >> 5);
    clsw[i] = (lane & 31) ^ (rloc[i] & 7);
  }

  f32x4 acc0 = {0.f, 0.f, 0.f, 0.f}, acc1 = {0.f, 0.f, 0.f, 0.f};
  for (int c = 0; c < 8; c++) {
    if (c) __syncthreads();
#pragma unroll
    for (int i = 0; i < 4; i++) {
      const unsigned short* src =
          u_bf + (size_t)slr[rloc[i]] * DIM + c * 256 + clsw[i] * 8;
      __builtin_amdgcn_global_load_lds(
          (const __attribute__((address_space(1))) void*)src,
          (__attribute__((address_space(3))) void*)(Xs + (w * 8 + i * 2) * 256), 16, 0, 0);
    }
    __syncthreads();
#pragma unroll
    for (int ks = 0; ks < 8; ks++) {
      const int ch = ks * 4 + kg;
      int Ra = rb * 16 + lr;
      bf16x8 fa = *(const bf16x8*)&Xs[Ra * 256 + ((ch ^ (Ra & 7)) << 3)];
      int R0 = (cp * 2) * 16 + lr;
      bf16x8 f0 = *(const bf16x8*)&Xs[R0 * 256 + ((ch ^ (R0 & 7)) << 3)];
      int R1 = (cp * 2 + 1) * 16 + lr;
      bf16x8 f1 = *(const bf16x8*)&Xs[R1 * 256 + ((ch ^ (R1 & 7)) << 3)];
      acc0 = __builtin_amdgcn_mfma_f32_16x16x32_bf16(fa, f0, acc0, 0, 0, 0);
      acc1 = __builtin_amdgcn_mfma_f32_16x16x32_bf16(fa, f1, acc1, 0, 0, 0);
    }
  }

  __syncthreads();
  float* Cs = (float*)big;
#pragma unroll
  for (int r = 0; r < 4; r++) {
    Cs[(rb * 16 + kg * 4 + r) * 68 + cp * 32 + lr] = acc0[r];
    Cs[(rb * 16 + kg * 4 + r) * 68 + cp * 32 + 16 + lr] = acc1[r];
  }
  __syncthreads();

  int row = t >> 3, seg = t & 7;
  float nr = nks[row];
  float v[8];
  float mx = -1e30f;
#pragma unroll
  for (int i = 0; i < 8; i++) {
    int j = seg * 8 + i;
    v[i] = Cs[row * 68 + j] * nr * nks[j] * wjs[j];
    mx = fmaxf(mx, v[i]);
  }
  mx = fmaxf(mx, __shfl_xor(mx, 1));
  mx = fmaxf(mx, __shfl_xor(mx, 2));
  mx = fmaxf(mx, __shfl_xor(mx, 4));
  float sum = 0.f;
#pragma unroll
  for (int i = 0; i < 8; i++) {
    v[i] = expf(v[i] - mx);
    sum += v[i];
  }
  sum += __shfl_xor(sum, 1);
  sum += __shfl_xor(sum, 2);
  sum += __shfl_xor(sum, 4);
  float inv = 1.0f / sum;
  float* outp = A + ((size_t)b * KK + row) * KK + seg * 8;
  *(float4*)(outp)     = make_float4(v[0] * inv, v[1] * inv, v[2] * inv, v[3] * inv);
  *(float4*)(outp + 4) = make_float4(v[4] * inv, v[5] * inv, v[6] * inv, v[7] * inv);
}

// ---- fused layer1-combine + layer2: x2 per sample; x1 lives in LDS ---------
// Stage 0 (combine1): x1s[64][512] = relu(Za + P@Bg + b1)  (4 d-blocks of 128)
// Stage A (gemm2):    Z2 = x1s @ [W2a|W2b]^T  (K=512, N=512; Ws streamed)
// Stage B (combine2): x2 = relu(Z2a + A@Z2b + b2)
__global__ __launch_bounds__(512) void k_l12fused(const float* __restrict__ A,
                                                  const unsigned short* __restrict__ UR1,
                                                  const int* __restrict__ sublabs,
                                                  const float* __restrict__ b1,
                                                  const unsigned short* __restrict__ W2tp,
                                                  const float* __restrict__ b2,
                                                  unsigned short* __restrict__ x2) {
  __shared__ char lds[131072];
  unsigned short* x1s = (unsigned short*)lds;              // [64][512] swizzled, 64KB
  char* R = lds + 65536;
  unsigned short* Pl = (unsigned short*)R;                 // [64][80]  10240
  unsigned short* Bl = (unsigned short*)(R + 10240);       // [128][80] 20480
  unsigned short* Ag = (unsigned short*)(R + 30720);       // [64][136] 17408
  float* Raf = (float*)(R + 48128);                        // [128]
  float* red8 = (float*)(R + 48640);                       // [64][8]
  int* slh = (int*)(R + 50688);                            // [64]
  unsigned short* Ws = (unsigned short*)R;                 // stage A: [512][64] 64KB
  unsigned short* Za = (unsigned short*)lds;               // stage B: [64][264] 33792
  unsigned short* Zb = (unsigned short*)(lds + 34816);     // [256][72] 36864
  unsigned short* Pl2 = (unsigned short*)(lds + 71680);    // [64][72]  9216

  const int b = blockIdx.x;
  const int t = threadIdx.x;
  const int w = t >> 6, lane = t & 63;
  const int lr = lane & 15, kg = lane >> 4;
  constexpr int NSTR = 2 * NHID;   // 1024

  // ---- stage 0 prologue: slh + P build ----
  if (t < 64) slh[t] = sublabs[b * KK + t];
  {
    int pk = t & 63, pp = t >> 6;   // 8 parts of 8
    const float* Arow = A + ((size_t)b * KK + pk) * KK;
    float part = 0.f;
#pragma unroll
    for (int e = 0; e < 8; e++) {
      int j = pp * 8 + e;
      float av = Arow[j];
      if (j > 0) {
        Pl[pk * 80 + j] = f2bf(av);
        part += av;
      }
    }
    red8[pk * 8 + pp] = part;
  }
  __syncthreads();
  if (t < 64) {
    float rs = 0.f;
#pragma unroll
    for (int p = 0; p < 8; p++) rs += red8[t * 8 + p];
    Pl[t * 80 + 0] = f2bf(-rs);
  }

  // ---- stage 0: 4 d-blocks of 128 ----
  for (int db = 0; db < 4; db++) {
    const int dblk = db * 128;
    __syncthreads();   // P ready / previous MFMA readers done
    {
      int gj = t >> 3, gc0 = t & 7;
      size_t brow = (gj == 0) ? (size_t)(NSUB + b) : (size_t)slh[gj];
      const unsigned short* Bp = UR1 + brow * NSTR + NHID + dblk;
#pragma unroll
      for (int it = 0; it < 2; it++) {
        int c = gc0 + it * 8;
        bf16x8 v = *(const bf16x8*)(Bp + c * 8);
#pragma unroll
        for (int e = 0; e < 8; e++) Bl[(c * 8 + e) * 80 + gj] = v[e];
      }
    }
    {
      int ak = t >> 3, ac0 = t & 7;
      const unsigned short* Ap = UR1 + (size_t)slh[ak] * NSTR + dblk;
#pragma unroll
      for (int it = 0; it < 2; it++) {
        int c = ac0 + it * 8;
        *(bf16x8*)&Ag[ak * 136 + c * 8] = *(const bf16x8*)(Ap + c * 8);
      }
      if (t < 128) Raf[t] = bf2f(UR1[(size_t)(NSUB + b) * NSTR + dblk + t]);
    }
    __syncthreads();

    f32x4 acc[4];
#pragma unroll
    for (int m = 0; m < 4; m++) acc[m] = (f32x4){0.f, 0.f, 0.f, 0.f};
#pragma unroll
    for (int ks = 0; ks < 2; ks++) {
      const int ch = ks * 4 + kg;
      bf16x8 bfr = *(const bf16x8*)&Bl[(w * 16 + lr) * 80 + ch * 8];
#pragma unroll
      for (int m = 0; m < 4; m++) {
        bf16x8 af = *(const bf16x8*)&Pl[(m * 16 + lr) * 80 + ch * 8];
        acc[m] = __builtin_amdgcn_mfma_f32_16x16x32_bf16(af, bfr, acc[m], 0, 0, 0);
      }
    }
    // epilogue -> x1s (swizzled by global chunk)
#pragma unroll
    for (int m = 0; m < 4; m++) {
      int d = w * 16 + lr;             // local 0..127
      float bd = b1[dblk + d];
#pragma unroll
      for (int j = 0; j < 4; j++) {
        int k = m * 16 + kg * 4 + j;
        float v = acc[m][j] + bd;
        if (k > 0) v += bf2f(Ag[k * 136 + d]) - Raf[d];
        int cg = dblk + d;             // global col 0..511
        int C = cg >> 3;
        x1s[k * 512 + (((C ^ (k & 7)) << 3) | (cg & 7))] = f2bf(fmaxf(v, 0.f));
      }
    }
  }
  __syncthreads();   // x1s complete; stage-0 bufs dead

  // ---- stage A: Z2 = x1s @ W2tp^T ----
  const int wr = w >> 2, wc = w & 3;
  f32x4 accA[2][8];
#pragma unroll
  for (int m = 0; m < 2; m++)
#pragma unroll
    for (int n = 0; n < 8; n++) accA[m][n] = (f32x4){0.f, 0.f, 0.f, 0.f};

  for (int kc = 0; kc < 8; kc++) {
    const int k0 = kc * 64;
    if (kc) __syncthreads();
#pragma unroll
    for (int i = 0; i < 8; i++) {
      int r = w * 64 + i * 8 + (lane >> 3);
      int cl = (lane & 7) ^ (r & 7);
      __builtin_amdgcn_global_load_lds(
          (const __attribute__((address_space(1))) void*)(W2tp + (size_t)r * NHID + k0 + cl * 8),
          (__attribute__((address_space(3))) void*)(Ws + (w * 64 + i * 8) * 64), 16, 0, 0);
    }
    __syncthreads();
#pragma unroll
    for (int ks = 0; ks < 2; ks++) {
      const int ch = ks * 4 + kg;
      const int C = kc * 8 + ch;
      bf16x8 af[2], bfr[8];
#pragma unroll
      for (int m = 0; m < 2; m++) {
        int row = wr * 32 + m * 16 + lr;
        af[m] = *(const bf16x8*)&x1s[row * 512 + ((C ^ (row & 7)) << 3)];
      }
#pragma unroll
      for (int n = 0; n < 8; n++) {
        int row = wc * 128 + n * 16 + lr;
        bfr[n] = *(const bf16x8*)&Ws[row * 64 + ((ch ^ (row & 7)) << 3)];
      }
#pragma unroll
      for (int m = 0; m < 2; m++)
#pragma unroll
        for (int n = 0; n < 8; n++)
          accA[m][n] = __builtin_amdgcn_mfma_f32_16x16x32_bf16(af[m], bfr[n], accA[m][n], 0, 0, 0);
    }
  }
  __syncthreads();   // x1s + Ws dead

  // ---- stage B: scatter Z2, P2 = bf16(A), combine ----
#pragma unroll
  for (int m = 0; m < 2; m++) {
#pragma unroll
    for (int n = 0; n < 8; n++) {
      int col = wc * 128 + n * 16 + lr;
#pragma unroll
      for (int j = 0; j < 4; j++) {
        int row = wr * 32 + m * 16 + kg * 4 + j;
        unsigned short hv = f2bf(accA[m][n][j]);
        if (col < 256) Za[row * 264 + col] = hv;
        else           Zb[(col - 256) * 72 + row] = hv;
      }
    }
  }
  {
    const float* Ap = A + (size_t)b * KK * KK + t * 8;
    float4 f0 = *(const float4*)(Ap);
    float4 f1 = *(const float4*)(Ap + 4);
    bf16x8 hv;
    hv[0] = (short)f2bf(f0.x); hv[1] = (short)f2bf(f0.y);
    hv[2] = (short)f2bf(f0.z); hv[3] = (short)f2bf(f0.w);
    hv[4] = (short)f2bf(f1.x); hv[5] = (short)f2bf(f1.y);
    hv[6] = (short)f2bf(f1.z); hv[7] = (short)f2bf(f1.w);
    *(bf16x8*)&Pl2[(t >> 3) * 72 + (t & 7) * 8] = hv;
  }
  __syncthreads();

  f32x4 acc2[4][2];
#pragma unroll
  for (int m = 0; m < 4; m++)
#pragma unroll
    for (int n = 0; n < 2; n++) acc2[m][n] = (f32x4){0.f, 0.f, 0.f, 0.f};
#pragma unroll
  for (int ks = 0; ks < 2; ks++) {
    const int ch = ks * 4 + kg;
    bf16x8 af[4], bfr[2];
#pragma unroll
    for (int m = 0; m < 4; m++) af[m] = *(const bf16x8*)&Pl2[(m * 16 + lr) * 72 + ch * 8];
#pragma unroll
    for (int n = 0; n < 2; n++) bfr[n] = *(const bf16x8*)&Zb[(w * 32 + n * 16 + lr) * 72 + ch * 8];
#pragma unroll
    for (int m = 0; m < 4; m++)
#pragma unroll
      for (int n = 0; n < 2; n++)
        acc2[m][n] = __builtin_amdgcn_mfma_f32_16x16x32_bf16(af[m], bfr[n], acc2[m][n], 0, 0, 0);
  }

#pragma unroll
  for (int m = 0; m < 4; m++) {
#pragma unroll
    for (int n = 0; n < 2; n++) {
      int d = w * 32 + n * 16 + lr;
      float bd = b2[d];
#pragma unroll
      for (int j = 0; j < 4; j++) {
        int k = m * 16 + kg * 4 + j;
        float v = acc2[m][n][j] + bf2f(Za[k * 264 + d]) + bd;
        x2[((size_t)b * KK + k) * DOUT + d] = f2bf(fmaxf(v, 0.f));
      }
    }
  }
}

// ---- fused classifier: probs = softmax( PReLU(x2@Wc1+bc1) @ Wc2 + bc2 ) ----
__global__ __launch_bounds__(512) void k_cls_fused(const unsigned short* __restrict__ X,
                                                   const unsigned short* __restrict__ Wt,
                                                   const float* __restrict__ bc1,
                                                   const float* __restrict__ pa,
                                                   const float* __restrict__ Wc2,
                                                   const float* __restrict__ bc2,
                                                   float* __restrict__ probs) {
  const int t = threadIdx.x;
  const int w = t >> 6, lane = t & 63;
  const int lr = lane & 15, kg = lane >> 4;
  const int wr = w >> 2, wc = w & 3;
  const int mt = blockIdx.x * 128;
  __shared__ unsigned short As[128 * 64];
  __shared__ unsigned short Bs[256 * 64];
  __shared__ float Lred[128][4][2];

  f32x4 acc[4][4];
#pragma unroll
  for (int m = 0; m < 4; m++)
#pragma unroll
    for (int n = 0; n < 4; n++) acc[m][n] = (f32x4){0.f, 0.f, 0.f, 0.f};

  for (int kc = 0; kc < 4; kc++) {
    const int k0 = kc * 64;
#pragma unroll
    for (int i = 0; i < 2; i++) {
      int q = (w * 2 + i) * 64 + lane;
      int r = q >> 3;
      int cl = (q & 7) ^ (r & 7);
      __builtin_amdgcn_global_load_lds(
          (const __attribute__((address_space(1))) void*)(X + (size_t)(mt + r) * DOUT + k0 + cl * 8),
          (__attribute__((address_space(3))) void*)(As + (w * 2 + i) * 512), 16, 0, 0);
    }
#pragma unroll
    for (int i = 0; i < 4; i++) {
      int q = (w * 4 + i) * 64 + lane;
      int r = q >> 3;
      int cl = (q & 7) ^ (r & 7);
      __builtin_amdgcn_global_load_lds(
          (const __attribute__((address_space(1))) void*)(Wt + (size_t)r * DOUT + k0 + cl * 8),
          (__attribute__((address_space(3))) void*)(Bs + (w * 4 + i) * 512), 16, 0, 0);
    }
    __syncthreads();
#pragma unroll
    for (int ks = 0; ks < 2; ks++) {
      bf16x8 af[4], bfr[4];
      const int ch = ks * 4 + kg;
#pragma unroll
      for (int m = 0; m < 4; m++) {
        int row = wr * 64 + m * 16 + lr;
        af[m] = *(const bf16x8*)&As[row * 64 + ((ch ^ (row & 7)) << 3)];
      }
#pragma unroll
      for (int n = 0; n < 4; n++) {
        int row = wc * 64 + n * 16 + lr;
        bfr[n] = *(const bf16x8*)&Bs[row * 64 + ((ch ^ (row & 7)) << 3)];
      }
#pragma unroll
      for (int m = 0; m < 4; m++)
#pragma unroll
        for (int n = 0; n < 4; n++)
          acc[m][n] = __builtin_amdgcn_mfma_f32_16x16x32_bf16(af[m], bfr[n], acc[m][n], 0, 0, 0);
    }
    __syncthreads();
  }

  float bc1v[4], pav[4], w0v[4], w1v[4];
#pragma unroll
  for (int n = 0; n < 4; n++) {
    int col = wc * 64 + n * 16 + lr;
    bc1v[n] = bc1[col];
    pav[n] = pa[col];
    w0v[n] = Wc2[col * 2 + 0];
    w1v[n] = Wc2[col * 2 + 1];
  }
#pragma unroll
  for (int m = 0; m < 4; m++) {
#pragma unroll
    for (int j = 0; j < 4; j++) {
      float p0 = 0.f, p1 = 0.f;
#pragma unroll
      for (int n = 0; n < 4; n++) {
        float h = acc[m][n][j] + bc1v[n];
        h = (h >= 0.f) ? h : pav[n] * h;
        p0 += h * w0v[n];
        p1 += h * w1v[n];
      }
      p0 += __shfl_xor(p0, 1); p1 += __shfl_xor(p1, 1);
      p0 += __shfl_xor(p0, 2); p1 += __shfl_xor(p1, 2);
      p0 += __shfl_xor(p0, 4); p1 += __shfl_xor(p1, 4);
      p0 += __shfl_xor(p0, 8); p1 += __shfl_xor(p1, 8);
      if (lr == 0) {
        int rowl = wr * 64 + m * 16 + kg * 4 + j;
        Lred[rowl][wc][0] = p0;
        Lred[rowl][wc][1] = p1;
      }
    }
  }
  __syncthreads();
  if (t < 128) {
    float l0 = Lred[t][0][0] + Lred[t][1][0] + Lred[t][2][0] + Lred[t][3][0] + bc2[0];
    float l1 = Lred[t][0][1] + Lred[t][1][1] + Lred[t][2][1] + Lred[t][3][1] + bc2[1];
    float m = fmaxf(l0, l1);
    float e0 = expf(l0 - m), e1 = expf(l1 - m);
    float inv = 1.0f / (e0 + e1);
    *(float2*)(probs + (size_t)(mt + t) * 2) = make_float2(e0 * inv, e1 * inv);
  }
}

// ---------------------------------------------------------------------------

extern "C" void kernel_launch(void* const* d_in, const int* in_sizes, int n_in,
                              void* d_out, int out_size, void* d_ws, size_t ws_size,
                              hipStream_t stream) {
  const int* indexes = (const int*)d_in[0];
  const float* features = (const float*)d_in[1];
  const int* sub_label = (const int*)d_in[3];
  const int* knn = (const int*)d_in[6];
  const float* all_pred = (const float*)d_in[7];
  const float* W1 = (const float*)d_in[9];
  const float* b1 = (const float*)d_in[10];
  const float* W2 = (const float*)d_in[11];
  const float* b2 = (const float*)d_in[12];
  const float* Wc1 = (const float*)d_in[13];
  const float* bc1 = (const float*)d_in[14];
  const float* pa = (const float*)d_in[15];
  const float* Wc2 = (const float*)d_in[16];
  const float* bc2 = (const float*)d_in[17];

  float* out = (float*)d_out;
  float* probs = out;                    // [B*K*2]
  float* simm = out + 32768;             // [2000]
  float* submean = out + 34768;          // [2000*2048]
  float* nums = out + 4130768;           // [2000]

  // ---- workspace layout (bytes) ----
  char* ws = (char*)d_ws;
  size_t off = 0;
  unsigned short* u_bf = (unsigned short*)(ws + off); off += (size_t)MU * DIM * 2;            // 9.4MB
  unsigned short* UR1  = (unsigned short*)(ws + off); off += (size_t)MU * 2 * NHID * 2;       // 4.7MB
  unsigned short* x2   = (unsigned short*)(ws + off); off += (size_t)MM * DOUT * 2;           // 8.4MB
  unsigned short* W1tp = (unsigned short*)(ws + off); off += (size_t)(2 * NHID) * DIM * 2;    // 4.2MB
  unsigned short* W2tp = (unsigned short*)(ws + off); off += (size_t)(2 * DOUT) * NHID * 2;   // 0.5MB
  unsigned short* Wc1t = (unsigned short*)(ws + off); off += (size_t)DOUT * DOUT * 2;         // 0.13MB
  float* Abuf = (float*)(ws + off); off += (size_t)MM * KK * 4;                               // 4MB
  int* cnt     = (int*)(ws + off); off += NSUB * 4;
  int* rowlist = (int*)(ws + off); off += (size_t)NSUB * CAP * 4;                             // 1MB
  int* sublabs = (int*)(ws + off); off += (size_t)MM * 4;
  float* norms0 = (float*)(ws + off); off += (size_t)BB * 4;

  hipMemsetAsync(cnt, 0, NSUB * sizeof(int), stream);

  k_build_misc<<<196 + 2368 + 304, 256, 0, stream>>>(
      sub_label, cnt, rowlist, W1, W2, Wc1, W1tp, W2tp, Wc1t,
      indexes, features, u_bf, norms0);
  k_cluster_sum<<<NSUB, 256, 0, stream>>>(features, rowlist, cnt,
                                          submean, simm, nums, u_bf);
  k_gram_gemm<<<NGEMM + BB, 512, 0, stream>>>(u_bf, W1tp, UR1, sub_label, knn,
                                              simm, norms0, all_pred, Abuf, sublabs);
  k_l12fused<<<BB, 512, 0, stream>>>(Abuf, UR1, sublabs, b1, W2tp, b2, x2);
  k_cls_fused<<<MM / 128, 512, 0, stream>>>(x2, Wc1t, bc1, pa, Wc2, bc2, probs);
}

// Round 10
// 180.263 us; speedup vs baseline: 9.1997x; 1.1038x over previous
//
#include <hip/hip_runtime.h>
#include <hip/hip_bf16.h>

// ---------------------------------------------------------------------------
// Sub_Cluster_Level_GCN — round 9:
//   * classifier fused as stage C of k_l12c (x2 never leaves LDS; probs direct)
//   * W transposes + r0 cast merged into cluster_sum launch (hidden under BW)
//   4 kernels + 1 memset total.
// ---------------------------------------------------------------------------

#define NROW 50000
#define DIM  2048
#define NSUB 2000
#define BB   256
#define KK   64
#define NHID 512
#define DOUT 256
#define MM   (BB * KK)
#define MU   2304
#define CAP  128

typedef __attribute__((ext_vector_type(8))) short bf16x8;
typedef __attribute__((ext_vector_type(4))) float f32x4;

__device__ __forceinline__ unsigned short f2bf(float f) {
  union { float f; unsigned u; } v; v.f = f;
  unsigned r = v.u + 0x7FFF + ((v.u >> 16) & 1);
  return (unsigned short)(r >> 16);
}
__device__ __forceinline__ float bf2f(unsigned short h) {
  union { unsigned u; float f; } v; v.u = ((unsigned)h) << 16;
  return v.f;
}

// ---------------- build: bucketed rowlist ----------------------------------
__global__ __launch_bounds__(256) void k_build(const int* __restrict__ sub_label,
                                               int* __restrict__ cnt,
                                               int* __restrict__ rowlist) {
  int i = blockIdx.x * 256 + threadIdx.x;
  if (i < NROW) {
    int s = sub_label[i];
    int pos = atomicAdd(&cnt[s], 1);
    rowlist[(s << 7) + pos] = i;
  }
}

// --- cluster_sum (2000) + W transposes (2368) + r0 cast (304) in one launch -
__global__ __launch_bounds__(256) void k_sum_misc(const float* __restrict__ features,
                                                  const int* __restrict__ rowlist,
                                                  const int* __restrict__ cnt,
                                                  float* __restrict__ submean,
                                                  float* __restrict__ simm,
                                                  float* __restrict__ nums,
                                                  unsigned short* __restrict__ u_bf,
                                                  const float* __restrict__ W1,
                                                  const float* __restrict__ W2,
                                                  const float* __restrict__ Wc1,
                                                  unsigned short* __restrict__ W1t,
                                                  unsigned short* __restrict__ W2t,
                                                  unsigned short* __restrict__ Wc1t,
                                                  const int* __restrict__ indexes,
                                                  float* __restrict__ norms0) {
  int bid = blockIdx.x;
  int t = threadIdx.x;
  if (bid < NSUB) {
    // ---- cluster mean + simm + nums + u row ----
    int s = bid;
    int n = cnt[s];
    const int* rl = rowlist + (s << 7);
    float acc[8] = {0, 0, 0, 0, 0, 0, 0, 0};
    int r = 0;
    for (; r + 3 < n; r += 4) {
      const float* rA = features + (size_t)rl[r] * DIM + t * 8;
      const float* rB = features + (size_t)rl[r + 1] * DIM + t * 8;
      const float* rC = features + (size_t)rl[r + 2] * DIM + t * 8;
      const float* rD = features + (size_t)rl[r + 3] * DIM + t * 8;
      float4 a0 = *(const float4*)(rA), a1 = *(const float4*)(rA + 4);
      float4 b0 = *(const float4*)(rB), b1 = *(const float4*)(rB + 4);
      float4 c0 = *(const float4*)(rC), c1 = *(const float4*)(rC + 4);
      float4 d0 = *(const float4*)(rD), d1 = *(const float4*)(rD + 4);
      acc[0] += (a0.x + b0.x) + (c0.x + d0.x);
      acc[1] += (a0.y + b0.y) + (c0.y + d0.y);
      acc[2] += (a0.z + b0.z) + (c0.z + d0.z);
      acc[3] += (a0.w + b0.w) + (c0.w + d0.w);
      acc[4] += (a1.x + b1.x) + (c1.x + d1.x);
      acc[5] += (a1.y + b1.y) + (c1.y + d1.y);
      acc[6] += (a1.z + b1.z) + (c1.z + d1.z);
      acc[7] += (a1.w + b1.w) + (c1.w + d1.w);
    }
    for (; r < n; r++) {
      const float* row = features + (size_t)rl[r] * DIM + t * 8;
      float4 v0 = *(const float4*)(row);
      float4 v1 = *(const float4*)(row + 4);
      acc[0] += v0.x; acc[1] += v0.y; acc[2] += v0.z; acc[3] += v0.w;
      acc[4] += v1.x; acc[5] += v1.y; acc[6] += v1.z; acc[7] += v1.w;
    }
    float inv = 1.0f / (float)(n > 0 ? n : 1);
    float m[8];
    float ss = 0.f;
#pragma unroll
    for (int i = 0; i < 8; i++) { m[i] = acc[i] * inv; ss += m[i] * m[i]; }
    float* outp = submean + (size_t)s * DIM + t * 8;
    *(float4*)(outp)     = make_float4(m[0], m[1], m[2], m[3]);
    *(float4*)(outp + 4) = make_float4(m[4], m[5], m[6], m[7]);
    __shared__ float red[256];
    red[t] = ss;
    __syncthreads();
    for (int s2 = 128; s2 > 0; s2 >>= 1) {
      if (t < s2) red[t] += red[t + s2];
      __syncthreads();
    }
    float tot = red[0];
    if (t == 0) {
      simm[s] = tot;
      nums[s] = (float)n;
    }
    float scale = (tot > 0.f) ? (1.0f / sqrtf(tot)) : 0.f;
    bf16x8 o;
    o[0] = (short)f2bf(m[0] * scale); o[1] = (short)f2bf(m[1] * scale);
    o[2] = (short)f2bf(m[2] * scale); o[3] = (short)f2bf(m[3] * scale);
    o[4] = (short)f2bf(m[4] * scale); o[5] = (short)f2bf(m[5] * scale);
    o[6] = (short)f2bf(m[6] * scale); o[7] = (short)f2bf(m[7] * scale);
    *(bf16x8*)(u_bf + (size_t)s * DIM + t * 8) = o;
    return;
  }
  bid -= NSUB;
  if (bid >= 2368) {
    // ---- r0 cast/norm ----
    int row = bid - 2368;
    unsigned short* dst = u_bf + (size_t)(NSUB + row) * DIM + t * 8;
    if (row >= BB) {
      bf16x8 z = {0, 0, 0, 0, 0, 0, 0, 0};
      *(bf16x8*)dst = z;
      return;
    }
    const float* src = features + (size_t)indexes[row] * DIM + t * 8;
    float4 v0 = *(const float4*)(src);
    float4 v1 = *(const float4*)(src + 4);
    float ss = v0.x * v0.x + v0.y * v0.y + v0.z * v0.z + v0.w * v0.w +
               v1.x * v1.x + v1.y * v1.y + v1.z * v1.z + v1.w * v1.w;
    __shared__ float red2[256];
    red2[t] = ss;
    __syncthreads();
    for (int s2 = 128; s2 > 0; s2 >>= 1) {
      if (t < s2) red2[t] += red2[t + s2];
      __syncthreads();
    }
    float nrm = sqrtf(red2[0]);
    if (t == 0) norms0[row] = nrm;
    float scale = 1.0f / nrm;
    bf16x8 o;
    o[0] = (short)f2bf(v0.x * scale); o[1] = (short)f2bf(v0.y * scale);
    o[2] = (short)f2bf(v0.z * scale); o[3] = (short)f2bf(v0.w * scale);
    o[4] = (short)f2bf(v1.x * scale); o[5] = (short)f2bf(v1.y * scale);
    o[6] = (short)f2bf(v1.z * scale); o[7] = (short)f2bf(v1.w * scale);
    *(bf16x8*)dst = o;
    return;
  }
  // ---- W transpose tiles ----
  const float* src;
  unsigned short* dst;
  int Nsrc, Kdst, ntn, local;
  if (bid < 1024)      { local = bid;        src = W1;                        dst = W1t;                      Nsrc = NHID; Kdst = DIM;  ntn = 16; }
  else if (bid < 2048) { local = bid - 1024; src = W1 + (size_t)DIM * NHID;   dst = W1t + (size_t)NHID * DIM; Nsrc = NHID; Kdst = DIM;  ntn = 16; }
  else if (bid < 2176) { local = bid - 2048; src = W2;                        dst = W2t;                      Nsrc = DOUT; Kdst = NHID; ntn = 8; }
  else if (bid < 2304) { local = bid - 2176; src = W2 + (size_t)NHID * DOUT;  dst = W2t + (size_t)DOUT * NHID;Nsrc = DOUT; Kdst = NHID; ntn = 8; }
  else                 { local = bid - 2304; src = Wc1;                       dst = Wc1t;                     Nsrc = DOUT; Kdst = DOUT; ntn = 8; }
  int n0 = (local % ntn) * 32, k0 = (local / ntn) * 32;
  __shared__ float tile[32][33];
  int c = t & 31, r8 = t >> 5;
#pragma unroll
  for (int i = 0; i < 4; i++) {
    int r = r8 + i * 8;
    tile[r][c] = src[(size_t)(k0 + r) * Nsrc + n0 + c];
  }
  __syncthreads();
#pragma unroll
  for (int i = 0; i < 4; i++) {
    int r = r8 + i * 8;
    dst[(size_t)(n0 + r) * Kdst + k0 + c] = f2bf(tile[c][r]);
  }
}

// ------- fused gram (256 blocks) + gemm1 (144 tiles), 512 threads -----------
#define NGEMM 144
__global__ __launch_bounds__(512) void k_gram_gemm(const unsigned short* __restrict__ u_bf,
                                                   const unsigned short* __restrict__ W1tp,
                                                   unsigned short* __restrict__ UR1,
                                                   const int* __restrict__ sub_label,
                                                   const int* __restrict__ knn,
                                                   const float* __restrict__ simm,
                                                   const float* __restrict__ norms0,
                                                   const float* __restrict__ all_pred,
                                                   float* __restrict__ A,
                                                   int* __restrict__ sublabs) {
  __shared__ char big[32768];
  __shared__ int slr[64];
  __shared__ float nks[64], wjs[64];
  const int t = threadIdx.x;
  const int w = t >> 6, lane = t & 63;
  const int lr = lane & 15, kg = lane >> 4;

  if (blockIdx.x < NGEMM) {
    constexpr int KTOT = DIM;
    constexpr int NTOT = 2 * NHID;
    unsigned short* As = (unsigned short*)big;
    unsigned short* Bs = (unsigned short*)(big + 16384);
    int orig = blockIdx.x;
    int swz = (orig & 7) * (NGEMM / 8) + (orig >> 3);
    const int nt = (swz & 7) * 128;
    const int mt = (swz >> 3) * 128;
    const int wr = w >> 2, wc = w & 3;

    f32x4 acc[4][2];
#pragma unroll
    for (int m = 0; m < 4; m++)
#pragma unroll
      for (int n = 0; n < 2; n++) acc[m][n] = (f32x4){0.f, 0.f, 0.f, 0.f};

    for (int kc = 0; kc < KTOT / 64; kc++) {
      const int k0 = kc * 64;
#pragma unroll
      for (int i = 0; i < 2; i++) {
        int q = (w * 2 + i) * 64 + lane;
        int r = q >> 3;
        int cl = (q & 7) ^ (r & 7);
        __builtin_amdgcn_global_load_lds(
            (const __attribute__((address_space(1))) void*)(u_bf + (size_t)(mt + r) * KTOT + k0 + cl * 8),
            (__attribute__((address_space(3))) void*)(As + (w * 2 + i) * 512), 16, 0, 0);
      }
#pragma unroll
      for (int i = 0; i < 2; i++) {
        int q = (w * 2 + i) * 64 + lane;
        int r = q >> 3;
        int cl = (q & 7) ^ (r & 7);
        __builtin_amdgcn_global_load_lds(
            (const __attribute__((address_space(1))) void*)(W1tp + (size_t)(nt + r) * KTOT + k0 + cl * 8),
            (__attribute__((address_space(3))) void*)(Bs + (w * 2 + i) * 512), 16, 0, 0);
      }
      __syncthreads();
#pragma unroll
      for (int ks = 0; ks < 2; ks++) {
        bf16x8 af[4], bfr[2];
        const int ch = ks * 4 + kg;
#pragma unroll
        for (int m = 0; m < 4; m++) {
          int row = wr * 64 + m * 16 + lr;
          af[m] = *(const bf16x8*)&As[row * 64 + ((ch ^ (row & 7)) << 3)];
        }
#pragma unroll
        for (int n = 0; n < 2; n++) {
          int row = wc * 32 + n * 16 + lr;
          bfr[n] = *(const bf16x8*)&Bs[row * 64 + ((ch ^ (row & 7)) << 3)];
        }
#pragma unroll
        for (int m = 0; m < 4; m++)
#pragma unroll
          for (int n = 0; n < 2; n++)
            acc[m][n] = __builtin_amdgcn_mfma_f32_16x16x32_bf16(af[m], bfr[n], acc[m][n], 0, 0, 0);
      }
      __syncthreads();
    }
#pragma unroll
    for (int m = 0; m < 4; m++) {
      int rm = mt + wr * 64 + m * 16 + kg * 4;
#pragma unroll
      for (int n = 0; n < 2; n++) {
        int col = nt + wc * 32 + n * 16 + lr;
#pragma unroll
        for (int j = 0; j < 4; j++)
          UR1[(size_t)(rm + j) * NTOT + col] = f2bf(acc[m][n][j]);
      }
    }
    return;
  }

  int b = blockIdx.x - NGEMM;
  unsigned short* Xs = (unsigned short*)big;
  if (t < 64) {
    int sl = sub_label[knn[b * KK + t]];
    sublabs[b * KK + t] = sl;
    slr[t] = (t == 0) ? (NSUB + b) : sl;
    float s2 = (t == 0) ? 0.f : simm[sl];
    nks[t] = (t == 0) ? norms0[b] : ((s2 > 0.f) ? sqrtf(s2) : 0.f);
    wjs[t] = expf(all_pred[(size_t)(b * KK + t) * 2 + 1]);
  }
  __syncthreads();

  const int rb = w & 3;
  const int cp = w >> 2;
  int rloc[4], clsw[4];
#pragma unroll
  for (int i = 0; i < 4; i++) {
    rloc[i] = w * 8 + i * 2 + (lane >> 5);
    clsw[i] = (lane & 31) ^ (rloc[i] & 7);
  }

  f32x4 acc0 = {0.f, 0.f, 0.f, 0.f}, acc1 = {0.f, 0.f, 0.f, 0.f};
  for (int c = 0; c < 8; c++) {
    if (c) __syncthreads();
#pragma unroll
    for (int i = 0; i < 4; i++) {
      const unsigned short* src =
          u_bf + (size_t)slr[rloc[i]] * DIM + c * 256 + clsw[i] * 8;
      __builtin_amdgcn_global_load_lds(
          (const __attribute__((address_space(1))) void*)src,
          (__attribute__((address_space(3))) void*)(Xs + (w * 8 + i * 2) * 256), 16, 0, 0);
    }
    __syncthreads();
#pragma unroll
    for (int ks = 0; ks < 8; ks++) {
      const int ch = ks * 4 + kg;
      int Ra = rb * 16 + lr;
      bf16x8 fa = *(const bf16x8*)&Xs[Ra * 256 + ((ch ^ (Ra & 7)) << 3)];
      int R0 = (cp * 2) * 16 + lr;
      bf16x8 f0 = *(const bf16x8*)&Xs[R0 * 256 + ((ch ^ (R0 & 7)) << 3)];
      int R1 = (cp * 2 + 1) * 16 + lr;
      bf16x8 f1 = *(const bf16x8*)&Xs[R1 * 256 + ((ch ^ (R1 & 7)) << 3)];
      acc0 = __builtin_amdgcn_mfma_f32_16x16x32_bf16(fa, f0, acc0, 0, 0, 0);
      acc1 = __builtin_amdgcn_mfma_f32_16x16x32_bf16(fa, f1, acc1, 0, 0, 0);
    }
  }

  __syncthreads();
  float* Cs = (float*)big;
#pragma unroll
  for (int r = 0; r < 4; r++) {
    Cs[(rb * 16 + kg * 4 + r) * 68 + cp * 32 + lr] = acc0[r];
    Cs[(rb * 16 + kg * 4 + r) * 68 + cp * 32 + 16 + lr] = acc1[r];
  }
  __syncthreads();

  int row = t >> 3, seg = t & 7;
  float nr = nks[row];
  float v[8];
  float mx = -1e30f;
#pragma unroll
  for (int i = 0; i < 8; i++) {
    int j = seg * 8 + i;
    v[i] = Cs[row * 68 + j] * nr * nks[j] * wjs[j];
    mx = fmaxf(mx, v[i]);
  }
  mx = fmaxf(mx, __shfl_xor(mx, 1));
  mx = fmaxf(mx, __shfl_xor(mx, 2));
  mx = fmaxf(mx, __shfl_xor(mx, 4));
  float sum = 0.f;
#pragma unroll
  for (int i = 0; i < 8; i++) {
    v[i] = expf(v[i] - mx);
    sum += v[i];
  }
  sum += __shfl_xor(sum, 1);
  sum += __shfl_xor(sum, 2);
  sum += __shfl_xor(sum, 4);
  float inv = 1.0f / sum;
  float* outp = A + ((size_t)b * KK + row) * KK + seg * 8;
  *(float4*)(outp)     = make_float4(v[0] * inv, v[1] * inv, v[2] * inv, v[3] * inv);
  *(float4*)(outp + 4) = make_float4(v[4] * inv, v[5] * inv, v[6] * inv, v[7] * inv);
}

// ---- l12c: combine1 + gemm2 + combine2 + classifier, all per-sample --------
// Stage 0: x1s[64][512](LDS) = relu(Za + P@Bg + b1)
// Stage A: Z2 = x1s @ [W2a|W2b]^T (Ws streamed)
// Stage B: x2s[64][256](LDS) = relu(Z2a + A@Z2b + b2)
// Stage C: h = PReLU(x2s@Wc1t^T + bc1); probs = softmax(h@Wc2 + bc2)
__global__ __launch_bounds__(512) void k_l12c(const float* __restrict__ A,
                                              const unsigned short* __restrict__ UR1,
                                              const int* __restrict__ sublabs,
                                              const float* __restrict__ b1,
                                              const unsigned short* __restrict__ W2tp,
                                              const float* __restrict__ b2,
                                              const unsigned short* __restrict__ Wc1t,
                                              const float* __restrict__ bc1,
                                              const float* __restrict__ pa,
                                              const float* __restrict__ Wc2,
                                              const float* __restrict__ bc2,
                                              float* __restrict__ probs) {
  __shared__ char lds[131072];
  unsigned short* x1s = (unsigned short*)lds;              // [64][512] 64KB (st0/A)
  char* R = lds + 65536;
  unsigned short* Pl = (unsigned short*)R;                 // [64][80]
  unsigned short* Bl = (unsigned short*)(R + 10240);       // [128][80]
  unsigned short* Ag = (unsigned short*)(R + 30720);       // [64][136]
  float* Raf = (float*)(R + 48128);                        // [128]
  float* red8 = (float*)(R + 48640);                       // [64][8]
  int* slh = (int*)(R + 50688);                            // [64]
  unsigned short* Ws = (unsigned short*)R;                 // stage A: [512][64] 64KB
  unsigned short* Za = (unsigned short*)lds;               // stage B: [64][264]
  unsigned short* Zb = (unsigned short*)(lds + 34816);     // [256][72]
  unsigned short* Pl2 = (unsigned short*)(lds + 71680);    // [64][72]
  unsigned short* x2s = (unsigned short*)(lds + 34816);    // stage C: [64][256] 32KB
  unsigned short* Ws2 = (unsigned short*)lds;              // stage C: [256][64] 32KB
  float* Lred = (float*)(lds + 71680);                     // [64][8][2] 4KB

  const int b = blockIdx.x;
  const int t = threadIdx.x;
  const int w = t >> 6, lane = t & 63;
  const int lr = lane & 15, kg = lane >> 4;
  constexpr int NSTR = 2 * NHID;

  // ---- stage 0 prologue ----
  if (t < 64) slh[t] = sublabs[b * KK + t];
  {
    int pk = t & 63, pp = t >> 6;
    const float* Arow = A + ((size_t)b * KK + pk) * KK;
    float part = 0.f;
#pragma unroll
    for (int e = 0; e < 8; e++) {
      int j = pp * 8 + e;
      float av = Arow[j];
      if (j > 0) {
        Pl[pk * 80 + j] = f2bf(av);
        part += av;
      }
    }
    red8[pk * 8 + pp] = part;
  }
  __syncthreads();
  if (t < 64) {
    float rs = 0.f;
#pragma unroll
    for (int p = 0; p < 8; p++) rs += red8[t * 8 + p];
    Pl[t * 80 + 0] = f2bf(-rs);
  }

  // ---- stage 0: combine1, 4 d-blocks ----
  for (int db = 0; db < 4; db++) {
    const int dblk = db * 128;
    __syncthreads();
    {
      int gj = t >> 3, gc0 = t & 7;
      size_t brow = (gj == 0) ? (size_t)(NSUB + b) : (size_t)slh[gj];
      const unsigned short* Bp = UR1 + brow * NSTR + NHID + dblk;
#pragma unroll
      for (int it = 0; it < 2; it++) {
        int c = gc0 + it * 8;
        bf16x8 v = *(const bf16x8*)(Bp + c * 8);
#pragma unroll
        for (int e = 0; e < 8; e++) Bl[(c * 8 + e) * 80 + gj] = v[e];
      }
    }
    {
      int ak = t >> 3, ac0 = t & 7;
      const unsigned short* Ap = UR1 + (size_t)slh[ak] * NSTR + dblk;
#pragma unroll
      for (int it = 0; it < 2; it++) {
        int c = ac0 + it * 8;
        *(bf16x8*)&Ag[ak * 136 + c * 8] = *(const bf16x8*)(Ap + c * 8);
      }
      if (t < 128) Raf[t] = bf2f(UR1[(size_t)(NSUB + b) * NSTR + dblk + t]);
    }
    __syncthreads();

    f32x4 acc[4];
#pragma unroll
    for (int m = 0; m < 4; m++) acc[m] = (f32x4){0.f, 0.f, 0.f, 0.f};
#pragma unroll
    for (int ks = 0; ks < 2; ks++) {
      const int ch = ks * 4 + kg;
      bf16x8 bfr = *(const bf16x8*)&Bl[(w * 16 + lr) * 80 + ch * 8];
#pragma unroll
      for (int m = 0; m < 4; m++) {
        bf16x8 af = *(const bf16x8*)&Pl[(m * 16 + lr) * 80 + ch * 8];
        acc[m] = __builtin_amdgcn_mfma_f32_16x16x32_bf16(af, bfr, acc[m], 0, 0, 0);
      }
    }
#pragma unroll
    for (int m = 0; m < 4; m++) {
      int d = w * 16 + lr;
      float bd = b1[dblk + d];
#pragma unroll
      for (int j = 0; j < 4; j++) {
        int k = m * 16 + kg * 4 + j;
        float v = acc[m][j] + bd;
        if (k > 0) v += bf2f(Ag[k * 136 + d]) - Raf[d];
        int cg = dblk + d;
        int C = cg >> 3;
        x1s[k * 512 + (((C ^ (k & 7)) << 3) | (cg & 7))] = f2bf(fmaxf(v, 0.f));
      }
    }
  }
  __syncthreads();

  // ---- stage A: Z2 = x1s @ W2tp^T ----
  const int wr = w >> 2, wc = w & 3;
  f32x4 accA[2][8];
#pragma unroll
  for (int m = 0; m < 2; m++)
#pragma unroll
    for (int n = 0; n < 8; n++) accA[m][n] = (f32x4){0.f, 0.f, 0.f, 0.f};

  for (int kc = 0; kc < 8; kc++) {
    const int k0 = kc * 64;
    if (kc) __syncthreads();
#pragma unroll
    for (int i = 0; i < 8; i++) {
      int r = w * 64 + i * 8 + (lane >> 3);
      int cl = (lane & 7) ^ (r & 7);
      __builtin_amdgcn_global_load_lds(
          (const __attribute__((address_space(1))) void*)(W2tp + (size_t)r * NHID + k0 + cl * 8),
          (__attribute__((address_space(3))) void*)(Ws + (w * 64 + i * 8) * 64), 16, 0, 0);
    }
    __syncthreads();
#pragma unroll
    for (int ks = 0; ks < 2; ks++) {
      const int ch = ks * 4 + kg;
      const int C = kc * 8 + ch;
      bf16x8 af[2], bfr[8];
#pragma unroll
      for (int m = 0; m < 2; m++) {
        int row = wr * 32 + m * 16 + lr;
        af[m] = *(const bf16x8*)&x1s[row * 512 + ((C ^ (row & 7)) << 3)];
      }
#pragma unroll
      for (int n = 0; n < 8; n++) {
        int row = wc * 128 + n * 16 + lr;
        bfr[n] = *(const bf16x8*)&Ws[row * 64 + ((ch ^ (row & 7)) << 3)];
      }
#pragma unroll
      for (int m = 0; m < 2; m++)
#pragma unroll
        for (int n = 0; n < 8; n++)
          accA[m][n] = __builtin_amdgcn_mfma_f32_16x16x32_bf16(af[m], bfr[n], accA[m][n], 0, 0, 0);
    }
  }
  __syncthreads();

  // ---- stage B: scatter Z2, P2 = bf16(A), combine -> x2s (LDS) ----
#pragma unroll
  for (int m = 0; m < 2; m++) {
#pragma unroll
    for (int n = 0; n < 8; n++) {
      int col = wc * 128 + n * 16 + lr;
#pragma unroll
      for (int j = 0; j < 4; j++) {
        int row = wr * 32 + m * 16 + kg * 4 + j;
        unsigned short hv = f2bf(accA[m][n][j]);
        if (col < 256) Za[row * 264 + col] = hv;
        else           Zb[(col - 256) * 72 + row] = hv;
      }
    }
  }
  {
    const float* Ap = A + (size_t)b * KK * KK + t * 8;
    float4 f0 = *(const float4*)(Ap);
    float4 f1 = *(const float4*)(Ap + 4);
    bf16x8 hv;
    hv[0] = (short)f2bf(f0.x); hv[1] = (short)f2bf(f0.y);
    hv[2] = (short)f2bf(f0.z); hv[3] = (short)f2bf(f0.w);
    hv[4] = (short)f2bf(f1.x); hv[5] = (short)f2bf(f1.y);
    hv[6] = (short)f2bf(f1.z); hv[7] = (short)f2bf(f1.w);
    *(bf16x8*)&Pl2[(t >> 3) * 72 + (t & 7) * 8] = hv;
  }
  __syncthreads();

  f32x4 acc2[4][2];
#pragma unroll
  for (int m = 0; m < 4; m++)
#pragma unroll
    for (int n = 0; n < 2; n++) acc2[m][n] = (f32x4){0.f, 0.f, 0.f, 0.f};
#pragma unroll
  for (int ks = 0; ks < 2; ks++) {
    const int ch = ks * 4 + kg;
    bf16x8 af[4], bfr[2];
#pragma unroll
    for (int m = 0; m < 4; m++) af[m] = *(const bf16x8*)&Pl2[(m * 16 + lr) * 72 + ch * 8];
#pragma unroll
    for (int n = 0; n < 2; n++) bfr[n] = *(const bf16x8*)&Zb[(w * 32 + n * 16 + lr) * 72 + ch * 8];
#pragma unroll
    for (int m = 0; m < 4; m++)
#pragma unroll
      for (int n = 0; n < 2; n++)
        acc2[m][n] = __builtin_amdgcn_mfma_f32_16x16x32_bf16(af[m], bfr[n], acc2[m][n], 0, 0, 0);
  }
  __syncthreads();   // Zb reads done -> x2s region writable

#pragma unroll
  for (int m = 0; m < 4; m++) {
#pragma unroll
    for (int n = 0; n < 2; n++) {
      int d = w * 32 + n * 16 + lr;
      float bd = b2[d];
#pragma unroll
      for (int j = 0; j < 4; j++) {
        int k = m * 16 + kg * 4 + j;
        float v = acc2[m][n][j] + bf2f(Za[k * 264 + d]) + bd;
        int C = d >> 3;
        x2s[k * 256 + (((C ^ (k & 7)) << 3) | (d & 7))] = f2bf(fmaxf(v, 0.f));
      }
    }
  }
  __syncthreads();   // Za reads done -> Ws2 region writable; x2s complete

  // ---- stage C: classifier ----
  f32x4 acc3[4][2];
#pragma unroll
  for (int m = 0; m < 4; m++)
#pragma unroll
    for (int n = 0; n < 2; n++) acc3[m][n] = (f32x4){0.f, 0.f, 0.f, 0.f};

  for (int kc = 0; kc < 4; kc++) {
    const int k0 = kc * 64;
    if (kc) __syncthreads();
#pragma unroll
    for (int i = 0; i < 4; i++) {
      int r = w * 32 + i * 8 + (lane >> 3);
      int cl = (lane & 7) ^ (r & 7);
      __builtin_amdgcn_global_load_lds(
          (const __attribute__((address_space(1))) void*)(Wc1t + (size_t)r * DOUT + k0 + cl * 8),
          (__attribute__((address_space(3))) void*)(Ws2 + (w * 32 + i * 8) * 64), 16, 0, 0);
    }
    __syncthreads();
#pragma unroll
    for (int ks = 0; ks < 2; ks++) {
      const int ch = ks * 4 + kg;
      const int C = kc * 8 + ch;
      bf16x8 af[4], bfr[2];
#pragma unroll
      for (int m = 0; m < 4; m++) {
        int row = m * 16 + lr;
        af[m] = *(const bf16x8*)&x2s[row * 256 + ((C ^ (row & 7)) << 3)];
      }
#pragma unroll
      for (int n = 0; n < 2; n++) {
        int row = w * 32 + n * 16 + lr;
        bfr[n] = *(const bf16x8*)&Ws2[row * 64 + ((ch ^ (row & 7)) << 3)];
      }
#pragma unroll
      for (int m = 0; m < 4; m++)
#pragma unroll
        for (int n = 0; n < 2; n++)
          acc3[m][n] = __builtin_amdgcn_mfma_f32_16x16x32_bf16(af[m], bfr[n], acc3[m][n], 0, 0, 0);
    }
  }

  float bc1v[2], pav[2], w0v[2], w1v[2];
#pragma unroll
  for (int n = 0; n < 2; n++) {
    int col = w * 32 + n * 16 + lr;
    bc1v[n] = bc1[col];
    pav[n] = pa[col];
    w0v[n] = Wc2[col * 2 + 0];
    w1v[n] = Wc2[col * 2 + 1];
  }
  __syncthreads();   // Ws2 reads done -> Lred region writable
#pragma unroll
  for (int m = 0; m < 4; m++) {
#pragma unroll
    for (int j = 0; j < 4; j++) {
      float p0 = 0.f, p1 = 0.f;
#pragma unroll
      for (int n = 0; n < 2; n++) {
        float h = acc3[m][n][j] + bc1v[n];
        h = (h >= 0.f) ? h : pav[n] * h;
        p0 += h * w0v[n];
        p1 += h * w1v[n];
      }
      p0 += __shfl_xor(p0, 1); p1 += __shfl_xor(p1, 1);
      p0 += __shfl_xor(p0, 2); p1 += __shfl_xor(p1, 2);
      p0 += __shfl_xor(p0, 4); p1 += __shfl_xor(p1, 4);
      p0 += __shfl_xor(p0, 8); p1 += __shfl_xor(p1, 8);
      if (lr == 0) {
        int rowl = m * 16 + kg * 4 + j;
        Lred[(rowl * 8 + w) * 2 + 0] = p0;
        Lred[(rowl * 8 + w) * 2 + 1] = p1;
      }
    }
  }
  __syncthreads();
  if (t < 64) {
    float l0 = bc2[0], l1 = bc2[1];
#pragma unroll
    for (int p = 0; p < 8; p++) {
      l0 += Lred[(t * 8 + p) * 2 + 0];
      l1 += Lred[(t * 8 + p) * 2 + 1];
    }
    float m = fmaxf(l0, l1);
    float e0 = expf(l0 - m), e1 = expf(l1 - m);
    float inv = 1.0f / (e0 + e1);
    *(float2*)(probs + (size_t)(b * KK + t) * 2) = make_float2(e0 * inv, e1 * inv);
  }
}

// ---------------------------------------------------------------------------

extern "C" void kernel_launch(void* const* d_in, const int* in_sizes, int n_in,
                              void* d_out, int out_size, void* d_ws, size_t ws_size,
                              hipStream_t stream) {
  const int* indexes = (const int*)d_in[0];
  const float* features = (const float*)d_in[1];
  const int* sub_label = (const int*)d_in[3];
  const int* knn = (const int*)d_in[6];
  const float* all_pred = (const float*)d_in[7];
  const float* W1 = (const float*)d_in[9];
  const float* b1 = (const float*)d_in[10];
  const float* W2 = (const float*)d_in[11];
  const float* b2 = (const float*)d_in[12];
  const float* Wc1 = (const float*)d_in[13];
  const float* bc1 = (const float*)d_in[14];
  const float* pa = (const float*)d_in[15];
  const float* Wc2 = (const float*)d_in[16];
  const float* bc2 = (const float*)d_in[17];

  float* out = (float*)d_out;
  float* probs = out;
  float* simm = out + 32768;
  float* submean = out + 34768;
  float* nums = out + 4130768;

  char* ws = (char*)d_ws;
  size_t off = 0;
  unsigned short* u_bf = (unsigned short*)(ws + off); off += (size_t)MU * DIM * 2;
  unsigned short* UR1  = (unsigned short*)(ws + off); off += (size_t)MU * 2 * NHID * 2;
  unsigned short* W1tp = (unsigned short*)(ws + off); off += (size_t)(2 * NHID) * DIM * 2;
  unsigned short* W2tp = (unsigned short*)(ws + off); off += (size_t)(2 * DOUT) * NHID * 2;
  unsigned short* Wc1t = (unsigned short*)(ws + off); off += (size_t)DOUT * DOUT * 2;
  float* Abuf = (float*)(ws + off); off += (size_t)MM * KK * 4;
  int* cnt     = (int*)(ws + off); off += NSUB * 4;
  int* rowlist = (int*)(ws + off); off += (size_t)NSUB * CAP * 4;
  int* sublabs = (int*)(ws + off); off += (size_t)MM * 4;
  float* norms0 = (float*)(ws + off); off += (size_t)BB * 4;

  hipMemsetAsync(cnt, 0, NSUB * sizeof(int), stream);

  k_build<<<(NROW + 255) / 256, 256, 0, stream>>>(sub_label, cnt, rowlist);
  k_sum_misc<<<NSUB + 2368 + 304, 256, 0, stream>>>(
      features, rowlist, cnt, submean, simm, nums, u_bf,
      W1, W2, Wc1, W1tp, W2tp, Wc1t, indexes, norms0);
  k_gram_gemm<<<NGEMM + BB, 512, 0, stream>>>(u_bf, W1tp, UR1, sub_label, knn,
                                              simm, norms0, all_pred, Abuf, sublabs);
  k_l12c<<<BB, 512, 0, stream>>>(Abuf, UR1, sublabs, b1, W2tp, b2,
                                 Wc1t, bc1, pa, Wc2, bc2, probs);
}